// Round 1
// baseline (3283.220 us; speedup 1.0000x reference)
//
#include <hip/hip_runtime.h>
#include <hip/hip_bf16.h>
#include <math.h>

constexpr int S_ = 2048, H_ = 1024, NH_ = 16, KVH_ = 8, HD_ = 64;
constexpr int E_ = 8, I_ = 3584;
constexpr float EPS_ = 1e-6f;
constexpr float THETA_ = 1000000.0f;

#define SDIV(a,b) (((a)+(b)-1)/(b))

// ---------------- RMSNorm: one 256-thread block per row (H=1024 -> 4 f32/thread)
__global__ __launch_bounds__(256) void rmsnorm_k(const float* __restrict__ x,
                                                 const float* __restrict__ w,
                                                 float* __restrict__ out)
{
    int row = blockIdx.x;
    int tid = threadIdx.x;
    const float* xr = x + (size_t)row * H_;
    float4 v = *(const float4*)&xr[tid * 4];
    float ss = v.x*v.x + v.y*v.y + v.z*v.z + v.w*v.w;
#pragma unroll
    for (int off = 32; off > 0; off >>= 1) ss += __shfl_xor(ss, off);
    __shared__ float red[4];
    if ((tid & 63) == 0) red[tid >> 6] = ss;
    __syncthreads();
    float tot = red[0] + red[1] + red[2] + red[3];
    float r = rsqrtf(tot / (float)H_ + EPS_);
    float4 wv = *(const float4*)&w[tid * 4];
    float4 o;
    o.x = v.x * r * wv.x; o.y = v.y * r * wv.y;
    o.z = v.z * r * wv.z; o.w = v.w * r * wv.w;
    *(float4*)&out[(size_t)row * H_ + tid * 4] = o;
}

// ---------------- Generic fp32 GEMM: C[M,N] = (Res?) + A[M,K] * B[N,K]^T
// 64x64 tile, 256 threads, 4x4 per thread. M,N %64==0, K %16==0.
__global__ __launch_bounds__(256) void gemm_nt(const float* __restrict__ A,
                                               const float* __restrict__ Bm,
                                               const float* __restrict__ Res,
                                               float* __restrict__ C,
                                               int M, int N, int K)
{
    __shared__ float As[16][64];
    __shared__ float Bs[16][64];
    int tid = threadIdx.x;
    int m0 = blockIdx.y * 64, n0 = blockIdx.x * 64;
    int lr = tid >> 2, lc = (tid & 3) << 2;
    int tx = tid & 15, ty = tid >> 4;
    float acc[4][4] = {};
    const float* Aptr = A + (size_t)(m0 + lr) * K + lc;
    const float* Bptr = Bm + (size_t)(n0 + lr) * K + lc;
    for (int kb = 0; kb < K; kb += 16) {
        float4 av = *(const float4*)(Aptr + kb);
        float4 bv = *(const float4*)(Bptr + kb);
        __syncthreads();
        As[lc+0][lr]=av.x; As[lc+1][lr]=av.y; As[lc+2][lr]=av.z; As[lc+3][lr]=av.w;
        Bs[lc+0][lr]=bv.x; Bs[lc+1][lr]=bv.y; Bs[lc+2][lr]=bv.z; Bs[lc+3][lr]=bv.w;
        __syncthreads();
#pragma unroll
        for (int kk = 0; kk < 16; ++kk) {
            float4 a4 = *(const float4*)&As[kk][ty << 2];
            float4 b4 = *(const float4*)&Bs[kk][tx << 2];
            float aa[4] = {a4.x, a4.y, a4.z, a4.w};
            float bb[4] = {b4.x, b4.y, b4.z, b4.w};
#pragma unroll
            for (int i = 0; i < 4; ++i)
#pragma unroll
                for (int j = 0; j < 4; ++j)
                    acc[i][j] = fmaf(aa[i], bb[j], acc[i][j]);
        }
    }
#pragma unroll
    for (int i = 0; i < 4; ++i) {
        int row = m0 + (ty << 2) + i;
#pragma unroll
        for (int j = 0; j < 4; ++j) {
            int col = n0 + (tx << 2) + j;
            float r = Res ? Res[(size_t)row * N + col] : 0.0f;
            C[(size_t)row * N + col] = acc[i][j] + r;
        }
    }
}

// ---------------- RoPE in-place on q [S,NH*HD] and k [S,KVH*HD]
__global__ __launch_bounds__(256) void rope_k(float* __restrict__ q, float* __restrict__ k)
{
    int idx = blockIdx.x * 256 + threadIdx.x;
    const int totq = S_ * NH_ * (HD_ / 2);
    const int tot = totq + S_ * KVH_ * (HD_ / 2);
    if (idx >= tot) return;
    float* base; int s, di;
    if (idx < totq) {
        s = idx / (NH_ * 32); int r = idx % (NH_ * 32);
        base = q + ((size_t)s * NH_ + (r >> 5)) * HD_; di = r & 31;
    } else {
        int j = idx - totq;
        s = j / (KVH_ * 32); int r = j % (KVH_ * 32);
        base = k + ((size_t)s * KVH_ + (r >> 5)) * HD_; di = r & 31;
    }
    float invf = powf(THETA_, -(2.0f * di) / (float)HD_);
    float ang = (float)s * invf;
    float c = cosf(ang), sn = sinf(ang);
    float x0 = base[di], x1 = base[di + 32];
    base[di]      = x0 * c - x1 * sn;
    base[di + 32] = x1 * c + x0 * sn;
}

// ---------------- Attention: one 64-lane wave per (query, head). Causal, GQA rep=2.
__global__ __launch_bounds__(64) void attn_k(const float* __restrict__ q,
                                             const float* __restrict__ k,
                                             const float* __restrict__ v,
                                             float* __restrict__ ctx)
{
    int sq = blockIdx.x, h = blockIdx.y;
    int lane = threadIdx.x;
    int kvh = h >> 1;  // NH/KVH = 2
    __shared__ float qs[HD_];
    __shared__ float sc[S_];
    qs[lane] = q[((size_t)sq * NH_ + h) * HD_ + lane];
    __syncthreads();
    float lmax = -1e30f;
    for (int t = lane; t <= sq; t += 64) {
        const float4* kr = (const float4*)(k + ((size_t)t * KVH_ + kvh) * HD_);
        const float4* q4 = (const float4*)qs;
        float d0 = 0.f, d1 = 0.f, d2 = 0.f, d3 = 0.f;
#pragma unroll
        for (int x = 0; x < HD_ / 4; ++x) {
            float4 kv = kr[x]; float4 qv = q4[x];
            d0 = fmaf(qv.x, kv.x, d0); d1 = fmaf(qv.y, kv.y, d1);
            d2 = fmaf(qv.z, kv.z, d2); d3 = fmaf(qv.w, kv.w, d3);
        }
        float d = ((d0 + d1) + (d2 + d3)) * 0.125f;
        sc[t] = d;
        lmax = fmaxf(lmax, d);
    }
#pragma unroll
    for (int off = 32; off > 0; off >>= 1) lmax = fmaxf(lmax, __shfl_xor(lmax, off));
    float lsum = 0.f;
    for (int t = lane; t <= sq; t += 64) {
        float p = expf(sc[t] - lmax);
        sc[t] = p; lsum += p;
    }
#pragma unroll
    for (int off = 32; off > 0; off >>= 1) lsum += __shfl_xor(lsum, off);
    __syncthreads();
    // output: lane owns dim d = lane
    float a0 = 0.f, a1 = 0.f, a2 = 0.f, a3 = 0.f;
    const float* vb = v + (size_t)kvh * HD_ + lane;
    int t = 0;
    for (; t + 4 <= sq + 1; t += 4) {
        a0 = fmaf(sc[t+0], vb[(size_t)(t+0) * KVH_ * HD_], a0);
        a1 = fmaf(sc[t+1], vb[(size_t)(t+1) * KVH_ * HD_], a1);
        a2 = fmaf(sc[t+2], vb[(size_t)(t+2) * KVH_ * HD_], a2);
        a3 = fmaf(sc[t+3], vb[(size_t)(t+3) * KVH_ * HD_], a3);
    }
    for (; t <= sq; ++t) a0 = fmaf(sc[t], vb[(size_t)t * KVH_ * HD_], a0);
    float acc = (a0 + a1) + (a2 + a3);
    ctx[((size_t)sq * NH_ + h) * HD_ + lane] = acc / lsum;
}

// ---------------- Router: 1 wave per token; 28-combination argmax; atomic expert lists
__global__ __launch_bounds__(64) void router_k(const float* __restrict__ x2,
                                               const float* __restrict__ gw,
                                               int* __restrict__ cnt,
                                               int* __restrict__ elist,
                                               int* __restrict__ eslot,
                                               float* __restrict__ wslot)
{
    int n = blockIdx.x, lane = threadIdx.x;
    float part[E_];
#pragma unroll
    for (int e = 0; e < E_; ++e) part[e] = 0.f;
    const float* xr = x2 + (size_t)n * H_;
    for (int j = lane; j < H_; j += 64) {
        float xv = xr[j];
#pragma unroll
        for (int e = 0; e < E_; ++e) part[e] = fmaf(xv, gw[e * H_ + j], part[e]);
    }
#pragma unroll
    for (int e = 0; e < E_; ++e)
#pragma unroll
        for (int off = 32; off > 0; off >>= 1) part[e] += __shfl_xor(part[e], off);
    if (lane == 0) {
        float mx = part[0];
#pragma unroll
        for (int e = 1; e < E_; ++e) mx = fmaxf(mx, part[e]);
        float rw[E_]; float ssum = 0.f;
#pragma unroll
        for (int e = 0; e < E_; ++e) { rw[e] = expf(part[e] - mx); ssum += rw[e]; }
#pragma unroll
        for (int e = 0; e < E_; ++e) rw[e] /= ssum;
        // combinations in itertools order; first strict max wins (matches jnp.argmax)
        float best = -1.f; int ba = 0, bb = 1;
        for (int a = 0; a < E_; ++a)
            for (int b = a + 1; b < E_; ++b) {
                float scv = rw[a] + rw[b];
                if (scv > best) { best = scv; ba = a; bb = b; }
            }
        float wa = rw[ba], wb = rw[bb], wsum = wa + wb;
        wa /= wsum; wb /= wsum;
        int p = atomicAdd(&cnt[ba], 1);
        elist[ba * S_ + p] = n; eslot[ba * S_ + p] = 2 * n;
        p = atomicAdd(&cnt[bb], 1);
        elist[bb * S_ + p] = n; eslot[bb * S_ + p] = 2 * n + 1;
        wslot[2 * n] = wa; wslot[2 * n + 1] = wb;
    }
}

// ---------------- MoE up-proj (gathered): h[slot,i] = silu(x·w1[e,i]) * (x·w3[e,i])
__global__ __launch_bounds__(256) void moe_up_k(const float* __restrict__ x2,
                                                const float* __restrict__ w1,
                                                const float* __restrict__ w3,
                                                const int* __restrict__ cnt,
                                                const int* __restrict__ elist,
                                                const int* __restrict__ eslot,
                                                float* __restrict__ hbuf)
{
    int e = blockIdx.z;
    int c = cnt[e];
    int p0 = blockIdx.y * 64;
    if (p0 >= c) return;
    int i0 = blockIdx.x * 64;
    __shared__ float As[16][64], B1s[16][64], B3s[16][64];
    __shared__ int rowtok[64];
    int tid = threadIdx.x;
    if (tid < 64) rowtok[tid] = elist[e * S_ + min(p0 + tid, c - 1)];
    __syncthreads();
    int lr = tid >> 2, lc = (tid & 3) << 2, tx = tid & 15, ty = tid >> 4;
    const float* W1 = w1 + (size_t)e * I_ * H_ + (size_t)(i0 + lr) * H_ + lc;
    const float* W3 = w3 + (size_t)e * I_ * H_ + (size_t)(i0 + lr) * H_ + lc;
    const float* Ar = x2 + (size_t)rowtok[lr] * H_ + lc;
    float acc1[4][4] = {}, acc3[4][4] = {};
    for (int kb = 0; kb < H_; kb += 16) {
        float4 av = *(const float4*)(Ar + kb);
        float4 b1 = *(const float4*)(W1 + kb);
        float4 b3 = *(const float4*)(W3 + kb);
        __syncthreads();
        As[lc+0][lr]=av.x;  As[lc+1][lr]=av.y;  As[lc+2][lr]=av.z;  As[lc+3][lr]=av.w;
        B1s[lc+0][lr]=b1.x; B1s[lc+1][lr]=b1.y; B1s[lc+2][lr]=b1.z; B1s[lc+3][lr]=b1.w;
        B3s[lc+0][lr]=b3.x; B3s[lc+1][lr]=b3.y; B3s[lc+2][lr]=b3.z; B3s[lc+3][lr]=b3.w;
        __syncthreads();
#pragma unroll
        for (int kk = 0; kk < 16; ++kk) {
            float4 a4 = *(const float4*)&As[kk][ty << 2];
            float4 b14 = *(const float4*)&B1s[kk][tx << 2];
            float4 b34 = *(const float4*)&B3s[kk][tx << 2];
            float aa[4] = {a4.x, a4.y, a4.z, a4.w};
            float u1[4] = {b14.x, b14.y, b14.z, b14.w};
            float u3[4] = {b34.x, b34.y, b34.z, b34.w};
#pragma unroll
            for (int i = 0; i < 4; ++i)
#pragma unroll
                for (int j = 0; j < 4; ++j) {
                    acc1[i][j] = fmaf(aa[i], u1[j], acc1[i][j]);
                    acc3[i][j] = fmaf(aa[i], u3[j], acc3[i][j]);
                }
        }
    }
#pragma unroll
    for (int i = 0; i < 4; ++i) {
        int p = p0 + (ty << 2) + i;
        if (p < c) {
            int slot = eslot[e * S_ + p];
            float* hr = hbuf + (size_t)slot * I_ + i0 + (tx << 2);
#pragma unroll
            for (int j = 0; j < 4; ++j) {
                float h1 = acc1[i][j];
                float sig = 1.f / (1.f + expf(-h1));
                hr[j] = h1 * sig * acc3[i][j];
            }
        }
    }
}

// ---------------- MoE down-proj (gathered): dbuf[slot,:] = h[slot]·w2[e]^T
__global__ __launch_bounds__(256) void moe_down_k(const float* __restrict__ hbuf,
                                                  const float* __restrict__ w2,
                                                  const int* __restrict__ cnt,
                                                  const int* __restrict__ eslot,
                                                  float* __restrict__ dbuf)
{
    int e = blockIdx.z;
    int c = cnt[e];
    int p0 = blockIdx.y * 64;
    if (p0 >= c) return;
    int h0 = blockIdx.x * 64;
    __shared__ float As[16][64], Bs[16][64];
    __shared__ int rowslot[64];
    int tid = threadIdx.x;
    if (tid < 64) rowslot[tid] = eslot[e * S_ + min(p0 + tid, c - 1)];
    __syncthreads();
    int lr = tid >> 2, lc = (tid & 3) << 2, tx = tid & 15, ty = tid >> 4;
    const float* Ar = hbuf + (size_t)rowslot[lr] * I_ + lc;
    const float* Br = w2 + (size_t)e * H_ * I_ + (size_t)(h0 + lr) * I_ + lc;
    float acc[4][4] = {};
    for (int kb = 0; kb < I_; kb += 16) {
        float4 av = *(const float4*)(Ar + kb);
        float4 bv = *(const float4*)(Br + kb);
        __syncthreads();
        As[lc+0][lr]=av.x; As[lc+1][lr]=av.y; As[lc+2][lr]=av.z; As[lc+3][lr]=av.w;
        Bs[lc+0][lr]=bv.x; Bs[lc+1][lr]=bv.y; Bs[lc+2][lr]=bv.z; Bs[lc+3][lr]=bv.w;
        __syncthreads();
#pragma unroll
        for (int kk = 0; kk < 16; ++kk) {
            float4 a4 = *(const float4*)&As[kk][ty << 2];
            float4 b4 = *(const float4*)&Bs[kk][tx << 2];
            float aa[4] = {a4.x, a4.y, a4.z, a4.w};
            float bb[4] = {b4.x, b4.y, b4.z, b4.w};
#pragma unroll
            for (int i = 0; i < 4; ++i)
#pragma unroll
                for (int j = 0; j < 4; ++j)
                    acc[i][j] = fmaf(aa[i], bb[j], acc[i][j]);
        }
    }
#pragma unroll
    for (int i = 0; i < 4; ++i) {
        int p = p0 + (ty << 2) + i;
        if (p < c) {
            int slot = rowslot[(ty << 2) + i];
            float* dr = dbuf + (size_t)slot * H_ + h0 + (tx << 2);
#pragma unroll
            for (int j = 0; j < 4; ++j) dr[j] = acc[i][j];
        }
    }
}

// ---------------- Final combine: out = hid2 + w0*dbuf[2n] + w1*dbuf[2n+1]
__global__ __launch_bounds__(256) void combine_k(const float* __restrict__ hid2,
                                                 const float* __restrict__ dbuf,
                                                 const float* __restrict__ wslot,
                                                 float* __restrict__ out)
{
    int idx = blockIdx.x * 256 + threadIdx.x;
    if (idx >= S_ * H_) return;
    int n = idx >> 10;        // / H_
    int hcol = idx & (H_ - 1);
    out[idx] = hid2[idx]
             + wslot[2 * n]     * dbuf[(size_t)(2 * n) * H_ + hcol]
             + wslot[2 * n + 1] * dbuf[(size_t)(2 * n + 1) * H_ + hcol];
}

extern "C" void kernel_launch(void* const* d_in, const int* in_sizes, int n_in,
                              void* d_out, int out_size, void* d_ws, size_t ws_size,
                              hipStream_t stream)
{
    const float* hidden = (const float*)d_in[0];
    const float* ln1    = (const float*)d_in[1];
    const float* ln2    = (const float*)d_in[2];
    const float* wq     = (const float*)d_in[3];
    const float* wk     = (const float*)d_in[4];
    const float* wv     = (const float*)d_in[5];
    const float* wo     = (const float*)d_in[6];
    const float* gw     = (const float*)d_in[7];
    const float* w1     = (const float*)d_in[8];
    const float* w2     = (const float*)d_in[9];
    const float* w3     = (const float*)d_in[10];
    float* out = (float*)d_out;

    char* p = (char*)d_ws;
    auto alloc_f = [&](size_t nfloat) { float* r = (float*)p; p += nfloat * sizeof(float); return r; };
    float* xb   = alloc_f((size_t)S_ * H_);            // rms1 out; reused as ctx
    float* q    = alloc_f((size_t)S_ * NH_ * HD_);
    float* kb   = alloc_f((size_t)S_ * KVH_ * HD_);
    float* vb   = alloc_f((size_t)S_ * KVH_ * HD_);
    float* hid2 = alloc_f((size_t)S_ * H_);
    float* x2   = alloc_f((size_t)S_ * H_);
    float* hbuf = alloc_f((size_t)S_ * 2 * I_);
    float* dbuf = alloc_f((size_t)S_ * 2 * H_);
    float* wslot= alloc_f((size_t)S_ * 2);
    int* cnt   = (int*)p; p += E_ * sizeof(int);
    int* elist = (int*)p; p += (size_t)E_ * S_ * sizeof(int);
    int* eslot = (int*)p; p += (size_t)E_ * S_ * sizeof(int);
    float* ctx = xb;  // alias: xb dead after QKV GEMMs

    hipMemsetAsync(cnt, 0, E_ * sizeof(int), stream);

    // 1. RMSNorm 1
    rmsnorm_k<<<S_, 256, 0, stream>>>(hidden, ln1, xb);
    // 2-4. QKV projections
    gemm_nt<<<dim3(16, 32), 256, 0, stream>>>(xb, wq, nullptr, q,  S_, NH_ * HD_, H_);
    gemm_nt<<<dim3(8, 32),  256, 0, stream>>>(xb, wk, nullptr, kb, S_, KVH_ * HD_, H_);
    gemm_nt<<<dim3(8, 32),  256, 0, stream>>>(xb, wv, nullptr, vb, S_, KVH_ * HD_, H_);
    // 5. RoPE
    {
        int tot = S_ * (NH_ + KVH_) * (HD_ / 2);
        rope_k<<<SDIV(tot, 256), 256, 0, stream>>>(q, kb);
    }
    // 6. Attention (writes ctx == xb, q/kb/vb are read-only here)
    attn_k<<<dim3(S_, NH_), 64, 0, stream>>>(q, kb, vb, ctx);
    // 7. Out-proj + residual
    gemm_nt<<<dim3(16, 32), 256, 0, stream>>>(ctx, wo, hidden, hid2, S_, H_, NH_ * HD_);
    // 8. RMSNorm 2
    rmsnorm_k<<<S_, 256, 0, stream>>>(hid2, ln2, x2);
    // 9. Router
    router_k<<<S_, 64, 0, stream>>>(x2, gw, cnt, elist, eslot, wslot);
    // 10. MoE up (grid covers worst case; blocks early-exit past cnt[e])
    moe_up_k<<<dim3(I_ / 64, S_ / 64, E_), 256, 0, stream>>>(x2, w1, w3, cnt, elist, eslot, hbuf);
    // 11. MoE down
    moe_down_k<<<dim3(H_ / 64, S_ / 64, E_), 256, 0, stream>>>(hbuf, w2, cnt, eslot, dbuf);
    // 12. Combine
    combine_k<<<SDIV(S_ * H_, 256), 256, 0, stream>>>(hid2, dbuf, wslot, out);
}

// Round 2
// 2049.903 us; speedup vs baseline: 1.6016x; 1.6016x over previous
//
#include <hip/hip_runtime.h>
#include <hip/hip_bf16.h>
#include <math.h>

constexpr int S_ = 2048, H_ = 1024, NH_ = 16, KVH_ = 8, HD_ = 64;
constexpr int E_ = 8, I_ = 3584;
constexpr float EPS_ = 1e-6f;
constexpr float THETA_ = 1000000.0f;

#define SDIV(a,b) (((a)+(b)-1)/(b))

// ---------------- RMSNorm: one 256-thread block per row (H=1024 -> 4 f32/thread)
__global__ __launch_bounds__(256) void rmsnorm_k(const float* __restrict__ x,
                                                 const float* __restrict__ w,
                                                 float* __restrict__ out)
{
    int row = blockIdx.x;
    int tid = threadIdx.x;
    const float* xr = x + (size_t)row * H_;
    float4 v = *(const float4*)&xr[tid * 4];
    float ss = v.x*v.x + v.y*v.y + v.z*v.z + v.w*v.w;
#pragma unroll
    for (int off = 32; off > 0; off >>= 1) ss += __shfl_xor(ss, off);
    __shared__ float red[4];
    if ((tid & 63) == 0) red[tid >> 6] = ss;
    __syncthreads();
    float tot = red[0] + red[1] + red[2] + red[3];
    float r = rsqrtf(tot / (float)H_ + EPS_);
    float4 wv = *(const float4*)&w[tid * 4];
    float4 o;
    o.x = v.x * r * wv.x; o.y = v.y * r * wv.y;
    o.z = v.z * r * wv.z; o.w = v.w * r * wv.w;
    *(float4*)&out[(size_t)row * H_ + tid * 4] = o;
}

// ---------------- Generic fp32 GEMM: C[M,N] = (Res?) + A[M,K] * B[N,K]^T
__global__ __launch_bounds__(256) void gemm_nt(const float* __restrict__ A,
                                               const float* __restrict__ Bm,
                                               const float* __restrict__ Res,
                                               float* __restrict__ C,
                                               int M, int N, int K)
{
    __shared__ float As[16][64];
    __shared__ float Bs[16][64];
    int tid = threadIdx.x;
    int m0 = blockIdx.y * 64, n0 = blockIdx.x * 64;
    int lr = tid >> 2, lc = (tid & 3) << 2;
    int tx = tid & 15, ty = tid >> 4;
    float acc[4][4] = {};
    const float* Aptr = A + (size_t)(m0 + lr) * K + lc;
    const float* Bptr = Bm + (size_t)(n0 + lr) * K + lc;
    for (int kb = 0; kb < K; kb += 16) {
        float4 av = *(const float4*)(Aptr + kb);
        float4 bv = *(const float4*)(Bptr + kb);
        __syncthreads();
        As[lc+0][lr]=av.x; As[lc+1][lr]=av.y; As[lc+2][lr]=av.z; As[lc+3][lr]=av.w;
        Bs[lc+0][lr]=bv.x; Bs[lc+1][lr]=bv.y; Bs[lc+2][lr]=bv.z; Bs[lc+3][lr]=bv.w;
        __syncthreads();
#pragma unroll
        for (int kk = 0; kk < 16; ++kk) {
            float4 a4 = *(const float4*)&As[kk][ty << 2];
            float4 b4 = *(const float4*)&Bs[kk][tx << 2];
            float aa[4] = {a4.x, a4.y, a4.z, a4.w};
            float bb[4] = {b4.x, b4.y, b4.z, b4.w};
#pragma unroll
            for (int i = 0; i < 4; ++i)
#pragma unroll
                for (int j = 0; j < 4; ++j)
                    acc[i][j] = fmaf(aa[i], bb[j], acc[i][j]);
        }
    }
#pragma unroll
    for (int i = 0; i < 4; ++i) {
        int row = m0 + (ty << 2) + i;
#pragma unroll
        for (int j = 0; j < 4; ++j) {
            int col = n0 + (tx << 2) + j;
            float r = Res ? Res[(size_t)row * N + col] : 0.0f;
            C[(size_t)row * N + col] = acc[i][j] + r;
        }
    }
}

// ---------------- RoPE in-place on q [S,NH*HD] and k [S,KVH*HD]
__global__ __launch_bounds__(256) void rope_k(float* __restrict__ q, float* __restrict__ k)
{
    int idx = blockIdx.x * 256 + threadIdx.x;
    const int totq = S_ * NH_ * (HD_ / 2);
    const int tot = totq + S_ * KVH_ * (HD_ / 2);
    if (idx >= tot) return;
    float* base; int s, di;
    if (idx < totq) {
        s = idx / (NH_ * 32); int r = idx % (NH_ * 32);
        base = q + ((size_t)s * NH_ + (r >> 5)) * HD_; di = r & 31;
    } else {
        int j = idx - totq;
        s = j / (KVH_ * 32); int r = j % (KVH_ * 32);
        base = k + ((size_t)s * KVH_ + (r >> 5)) * HD_; di = r & 31;
    }
    float invf = powf(THETA_, -(2.0f * di) / (float)HD_);
    float ang = (float)s * invf;
    float c = cosf(ang), sn = sinf(ang);
    float x0 = base[di], x1 = base[di + 32];
    base[di]      = x0 * c - x1 * sn;
    base[di + 32] = x1 * c + x0 * sn;
}

// ---------------- Tiled flash attention.
// Block = 256 threads (4 waves). Score tile 64q x 64k, per-thread 4x4.
// Pairing: block handles query-blocks (pair) and (31-pair) -> uniform 33 key-tiles.
// LDS: Qs[d][q] (transposed), KPs[d][k] for K then reused as [k][q] for P, Vs[k][d].
__global__ __launch_bounds__(256) void attn_tiled(const float* __restrict__ q,
                                                  const float* __restrict__ k,
                                                  const float* __restrict__ v,
                                                  float* __restrict__ ctx)
{
    __shared__ float Qs[64][68];
    __shared__ float KPs[64][68];
    __shared__ float Vs[64][68];
    int pair = blockIdx.x, h = blockIdx.y;
    int kvh = h >> 1;                 // NH/KVH = 2
    int tid = threadIdx.x;
    int ty = tid >> 4, tx = tid & 15; // 16 x 16
    const float scale = 0.125f;       // 1/sqrt(64)

    for (int half = 0; half < 2; ++half) {
        int qb = (half == 0) ? pair : (31 - pair);
        int q0 = qb * 64;

        __syncthreads();
        // stage Q transposed: Qs[d][q]
#pragma unroll
        for (int r = 0; r < 4; ++r) {
            int idx = tid + r * 256;
            int qq = idx >> 4, ds = (idx & 15) << 2;
            float4 qv = *(const float4*)&q[((size_t)(q0 + qq) * NH_ + h) * HD_ + ds];
            Qs[ds + 0][qq] = qv.x; Qs[ds + 1][qq] = qv.y;
            Qs[ds + 2][qq] = qv.z; Qs[ds + 3][qq] = qv.w;
        }

        float m_[4], l_[4], o_[4][4];
#pragma unroll
        for (int i = 0; i < 4; ++i) {
            m_[i] = -1e30f; l_[i] = 0.f;
#pragma unroll
            for (int j = 0; j < 4; ++j) o_[i][j] = 0.f;
        }

        for (int t0 = 0; t0 <= q0; t0 += 64) {
            __syncthreads();   // prev PV / prev QK done before restaging
            // stage K transposed (KPs[d][k]) and V natural (Vs[k][d])
#pragma unroll
            for (int r = 0; r < 4; ++r) {
                int idx = tid + r * 256;
                int kk = idx >> 4, ds = (idx & 15) << 2;
                const float* kr = &k[((size_t)(t0 + kk) * KVH_ + kvh) * HD_ + ds];
                float4 kv = *(const float4*)kr;
                KPs[ds + 0][kk] = kv.x; KPs[ds + 1][kk] = kv.y;
                KPs[ds + 2][kk] = kv.z; KPs[ds + 3][kk] = kv.w;
                float4 vv = *(const float4*)&v[((size_t)(t0 + kk) * KVH_ + kvh) * HD_ + ds];
                *(float4*)&Vs[kk][ds] = vv;
            }
            __syncthreads();

            // S = Q K^T  (kk = d dimension)
            float s_[4][4] = {};
#pragma unroll 4
            for (int kk = 0; kk < 64; ++kk) {
                float4 a4 = *(const float4*)&Qs[kk][ty << 2];
                float4 b4 = *(const float4*)&KPs[kk][tx << 2];
                float aa[4] = {a4.x, a4.y, a4.z, a4.w};
                float bb[4] = {b4.x, b4.y, b4.z, b4.w};
#pragma unroll
                for (int i = 0; i < 4; ++i)
#pragma unroll
                    for (int j = 0; j < 4; ++j)
                        s_[i][j] = fmaf(aa[i], bb[j], s_[i][j]);
            }
            bool diag = (t0 == q0);
#pragma unroll
            for (int i = 0; i < 4; ++i)
#pragma unroll
                for (int j = 0; j < 4; ++j) {
                    float sv = s_[i][j] * scale;
                    if (diag && (tx * 4 + j > ty * 4 + i)) sv = -1e30f;
                    s_[i][j] = sv;
                }
            // online softmax update (row reduce across tx: 16 lanes)
            float newm[4], resc[4];
#pragma unroll
            for (int i = 0; i < 4; ++i) {
                float rm = fmaxf(fmaxf(s_[i][0], s_[i][1]), fmaxf(s_[i][2], s_[i][3]));
#pragma unroll
                for (int off = 8; off > 0; off >>= 1) rm = fmaxf(rm, __shfl_xor(rm, off));
                newm[i] = fmaxf(m_[i], rm);
                resc[i] = __expf(m_[i] - newm[i]);
                float rs = 0.f;
#pragma unroll
                for (int j = 0; j < 4; ++j) {
                    float p = __expf(s_[i][j] - newm[i]);
                    s_[i][j] = p;  // reuse as P
                    rs += p;
                }
#pragma unroll
                for (int off = 8; off > 0; off >>= 1) rs += __shfl_xor(rs, off);
                l_[i] = l_[i] * resc[i] + rs;
                m_[i] = newm[i];
#pragma unroll
                for (int j = 0; j < 4; ++j) o_[i][j] *= resc[i];
            }
            __syncthreads();   // all QK reads of KPs done before P overwrite
            // write P transposed into KPs: KPs[key][q]
#pragma unroll
            for (int i = 0; i < 4; ++i)
#pragma unroll
                for (int j = 0; j < 4; ++j)
                    KPs[tx * 4 + j][ty * 4 + i] = s_[i][j];
            __syncthreads();

            // O += P V  (kk = key dimension)
#pragma unroll 4
            for (int kk = 0; kk < 64; ++kk) {
                float4 p4 = *(const float4*)&KPs[kk][ty << 2];
                float4 v4 = *(const float4*)&Vs[kk][tx << 2];
                float pp[4] = {p4.x, p4.y, p4.z, p4.w};
                float vv[4] = {v4.x, v4.y, v4.z, v4.w};
#pragma unroll
                for (int i = 0; i < 4; ++i)
#pragma unroll
                    for (int j = 0; j < 4; ++j)
                        o_[i][j] = fmaf(pp[i], vv[j], o_[i][j]);
            }
        }
        // write output
#pragma unroll
        for (int i = 0; i < 4; ++i) {
            float inv = 1.0f / l_[i];
            float4 st;
            st.x = o_[i][0] * inv; st.y = o_[i][1] * inv;
            st.z = o_[i][2] * inv; st.w = o_[i][3] * inv;
            *(float4*)&ctx[((size_t)(q0 + ty * 4 + i) * NH_ + h) * HD_ + tx * 4] = st;
        }
    }
}

// ---------------- Router: 1 wave per token; 28-combination argmax; atomic expert lists
__global__ __launch_bounds__(64) void router_k(const float* __restrict__ x2,
                                               const float* __restrict__ gw,
                                               int* __restrict__ cnt,
                                               int* __restrict__ elist,
                                               int* __restrict__ eslot,
                                               float* __restrict__ wslot)
{
    int n = blockIdx.x, lane = threadIdx.x;
    float part[E_];
#pragma unroll
    for (int e = 0; e < E_; ++e) part[e] = 0.f;
    const float* xr = x2 + (size_t)n * H_;
    for (int j = lane; j < H_; j += 64) {
        float xv = xr[j];
#pragma unroll
        for (int e = 0; e < E_; ++e) part[e] = fmaf(xv, gw[e * H_ + j], part[e]);
    }
#pragma unroll
    for (int e = 0; e < E_; ++e)
#pragma unroll
        for (int off = 32; off > 0; off >>= 1) part[e] += __shfl_xor(part[e], off);
    if (lane == 0) {
        float mx = part[0];
#pragma unroll
        for (int e = 1; e < E_; ++e) mx = fmaxf(mx, part[e]);
        float rw[E_]; float ssum = 0.f;
#pragma unroll
        for (int e = 0; e < E_; ++e) { rw[e] = expf(part[e] - mx); ssum += rw[e]; }
#pragma unroll
        for (int e = 0; e < E_; ++e) rw[e] /= ssum;
        float best = -1.f; int ba = 0, bb = 1;
        for (int a = 0; a < E_; ++a)
            for (int b = a + 1; b < E_; ++b) {
                float scv = rw[a] + rw[b];
                if (scv > best) { best = scv; ba = a; bb = b; }
            }
        float wa = rw[ba], wb = rw[bb], wsum = wa + wb;
        wa /= wsum; wb /= wsum;
        int p = atomicAdd(&cnt[ba], 1);
        elist[ba * S_ + p] = n; eslot[ba * S_ + p] = 2 * n;
        p = atomicAdd(&cnt[bb], 1);
        elist[bb * S_ + p] = n; eslot[bb * S_ + p] = 2 * n + 1;
        wslot[2 * n] = wa; wslot[2 * n + 1] = wb;
    }
}

// ---------------- MoE up-proj (gathered): h[slot,i] = silu(x·w1[e,i]) * (x·w3[e,i])
__global__ __launch_bounds__(256) void moe_up_k(const float* __restrict__ x2,
                                                const float* __restrict__ w1,
                                                const float* __restrict__ w3,
                                                const int* __restrict__ cnt,
                                                const int* __restrict__ elist,
                                                const int* __restrict__ eslot,
                                                float* __restrict__ hbuf)
{
    int e = blockIdx.z;
    int c = cnt[e];
    int p0 = blockIdx.y * 64;
    if (p0 >= c) return;
    int i0 = blockIdx.x * 64;
    __shared__ float As[16][64], B1s[16][64], B3s[16][64];
    __shared__ int rowtok[64];
    int tid = threadIdx.x;
    if (tid < 64) rowtok[tid] = elist[e * S_ + min(p0 + tid, c - 1)];
    __syncthreads();
    int lr = tid >> 2, lc = (tid & 3) << 2, tx = tid & 15, ty = tid >> 4;
    const float* W1 = w1 + (size_t)e * I_ * H_ + (size_t)(i0 + lr) * H_ + lc;
    const float* W3 = w3 + (size_t)e * I_ * H_ + (size_t)(i0 + lr) * H_ + lc;
    const float* Ar = x2 + (size_t)rowtok[lr] * H_ + lc;
    float acc1[4][4] = {}, acc3[4][4] = {};
    for (int kb = 0; kb < H_; kb += 16) {
        float4 av = *(const float4*)(Ar + kb);
        float4 b1 = *(const float4*)(W1 + kb);
        float4 b3 = *(const float4*)(W3 + kb);
        __syncthreads();
        As[lc+0][lr]=av.x;  As[lc+1][lr]=av.y;  As[lc+2][lr]=av.z;  As[lc+3][lr]=av.w;
        B1s[lc+0][lr]=b1.x; B1s[lc+1][lr]=b1.y; B1s[lc+2][lr]=b1.z; B1s[lc+3][lr]=b1.w;
        B3s[lc+0][lr]=b3.x; B3s[lc+1][lr]=b3.y; B3s[lc+2][lr]=b3.z; B3s[lc+3][lr]=b3.w;
        __syncthreads();
#pragma unroll
        for (int kk = 0; kk < 16; ++kk) {
            float4 a4 = *(const float4*)&As[kk][ty << 2];
            float4 b14 = *(const float4*)&B1s[kk][tx << 2];
            float4 b34 = *(const float4*)&B3s[kk][tx << 2];
            float aa[4] = {a4.x, a4.y, a4.z, a4.w};
            float u1[4] = {b14.x, b14.y, b14.z, b14.w};
            float u3[4] = {b34.x, b34.y, b34.z, b34.w};
#pragma unroll
            for (int i = 0; i < 4; ++i)
#pragma unroll
                for (int j = 0; j < 4; ++j) {
                    acc1[i][j] = fmaf(aa[i], u1[j], acc1[i][j]);
                    acc3[i][j] = fmaf(aa[i], u3[j], acc3[i][j]);
                }
        }
    }
#pragma unroll
    for (int i = 0; i < 4; ++i) {
        int p = p0 + (ty << 2) + i;
        if (p < c) {
            int slot = eslot[e * S_ + p];
            float* hr = hbuf + (size_t)slot * I_ + i0 + (tx << 2);
#pragma unroll
            for (int j = 0; j < 4; ++j) {
                float h1 = acc1[i][j];
                float sig = 1.f / (1.f + expf(-h1));
                hr[j] = h1 * sig * acc3[i][j];
            }
        }
    }
}

// ---------------- MoE down-proj (gathered): dbuf[slot,:] = h[slot]·w2[e]^T
__global__ __launch_bounds__(256) void moe_down_k(const float* __restrict__ hbuf,
                                                  const float* __restrict__ w2,
                                                  const int* __restrict__ cnt,
                                                  const int* __restrict__ eslot,
                                                  float* __restrict__ dbuf)
{
    int e = blockIdx.z;
    int c = cnt[e];
    int p0 = blockIdx.y * 64;
    if (p0 >= c) return;
    int h0 = blockIdx.x * 64;
    __shared__ float As[16][64], Bs[16][64];
    __shared__ int rowslot[64];
    int tid = threadIdx.x;
    if (tid < 64) rowslot[tid] = eslot[e * S_ + min(p0 + tid, c - 1)];
    __syncthreads();
    int lr = tid >> 2, lc = (tid & 3) << 2, tx = tid & 15, ty = tid >> 4;
    const float* Ar = hbuf + (size_t)rowslot[lr] * I_ + lc;
    const float* Br = w2 + (size_t)e * H_ * I_ + (size_t)(h0 + lr) * I_ + lc;
    float acc[4][4] = {};
    for (int kb = 0; kb < I_; kb += 16) {
        float4 av = *(const float4*)(Ar + kb);
        float4 bv = *(const float4*)(Br + kb);
        __syncthreads();
        As[lc+0][lr]=av.x; As[lc+1][lr]=av.y; As[lc+2][lr]=av.z; As[lc+3][lr]=av.w;
        Bs[lc+0][lr]=bv.x; Bs[lc+1][lr]=bv.y; Bs[lc+2][lr]=bv.z; Bs[lc+3][lr]=bv.w;
        __syncthreads();
#pragma unroll
        for (int kk = 0; kk < 16; ++kk) {
            float4 a4 = *(const float4*)&As[kk][ty << 2];
            float4 b4 = *(const float4*)&Bs[kk][tx << 2];
            float aa[4] = {a4.x, a4.y, a4.z, a4.w};
            float bb[4] = {b4.x, b4.y, b4.z, b4.w};
#pragma unroll
            for (int i = 0; i < 4; ++i)
#pragma unroll
                for (int j = 0; j < 4; ++j)
                    acc[i][j] = fmaf(aa[i], bb[j], acc[i][j]);
        }
    }
#pragma unroll
    for (int i = 0; i < 4; ++i) {
        int p = p0 + (ty << 2) + i;
        if (p < c) {
            int slot = rowslot[(ty << 2) + i];
            float* dr = dbuf + (size_t)slot * H_ + h0 + (tx << 2);
#pragma unroll
            for (int j = 0; j < 4; ++j) dr[j] = acc[i][j];
        }
    }
}

// ---------------- Final combine: out = hid2 + w0*dbuf[2n] + w1*dbuf[2n+1]
__global__ __launch_bounds__(256) void combine_k(const float* __restrict__ hid2,
                                                 const float* __restrict__ dbuf,
                                                 const float* __restrict__ wslot,
                                                 float* __restrict__ out)
{
    int idx = blockIdx.x * 256 + threadIdx.x;
    if (idx >= S_ * H_) return;
    int n = idx >> 10;
    int hcol = idx & (H_ - 1);
    out[idx] = hid2[idx]
             + wslot[2 * n]     * dbuf[(size_t)(2 * n) * H_ + hcol]
             + wslot[2 * n + 1] * dbuf[(size_t)(2 * n + 1) * H_ + hcol];
}

extern "C" void kernel_launch(void* const* d_in, const int* in_sizes, int n_in,
                              void* d_out, int out_size, void* d_ws, size_t ws_size,
                              hipStream_t stream)
{
    const float* hidden = (const float*)d_in[0];
    const float* ln1    = (const float*)d_in[1];
    const float* ln2    = (const float*)d_in[2];
    const float* wq     = (const float*)d_in[3];
    const float* wk     = (const float*)d_in[4];
    const float* wv     = (const float*)d_in[5];
    const float* wo     = (const float*)d_in[6];
    const float* gw     = (const float*)d_in[7];
    const float* w1     = (const float*)d_in[8];
    const float* w2     = (const float*)d_in[9];
    const float* w3     = (const float*)d_in[10];
    float* out = (float*)d_out;

    char* p = (char*)d_ws;
    auto alloc_f = [&](size_t nfloat) { float* r = (float*)p; p += nfloat * sizeof(float); return r; };
    float* xb   = alloc_f((size_t)S_ * H_);            // rms1 out; reused as ctx
    float* q    = alloc_f((size_t)S_ * NH_ * HD_);
    float* kb   = alloc_f((size_t)S_ * KVH_ * HD_);
    float* vb   = alloc_f((size_t)S_ * KVH_ * HD_);
    float* hid2 = alloc_f((size_t)S_ * H_);
    float* x2   = alloc_f((size_t)S_ * H_);
    float* hbuf = alloc_f((size_t)S_ * 2 * I_);
    float* dbuf = alloc_f((size_t)S_ * 2 * H_);
    float* wslot= alloc_f((size_t)S_ * 2);
    int* cnt   = (int*)p; p += E_ * sizeof(int);
    int* elist = (int*)p; p += (size_t)E_ * S_ * sizeof(int);
    int* eslot = (int*)p; p += (size_t)E_ * S_ * sizeof(int);
    float* ctx = xb;  // alias: xb dead after QKV GEMMs

    hipMemsetAsync(cnt, 0, E_ * sizeof(int), stream);

    // 1. RMSNorm 1
    rmsnorm_k<<<S_, 256, 0, stream>>>(hidden, ln1, xb);
    // 2-4. QKV projections
    gemm_nt<<<dim3(16, 32), 256, 0, stream>>>(xb, wq, nullptr, q,  S_, NH_ * HD_, H_);
    gemm_nt<<<dim3(8, 32),  256, 0, stream>>>(xb, wk, nullptr, kb, S_, KVH_ * HD_, H_);
    gemm_nt<<<dim3(8, 32),  256, 0, stream>>>(xb, wv, nullptr, vb, S_, KVH_ * HD_, H_);
    // 5. RoPE
    {
        int tot = S_ * (NH_ + KVH_) * (HD_ / 2);
        rope_k<<<SDIV(tot, 256), 256, 0, stream>>>(q, kb);
    }
    // 6. Tiled attention (writes ctx == xb)
    attn_tiled<<<dim3(16, 16), 256, 0, stream>>>(q, kb, vb, ctx);
    // 7. Out-proj + residual
    gemm_nt<<<dim3(16, 32), 256, 0, stream>>>(ctx, wo, hidden, hid2, S_, H_, NH_ * HD_);
    // 8. RMSNorm 2
    rmsnorm_k<<<S_, 256, 0, stream>>>(hid2, ln2, x2);
    // 9. Router
    router_k<<<S_, 64, 0, stream>>>(x2, gw, cnt, elist, eslot, wslot);
    // 10. MoE up
    moe_up_k<<<dim3(I_ / 64, S_ / 64, E_), 256, 0, stream>>>(x2, w1, w3, cnt, elist, eslot, hbuf);
    // 11. MoE down
    moe_down_k<<<dim3(H_ / 64, S_ / 64, E_), 256, 0, stream>>>(hbuf, w2, cnt, eslot, dbuf);
    // 12. Combine
    combine_k<<<SDIV(S_ * H_, 256), 256, 0, stream>>>(hid2, dbuf, wslot, out);
}

// Round 3
// 960.583 us; speedup vs baseline: 3.4179x; 2.1340x over previous
//
#include <hip/hip_runtime.h>
#include <hip/hip_bf16.h>
#include <math.h>

constexpr int S_ = 2048, H_ = 1024, NH_ = 16, KVH_ = 8, HD_ = 64;
constexpr int E_ = 8, I_ = 3584;
constexpr float EPS_ = 1e-6f;
constexpr float THETA_ = 1000000.0f;

#define SDIV(a,b) (((a)+(b)-1)/(b))

typedef __attribute__((ext_vector_type(8))) short bf16x8;
typedef __attribute__((ext_vector_type(4))) float f32x4;

__device__ inline unsigned pkbf(float a, float b) {
    unsigned r;
    asm("v_cvt_pk_bf16_f32 %0, %1, %2" : "=v"(r) : "v"(a), "v"(b));
    return r;
}
__device__ inline unsigned short f2bf(float f) {
    unsigned u = __float_as_uint(f);
    u += 0x7FFF + ((u >> 16) & 1);
    return (unsigned short)(u >> 16);
}

// ---------------- RMSNorm
__global__ __launch_bounds__(256) void rmsnorm_k(const float* __restrict__ x,
                                                 const float* __restrict__ w,
                                                 float* __restrict__ out)
{
    int row = blockIdx.x;
    int tid = threadIdx.x;
    const float* xr = x + (size_t)row * H_;
    float4 v = *(const float4*)&xr[tid * 4];
    float ss = v.x*v.x + v.y*v.y + v.z*v.z + v.w*v.w;
#pragma unroll
    for (int off = 32; off > 0; off >>= 1) ss += __shfl_xor(ss, off);
    __shared__ float red[4];
    if ((tid & 63) == 0) red[tid >> 6] = ss;
    __syncthreads();
    float tot = red[0] + red[1] + red[2] + red[3];
    float r = rsqrtf(tot / (float)H_ + EPS_);
    float4 wv = *(const float4*)&w[tid * 4];
    float4 o;
    o.x = v.x * r * wv.x; o.y = v.y * r * wv.y;
    o.z = v.z * r * wv.z; o.w = v.w * r * wv.w;
    *(float4*)&out[(size_t)row * H_ + tid * 4] = o;
}

// ---------------- Generic fp32 GEMM: C[M,N] = (Res?) + A[M,K] * B[N,K]^T
__global__ __launch_bounds__(256) void gemm_nt(const float* __restrict__ A,
                                               const float* __restrict__ Bm,
                                               const float* __restrict__ Res,
                                               float* __restrict__ C,
                                               int M, int N, int K)
{
    __shared__ float As[16][64];
    __shared__ float Bs[16][64];
    int tid = threadIdx.x;
    int m0 = blockIdx.y * 64, n0 = blockIdx.x * 64;
    int lr = tid >> 2, lc = (tid & 3) << 2;
    int tx = tid & 15, ty = tid >> 4;
    float acc[4][4] = {};
    const float* Aptr = A + (size_t)(m0 + lr) * K + lc;
    const float* Bptr = Bm + (size_t)(n0 + lr) * K + lc;
    for (int kb = 0; kb < K; kb += 16) {
        float4 av = *(const float4*)(Aptr + kb);
        float4 bv = *(const float4*)(Bptr + kb);
        __syncthreads();
        As[lc+0][lr]=av.x; As[lc+1][lr]=av.y; As[lc+2][lr]=av.z; As[lc+3][lr]=av.w;
        Bs[lc+0][lr]=bv.x; Bs[lc+1][lr]=bv.y; Bs[lc+2][lr]=bv.z; Bs[lc+3][lr]=bv.w;
        __syncthreads();
#pragma unroll
        for (int kk = 0; kk < 16; ++kk) {
            float4 a4 = *(const float4*)&As[kk][ty << 2];
            float4 b4 = *(const float4*)&Bs[kk][tx << 2];
            float aa[4] = {a4.x, a4.y, a4.z, a4.w};
            float bb[4] = {b4.x, b4.y, b4.z, b4.w};
#pragma unroll
            for (int i = 0; i < 4; ++i)
#pragma unroll
                for (int j = 0; j < 4; ++j)
                    acc[i][j] = fmaf(aa[i], bb[j], acc[i][j]);
        }
    }
#pragma unroll
    for (int i = 0; i < 4; ++i) {
        int row = m0 + (ty << 2) + i;
#pragma unroll
        for (int j = 0; j < 4; ++j) {
            int col = n0 + (tx << 2) + j;
            float r = Res ? Res[(size_t)row * N + col] : 0.0f;
            C[(size_t)row * N + col] = acc[i][j] + r;
        }
    }
}

// ---------------- RoPE
__global__ __launch_bounds__(256) void rope_k(float* __restrict__ q, float* __restrict__ k)
{
    int idx = blockIdx.x * 256 + threadIdx.x;
    const int totq = S_ * NH_ * (HD_ / 2);
    const int tot = totq + S_ * KVH_ * (HD_ / 2);
    if (idx >= tot) return;
    float* base; int s, di;
    if (idx < totq) {
        s = idx / (NH_ * 32); int r = idx % (NH_ * 32);
        base = q + ((size_t)s * NH_ + (r >> 5)) * HD_; di = r & 31;
    } else {
        int j = idx - totq;
        s = j / (KVH_ * 32); int r = j % (KVH_ * 32);
        base = k + ((size_t)s * KVH_ + (r >> 5)) * HD_; di = r & 31;
    }
    float invf = powf(THETA_, -(2.0f * di) / (float)HD_);
    float ang = (float)s * invf;
    float c = cosf(ang), sn = sinf(ang);
    float x0 = base[di], x1 = base[di + 32];
    base[di]      = x0 * c - x1 * sn;
    base[di + 32] = x1 * c + x0 * sn;
}

// ---------------- Tiled flash attention (unchanged from R2)
__global__ __launch_bounds__(256) void attn_tiled(const float* __restrict__ q,
                                                  const float* __restrict__ k,
                                                  const float* __restrict__ v,
                                                  float* __restrict__ ctx)
{
    __shared__ float Qs[64][68];
    __shared__ float KPs[64][68];
    __shared__ float Vs[64][68];
    int pair = blockIdx.x, h = blockIdx.y;
    int kvh = h >> 1;
    int tid = threadIdx.x;
    int ty = tid >> 4, tx = tid & 15;
    const float scale = 0.125f;

    for (int half = 0; half < 2; ++half) {
        int qb = (half == 0) ? pair : (31 - pair);
        int q0 = qb * 64;

        __syncthreads();
#pragma unroll
        for (int r = 0; r < 4; ++r) {
            int idx = tid + r * 256;
            int qq = idx >> 4, ds = (idx & 15) << 2;
            float4 qv = *(const float4*)&q[((size_t)(q0 + qq) * NH_ + h) * HD_ + ds];
            Qs[ds + 0][qq] = qv.x; Qs[ds + 1][qq] = qv.y;
            Qs[ds + 2][qq] = qv.z; Qs[ds + 3][qq] = qv.w;
        }

        float m_[4], l_[4], o_[4][4];
#pragma unroll
        for (int i = 0; i < 4; ++i) {
            m_[i] = -1e30f; l_[i] = 0.f;
#pragma unroll
            for (int j = 0; j < 4; ++j) o_[i][j] = 0.f;
        }

        for (int t0 = 0; t0 <= q0; t0 += 64) {
            __syncthreads();
#pragma unroll
            for (int r = 0; r < 4; ++r) {
                int idx = tid + r * 256;
                int kk = idx >> 4, ds = (idx & 15) << 2;
                float4 kv = *(const float4*)&k[((size_t)(t0 + kk) * KVH_ + kvh) * HD_ + ds];
                KPs[ds + 0][kk] = kv.x; KPs[ds + 1][kk] = kv.y;
                KPs[ds + 2][kk] = kv.z; KPs[ds + 3][kk] = kv.w;
                float4 vv = *(const float4*)&v[((size_t)(t0 + kk) * KVH_ + kvh) * HD_ + ds];
                *(float4*)&Vs[kk][ds] = vv;
            }
            __syncthreads();

            float s_[4][4] = {};
#pragma unroll 4
            for (int kk = 0; kk < 64; ++kk) {
                float4 a4 = *(const float4*)&Qs[kk][ty << 2];
                float4 b4 = *(const float4*)&KPs[kk][tx << 2];
                float aa[4] = {a4.x, a4.y, a4.z, a4.w};
                float bb[4] = {b4.x, b4.y, b4.z, b4.w};
#pragma unroll
                for (int i = 0; i < 4; ++i)
#pragma unroll
                    for (int j = 0; j < 4; ++j)
                        s_[i][j] = fmaf(aa[i], bb[j], s_[i][j]);
            }
            bool diag = (t0 == q0);
#pragma unroll
            for (int i = 0; i < 4; ++i)
#pragma unroll
                for (int j = 0; j < 4; ++j) {
                    float sv = s_[i][j] * scale;
                    if (diag && (tx * 4 + j > ty * 4 + i)) sv = -1e30f;
                    s_[i][j] = sv;
                }
            float newm[4], resc[4];
#pragma unroll
            for (int i = 0; i < 4; ++i) {
                float rm = fmaxf(fmaxf(s_[i][0], s_[i][1]), fmaxf(s_[i][2], s_[i][3]));
#pragma unroll
                for (int off = 8; off > 0; off >>= 1) rm = fmaxf(rm, __shfl_xor(rm, off));
                newm[i] = fmaxf(m_[i], rm);
                resc[i] = __expf(m_[i] - newm[i]);
                float rs = 0.f;
#pragma unroll
                for (int j = 0; j < 4; ++j) {
                    float p = __expf(s_[i][j] - newm[i]);
                    s_[i][j] = p;
                    rs += p;
                }
#pragma unroll
                for (int off = 8; off > 0; off >>= 1) rs += __shfl_xor(rs, off);
                l_[i] = l_[i] * resc[i] + rs;
                m_[i] = newm[i];
#pragma unroll
                for (int j = 0; j < 4; ++j) o_[i][j] *= resc[i];
            }
            __syncthreads();
#pragma unroll
            for (int i = 0; i < 4; ++i)
#pragma unroll
                for (int j = 0; j < 4; ++j)
                    KPs[tx * 4 + j][ty * 4 + i] = s_[i][j];
            __syncthreads();

#pragma unroll 4
            for (int kk = 0; kk < 64; ++kk) {
                float4 p4 = *(const float4*)&KPs[kk][ty << 2];
                float4 v4 = *(const float4*)&Vs[kk][tx << 2];
                float pp[4] = {p4.x, p4.y, p4.z, p4.w};
                float vv[4] = {v4.x, v4.y, v4.z, v4.w};
#pragma unroll
                for (int i = 0; i < 4; ++i)
#pragma unroll
                    for (int j = 0; j < 4; ++j)
                        o_[i][j] = fmaf(pp[i], vv[j], o_[i][j]);
            }
        }
#pragma unroll
        for (int i = 0; i < 4; ++i) {
            float inv = 1.0f / l_[i];
            float4 st;
            st.x = o_[i][0] * inv; st.y = o_[i][1] * inv;
            st.z = o_[i][2] * inv; st.w = o_[i][3] * inv;
            *(float4*)&ctx[((size_t)(q0 + ty * 4 + i) * NH_ + h) * HD_ + tx * 4] = st;
        }
    }
}

// ---------------- Router
__global__ __launch_bounds__(64) void router_k(const float* __restrict__ x2,
                                               const float* __restrict__ gw,
                                               int* __restrict__ cnt,
                                               int* __restrict__ elist,
                                               int* __restrict__ eslot,
                                               float* __restrict__ wslot)
{
    int n = blockIdx.x, lane = threadIdx.x;
    float part[E_];
#pragma unroll
    for (int e = 0; e < E_; ++e) part[e] = 0.f;
    const float* xr = x2 + (size_t)n * H_;
    for (int j = lane; j < H_; j += 64) {
        float xv = xr[j];
#pragma unroll
        for (int e = 0; e < E_; ++e) part[e] = fmaf(xv, gw[e * H_ + j], part[e]);
    }
#pragma unroll
    for (int e = 0; e < E_; ++e)
#pragma unroll
        for (int off = 32; off > 0; off >>= 1) part[e] += __shfl_xor(part[e], off);
    if (lane == 0) {
        float mx = part[0];
#pragma unroll
        for (int e = 1; e < E_; ++e) mx = fmaxf(mx, part[e]);
        float rw[E_]; float ssum = 0.f;
#pragma unroll
        for (int e = 0; e < E_; ++e) { rw[e] = expf(part[e] - mx); ssum += rw[e]; }
#pragma unroll
        for (int e = 0; e < E_; ++e) rw[e] /= ssum;
        float best = -1.f; int ba = 0, bb = 1;
        for (int a = 0; a < E_; ++a)
            for (int b = a + 1; b < E_; ++b) {
                float scv = rw[a] + rw[b];
                if (scv > best) { best = scv; ba = a; bb = b; }
            }
        float wa = rw[ba], wb = rw[bb], wsum = wa + wb;
        wa /= wsum; wb /= wsum;
        int p = atomicAdd(&cnt[ba], 1);
        elist[ba * S_ + p] = n; eslot[ba * S_ + p] = 2 * n;
        p = atomicAdd(&cnt[bb], 1);
        elist[bb * S_ + p] = n; eslot[bb * S_ + p] = 2 * n + 1;
        wslot[2 * n] = wa; wslot[2 * n + 1] = wb;
    }
}

// ---------------- MoE up (bf16 MFMA): 64(M) x 128(N) tile, BK=64.
// Waves 0..3 own 32-col strips. Dual accumulator (w1 & w3). Epilogue: silu*mul -> bf16 hbuf.
__global__ __launch_bounds__(256) void moe_up_mfma(const float* __restrict__ x2,
                                                   const float* __restrict__ w1,
                                                   const float* __restrict__ w3,
                                                   const int* __restrict__ cnt,
                                                   const int* __restrict__ elist,
                                                   const int* __restrict__ eslot,
                                                   unsigned short* __restrict__ hbuf)
{
    int e = blockIdx.z;
    int c = cnt[e];
    int p0 = blockIdx.y * 64;
    if (p0 >= c) return;
    int i0 = blockIdx.x * 128;
    int tid = threadIdx.x;

    __shared__ char smem[40960];          // A 8K | B1 16K | B3 16K
    char* AsB  = smem;
    char* B1sB = smem + 8192;
    char* B3sB = smem + 24576;
    __shared__ int rowtokS[64];
    __shared__ int rowslotS[64];

    if (tid < 64) {
        int p = min(p0 + tid, c - 1);
        rowtokS[tid]  = elist[e * S_ + p];
        rowslotS[tid] = eslot[e * S_ + p];
    }
    __syncthreads();

    const float* w1e = w1 + (size_t)e * I_ * H_;
    const float* w3e = w3 + (size_t)e * I_ * H_;

    int lane = tid & 63, w = tid >> 6;
    int lm = lane & 15, lk = lane >> 4;
    int sw = (lm & 7) << 4;

    float4 raA[2][2], raB1[4][2], raB3[4][2];

    auto loadAll = [&](int kb) {
#pragma unroll
        for (int it = 0; it < 2; ++it) {
            int g = tid + it * 256; int row = g >> 3, kg = g & 7;
            const float* s = x2 + (size_t)rowtokS[row] * H_ + kb + kg * 8;
            raA[it][0] = *(const float4*)s; raA[it][1] = *(const float4*)(s + 4);
        }
#pragma unroll
        for (int it = 0; it < 4; ++it) {
            int g = tid + it * 256; int row = g >> 3, kg = g & 7;
            size_t off = (size_t)(i0 + row) * H_ + kb + kg * 8;
            const float* s1 = w1e + off;
            const float* s3 = w3e + off;
            raB1[it][0] = *(const float4*)s1; raB1[it][1] = *(const float4*)(s1 + 4);
            raB3[it][0] = *(const float4*)s3; raB3[it][1] = *(const float4*)(s3 + 4);
        }
    };
    auto writeAll = [&]() {
#pragma unroll
        for (int it = 0; it < 2; ++it) {
            int g = tid + it * 256; int row = g >> 3, kg = g & 7;
            int byte = row * 128 + ((kg * 16) ^ ((row & 7) << 4));
            float4 f0 = raA[it][0], f1 = raA[it][1];
            *(int4*)(AsB + byte) = make_int4(pkbf(f0.x, f0.y), pkbf(f0.z, f0.w),
                                             pkbf(f1.x, f1.y), pkbf(f1.z, f1.w));
        }
#pragma unroll
        for (int it = 0; it < 4; ++it) {
            int g = tid + it * 256; int row = g >> 3, kg = g & 7;
            int byte = row * 128 + ((kg * 16) ^ ((row & 7) << 4));
            float4 f0 = raB1[it][0], f1 = raB1[it][1];
            *(int4*)(B1sB + byte) = make_int4(pkbf(f0.x, f0.y), pkbf(f0.z, f0.w),
                                              pkbf(f1.x, f1.y), pkbf(f1.z, f1.w));
            float4 g0 = raB3[it][0], g1 = raB3[it][1];
            *(int4*)(B3sB + byte) = make_int4(pkbf(g0.x, g0.y), pkbf(g0.z, g0.w),
                                              pkbf(g1.x, g1.y), pkbf(g1.z, g1.w));
        }
    };

    f32x4 z = {0.f, 0.f, 0.f, 0.f};
    f32x4 acc1[4][2], acc3[4][2];
#pragma unroll
    for (int mf = 0; mf < 4; ++mf)
#pragma unroll
        for (int nf = 0; nf < 2; ++nf) { acc1[mf][nf] = z; acc3[mf][nf] = z; }

    loadAll(0);
    for (int kt = 0; kt < H_ / 64; ++kt) {
        __syncthreads();
        writeAll();
        __syncthreads();
        if (kt + 1 < H_ / 64) loadAll((kt + 1) * 64);
#pragma unroll
        for (int ks = 0; ks < 2; ++ks) {
            bf16x8 af[4];
#pragma unroll
            for (int mf = 0; mf < 4; ++mf)
                af[mf] = *(const bf16x8*)(AsB + (mf * 16 + lm) * 128 + ((ks * 64 + lk * 16) ^ sw));
#pragma unroll
            for (int nf = 0; nf < 2; ++nf) {
                int bby = (w * 32 + nf * 16 + lm) * 128 + ((ks * 64 + lk * 16) ^ sw);
                bf16x8 b1 = *(const bf16x8*)(B1sB + bby);
                bf16x8 b3 = *(const bf16x8*)(B3sB + bby);
#pragma unroll
                for (int mf = 0; mf < 4; ++mf) {
                    acc1[mf][nf] = __builtin_amdgcn_mfma_f32_16x16x32_bf16(af[mf], b1, acc1[mf][nf], 0, 0, 0);
                    acc3[mf][nf] = __builtin_amdgcn_mfma_f32_16x16x32_bf16(af[mf], b3, acc3[mf][nf], 0, 0, 0);
                }
            }
        }
    }

#pragma unroll
    for (int mf = 0; mf < 4; ++mf)
#pragma unroll
        for (int nf = 0; nf < 2; ++nf) {
            int coli = i0 + w * 32 + nf * 16 + lm;
#pragma unroll
            for (int j = 0; j < 4; ++j) {
                int rloc = mf * 16 + lk * 4 + j;
                if (p0 + rloc < c) {
                    float h1 = acc1[mf][nf][j];
                    float val = h1 / (1.f + __expf(-h1)) * acc3[mf][nf][j];
                    hbuf[(size_t)rowslotS[rloc] * I_ + coli] = f2bf(val);
                }
            }
        }
}

// ---------------- MoE down (bf16 MFMA): 64(M) x 128(N) tile, BK=64. A from bf16 hbuf.
__global__ __launch_bounds__(256) void moe_dn_mfma(const unsigned short* __restrict__ hbuf,
                                                   const float* __restrict__ w2,
                                                   const int* __restrict__ cnt,
                                                   const int* __restrict__ eslot,
                                                   float* __restrict__ dbuf)
{
    int e = blockIdx.z;
    int c = cnt[e];
    int p0 = blockIdx.y * 64;
    if (p0 >= c) return;
    int h0 = blockIdx.x * 128;
    int tid = threadIdx.x;

    __shared__ char smem[24576];          // A 8K | B 16K
    char* AsB = smem;
    char* BsB = smem + 8192;
    __shared__ int rowslotS[64];

    if (tid < 64) rowslotS[tid] = eslot[e * S_ + min(p0 + tid, c - 1)];
    __syncthreads();

    const float* w2e = w2 + (size_t)e * H_ * I_;

    int lane = tid & 63, w = tid >> 6;
    int lm = lane & 15, lk = lane >> 4;
    int sw = (lm & 7) << 4;

    int4 rdA[2];
    float4 rdB[4][2];

    auto loadAll = [&](int kb) {
#pragma unroll
        for (int it = 0; it < 2; ++it) {
            int g = tid + it * 256; int row = g >> 3, kg = g & 7;
            rdA[it] = *(const int4*)(hbuf + (size_t)rowslotS[row] * I_ + kb + kg * 8);
        }
#pragma unroll
        for (int it = 0; it < 4; ++it) {
            int g = tid + it * 256; int row = g >> 3, kg = g & 7;
            const float* s = w2e + (size_t)(h0 + row) * I_ + kb + kg * 8;
            rdB[it][0] = *(const float4*)s; rdB[it][1] = *(const float4*)(s + 4);
        }
    };
    auto writeAll = [&]() {
#pragma unroll
        for (int it = 0; it < 2; ++it) {
            int g = tid + it * 256; int row = g >> 3, kg = g & 7;
            int byte = row * 128 + ((kg * 16) ^ ((row & 7) << 4));
            *(int4*)(AsB + byte) = rdA[it];
        }
#pragma unroll
        for (int it = 0; it < 4; ++it) {
            int g = tid + it * 256; int row = g >> 3, kg = g & 7;
            int byte = row * 128 + ((kg * 16) ^ ((row & 7) << 4));
            float4 f0 = rdB[it][0], f1 = rdB[it][1];
            *(int4*)(BsB + byte) = make_int4(pkbf(f0.x, f0.y), pkbf(f0.z, f0.w),
                                             pkbf(f1.x, f1.y), pkbf(f1.z, f1.w));
        }
    };

    f32x4 z = {0.f, 0.f, 0.f, 0.f};
    f32x4 acc[4][2];
#pragma unroll
    for (int mf = 0; mf < 4; ++mf)
#pragma unroll
        for (int nf = 0; nf < 2; ++nf) acc[mf][nf] = z;

    loadAll(0);
    for (int kt = 0; kt < I_ / 64; ++kt) {
        __syncthreads();
        writeAll();
        __syncthreads();
        if (kt + 1 < I_ / 64) loadAll((kt + 1) * 64);
#pragma unroll
        for (int ks = 0; ks < 2; ++ks) {
            bf16x8 af[4];
#pragma unroll
            for (int mf = 0; mf < 4; ++mf)
                af[mf] = *(const bf16x8*)(AsB + (mf * 16 + lm) * 128 + ((ks * 64 + lk * 16) ^ sw));
#pragma unroll
            for (int nf = 0; nf < 2; ++nf) {
                int bby = (w * 32 + nf * 16 + lm) * 128 + ((ks * 64 + lk * 16) ^ sw);
                bf16x8 bf = *(const bf16x8*)(BsB + bby);
#pragma unroll
                for (int mf = 0; mf < 4; ++mf)
                    acc[mf][nf] = __builtin_amdgcn_mfma_f32_16x16x32_bf16(af[mf], bf, acc[mf][nf], 0, 0, 0);
            }
        }
    }

#pragma unroll
    for (int mf = 0; mf < 4; ++mf)
#pragma unroll
        for (int nf = 0; nf < 2; ++nf) {
            int colh = h0 + w * 32 + nf * 16 + lm;
#pragma unroll
            for (int j = 0; j < 4; ++j) {
                int rloc = mf * 16 + lk * 4 + j;
                if (p0 + rloc < c)
                    dbuf[(size_t)rowslotS[rloc] * H_ + colh] = acc[mf][nf][j];
            }
        }
}

// ---------------- Final combine
__global__ __launch_bounds__(256) void combine_k(const float* __restrict__ hid2,
                                                 const float* __restrict__ dbuf,
                                                 const float* __restrict__ wslot,
                                                 float* __restrict__ out)
{
    int idx = blockIdx.x * 256 + threadIdx.x;
    if (idx >= S_ * H_) return;
    int n = idx >> 10;
    int hcol = idx & (H_ - 1);
    out[idx] = hid2[idx]
             + wslot[2 * n]     * dbuf[(size_t)(2 * n) * H_ + hcol]
             + wslot[2 * n + 1] * dbuf[(size_t)(2 * n + 1) * H_ + hcol];
}

extern "C" void kernel_launch(void* const* d_in, const int* in_sizes, int n_in,
                              void* d_out, int out_size, void* d_ws, size_t ws_size,
                              hipStream_t stream)
{
    const float* hidden = (const float*)d_in[0];
    const float* ln1    = (const float*)d_in[1];
    const float* ln2    = (const float*)d_in[2];
    const float* wq     = (const float*)d_in[3];
    const float* wk     = (const float*)d_in[4];
    const float* wv     = (const float*)d_in[5];
    const float* wo     = (const float*)d_in[6];
    const float* gw     = (const float*)d_in[7];
    const float* w1     = (const float*)d_in[8];
    const float* w2     = (const float*)d_in[9];
    const float* w3     = (const float*)d_in[10];
    float* out = (float*)d_out;

    char* p = (char*)d_ws;
    auto alloc_f = [&](size_t nfloat) { float* r = (float*)p; p += nfloat * sizeof(float); return r; };
    float* xb   = alloc_f((size_t)S_ * H_);
    float* q    = alloc_f((size_t)S_ * NH_ * HD_);
    float* kb   = alloc_f((size_t)S_ * KVH_ * HD_);
    float* vb   = alloc_f((size_t)S_ * KVH_ * HD_);
    float* hid2 = alloc_f((size_t)S_ * H_);
    float* x2   = alloc_f((size_t)S_ * H_);
    unsigned short* hbuf = (unsigned short*)p; p += (size_t)S_ * 2 * I_ * sizeof(unsigned short);
    float* dbuf = alloc_f((size_t)S_ * 2 * H_);
    float* wslot= alloc_f((size_t)S_ * 2);
    int* cnt   = (int*)p; p += E_ * sizeof(int);
    int* elist = (int*)p; p += (size_t)E_ * S_ * sizeof(int);
    int* eslot = (int*)p; p += (size_t)E_ * S_ * sizeof(int);
    float* ctx = xb;

    hipMemsetAsync(cnt, 0, E_ * sizeof(int), stream);

    rmsnorm_k<<<S_, 256, 0, stream>>>(hidden, ln1, xb);
    gemm_nt<<<dim3(16, 32), 256, 0, stream>>>(xb, wq, nullptr, q,  S_, NH_ * HD_, H_);
    gemm_nt<<<dim3(8, 32),  256, 0, stream>>>(xb, wk, nullptr, kb, S_, KVH_ * HD_, H_);
    gemm_nt<<<dim3(8, 32),  256, 0, stream>>>(xb, wv, nullptr, vb, S_, KVH_ * HD_, H_);
    {
        int tot = S_ * (NH_ + KVH_) * (HD_ / 2);
        rope_k<<<SDIV(tot, 256), 256, 0, stream>>>(q, kb);
    }
    attn_tiled<<<dim3(16, 16), 256, 0, stream>>>(q, kb, vb, ctx);
    gemm_nt<<<dim3(16, 32), 256, 0, stream>>>(ctx, wo, hidden, hid2, S_, H_, NH_ * HD_);
    rmsnorm_k<<<S_, 256, 0, stream>>>(hid2, ln2, x2);
    router_k<<<S_, 64, 0, stream>>>(x2, gw, cnt, elist, eslot, wslot);
    moe_up_mfma<<<dim3(I_ / 128, S_ / 64, E_), 256, 0, stream>>>(x2, w1, w3, cnt, elist, eslot, hbuf);
    moe_dn_mfma<<<dim3(H_ / 128, S_ / 64, E_), 256, 0, stream>>>(hbuf, w2, cnt, eslot, dbuf);
    combine_k<<<SDIV(S_ * H_, 256), 256, 0, stream>>>(hid2, dbuf, wslot, out);
}

// Round 4
// 840.501 us; speedup vs baseline: 3.9063x; 1.1429x over previous
//
#include <hip/hip_runtime.h>
#include <hip/hip_bf16.h>
#include <math.h>

constexpr int S_ = 2048, H_ = 1024, NH_ = 16, KVH_ = 8, HD_ = 64;
constexpr int E_ = 8, I_ = 3584;
constexpr float EPS_ = 1e-6f;
constexpr float THETA_ = 1000000.0f;

#define SDIV(a,b) (((a)+(b)-1)/(b))

typedef __attribute__((ext_vector_type(8))) short bf16x8;
typedef __attribute__((ext_vector_type(4))) float f32x4;

__device__ inline unsigned pkbf(float a, float b) {
    unsigned r;
    asm("v_cvt_pk_bf16_f32 %0, %1, %2" : "=v"(r) : "v"(a), "v"(b));
    return r;
}
__device__ inline unsigned short f2bf(float f) {
    unsigned u = __float_as_uint(f);
    u += 0x7FFF + ((u >> 16) & 1);
    return (unsigned short)(u >> 16);
}

// Load 8 weights as 8 packed bf16 (int4): direct if WB, else fp32->bf16 cvt.
template<bool WB>
__device__ inline int4 loadW16(const void* W, size_t elemOff) {
    if constexpr (WB) {
        return *(const int4*)((const unsigned short*)W + elemOff);
    } else {
        const float* s = (const float*)W + elemOff;
        float4 f0 = *(const float4*)s, f1 = *(const float4*)(s + 4);
        return make_int4(pkbf(f0.x, f0.y), pkbf(f0.z, f0.w),
                         pkbf(f1.x, f1.y), pkbf(f1.z, f1.w));
    }
}

// ---------------- fp32 -> bf16 bulk convert (n8 = count/8)
__global__ __launch_bounds__(256) void conv_bf16(const float* __restrict__ in,
                                                 unsigned short* __restrict__ out, long n8)
{
    long i = (long)blockIdx.x * 256 + threadIdx.x;
    long stride = (long)gridDim.x * 256;
    for (; i < n8; i += stride) {
        const float* s = in + i * 8;
        float4 f0 = *(const float4*)s, f1 = *(const float4*)(s + 4);
        *(int4*)(out + i * 8) = make_int4(pkbf(f0.x, f0.y), pkbf(f0.z, f0.w),
                                          pkbf(f1.x, f1.y), pkbf(f1.z, f1.w));
    }
}

// ---------------- RMSNorm
__global__ __launch_bounds__(256) void rmsnorm_k(const float* __restrict__ x,
                                                 const float* __restrict__ w,
                                                 float* __restrict__ out)
{
    int row = blockIdx.x;
    int tid = threadIdx.x;
    const float* xr = x + (size_t)row * H_;
    float4 v = *(const float4*)&xr[tid * 4];
    float ss = v.x*v.x + v.y*v.y + v.z*v.z + v.w*v.w;
#pragma unroll
    for (int off = 32; off > 0; off >>= 1) ss += __shfl_xor(ss, off);
    __shared__ float red[4];
    if ((tid & 63) == 0) red[tid >> 6] = ss;
    __syncthreads();
    float tot = red[0] + red[1] + red[2] + red[3];
    float r = rsqrtf(tot / (float)H_ + EPS_);
    float4 wv = *(const float4*)&w[tid * 4];
    float4 o;
    o.x = v.x * r * wv.x; o.y = v.y * r * wv.y;
    o.z = v.z * r * wv.z; o.w = v.w * r * wv.w;
    *(float4*)&out[(size_t)row * H_ + tid * 4] = o;
}

// ---------------- Dense bf16-MFMA GEMM: C[M,N] = (Res?) + A[M,K]*B[N,K]^T
// 128x128 tile, BK=64, 256 threads (2x2 waves of 64x64). A fp32 (inline cvt).
template<bool WB>
__global__ __launch_bounds__(256) void dense_mfma(const float* __restrict__ A,
                                                  const void* __restrict__ Bw,
                                                  const float* __restrict__ Res,
                                                  float* __restrict__ C,
                                                  int M, int N, int K)
{
    __shared__ char As[16384], Bs[16384];
    int tid = threadIdx.x;
    int m0 = blockIdx.y * 128, n0 = blockIdx.x * 128;
    int lane = tid & 63, w = tid >> 6, wm = w >> 1, wn = w & 1;
    int lm = lane & 15, lk = lane >> 4;

    int4 rA[4], rB[4];
    auto loadAll = [&](int kb) {
#pragma unroll
        for (int it = 0; it < 4; ++it) {
            int g = tid + it * 256, row = g >> 3, kg = g & 7;
            const float* s = A + (size_t)(m0 + row) * K + kb + kg * 8;
            float4 f0 = *(const float4*)s, f1 = *(const float4*)(s + 4);
            rA[it] = make_int4(pkbf(f0.x, f0.y), pkbf(f0.z, f0.w),
                               pkbf(f1.x, f1.y), pkbf(f1.z, f1.w));
            rB[it] = loadW16<WB>(Bw, (size_t)(n0 + row) * K + kb + kg * 8);
        }
    };
    auto writeAll = [&]() {
#pragma unroll
        for (int it = 0; it < 4; ++it) {
            int g = tid + it * 256, row = g >> 3, kg = g & 7;
            int byte = row * 128 + ((kg * 16) ^ ((row & 7) << 4));
            *(int4*)(As + byte) = rA[it];
            *(int4*)(Bs + byte) = rB[it];
        }
    };

    f32x4 z = {0.f, 0.f, 0.f, 0.f};
    f32x4 acc[4][4];
#pragma unroll
    for (int mf = 0; mf < 4; ++mf)
#pragma unroll
        for (int nf = 0; nf < 4; ++nf) acc[mf][nf] = z;

    loadAll(0);
    for (int kt = 0; kt < K / 64; ++kt) {
        __syncthreads();
        writeAll();
        __syncthreads();
        if (kt + 1 < K / 64) loadAll((kt + 1) * 64);
#pragma unroll
        for (int ks = 0; ks < 2; ++ks) {
            bf16x8 af[4];
#pragma unroll
            for (int mf = 0; mf < 4; ++mf) {
                int row = wm * 64 + mf * 16 + lm;
                af[mf] = *(const bf16x8*)(As + row * 128 + ((ks * 64 + lk * 16) ^ ((row & 7) << 4)));
            }
#pragma unroll
            for (int nf = 0; nf < 4; ++nf) {
                int brow = wn * 64 + nf * 16 + lm;
                bf16x8 bf = *(const bf16x8*)(Bs + brow * 128 + ((ks * 64 + lk * 16) ^ ((brow & 7) << 4)));
#pragma unroll
                for (int mf = 0; mf < 4; ++mf)
                    acc[mf][nf] = __builtin_amdgcn_mfma_f32_16x16x32_bf16(af[mf], bf, acc[mf][nf], 0, 0, 0);
            }
        }
    }

#pragma unroll
    for (int mf = 0; mf < 4; ++mf)
#pragma unroll
        for (int nf = 0; nf < 4; ++nf) {
            int col = n0 + wn * 64 + nf * 16 + lm;
#pragma unroll
            for (int j = 0; j < 4; ++j) {
                int row = m0 + wm * 64 + mf * 16 + lk * 4 + j;
                float r = Res ? Res[(size_t)row * N + col] : 0.0f;
                C[(size_t)row * N + col] = acc[mf][nf][j] + r;
            }
        }
}

// ---------------- RoPE
__global__ __launch_bounds__(256) void rope_k(float* __restrict__ q, float* __restrict__ k)
{
    int idx = blockIdx.x * 256 + threadIdx.x;
    const int totq = S_ * NH_ * (HD_ / 2);
    const int tot = totq + S_ * KVH_ * (HD_ / 2);
    if (idx >= tot) return;
    float* base; int s, di;
    if (idx < totq) {
        s = idx / (NH_ * 32); int r = idx % (NH_ * 32);
        base = q + ((size_t)s * NH_ + (r >> 5)) * HD_; di = r & 31;
    } else {
        int j = idx - totq;
        s = j / (KVH_ * 32); int r = j % (KVH_ * 32);
        base = k + ((size_t)s * KVH_ + (r >> 5)) * HD_; di = r & 31;
    }
    float invf = powf(THETA_, -(2.0f * di) / (float)HD_);
    float ang = (float)s * invf;
    float c = cosf(ang), sn = sinf(ang);
    float x0 = base[di], x1 = base[di + 32];
    base[di]      = x0 * c - x1 * sn;
    base[di + 32] = x1 * c + x0 * sn;
}

// ---------------- Tiled flash attention (fp32, unchanged)
__global__ __launch_bounds__(256) void attn_tiled(const float* __restrict__ q,
                                                  const float* __restrict__ k,
                                                  const float* __restrict__ v,
                                                  float* __restrict__ ctx)
{
    __shared__ float Qs[64][68];
    __shared__ float KPs[64][68];
    __shared__ float Vs[64][68];
    int pair = blockIdx.x, h = blockIdx.y;
    int kvh = h >> 1;
    int tid = threadIdx.x;
    int ty = tid >> 4, tx = tid & 15;
    const float scale = 0.125f;

    for (int half = 0; half < 2; ++half) {
        int qb = (half == 0) ? pair : (31 - pair);
        int q0 = qb * 64;

        __syncthreads();
#pragma unroll
        for (int r = 0; r < 4; ++r) {
            int idx = tid + r * 256;
            int qq = idx >> 4, ds = (idx & 15) << 2;
            float4 qv = *(const float4*)&q[((size_t)(q0 + qq) * NH_ + h) * HD_ + ds];
            Qs[ds + 0][qq] = qv.x; Qs[ds + 1][qq] = qv.y;
            Qs[ds + 2][qq] = qv.z; Qs[ds + 3][qq] = qv.w;
        }

        float m_[4], l_[4], o_[4][4];
#pragma unroll
        for (int i = 0; i < 4; ++i) {
            m_[i] = -1e30f; l_[i] = 0.f;
#pragma unroll
            for (int j = 0; j < 4; ++j) o_[i][j] = 0.f;
        }

        for (int t0 = 0; t0 <= q0; t0 += 64) {
            __syncthreads();
#pragma unroll
            for (int r = 0; r < 4; ++r) {
                int idx = tid + r * 256;
                int kk = idx >> 4, ds = (idx & 15) << 2;
                float4 kv = *(const float4*)&k[((size_t)(t0 + kk) * KVH_ + kvh) * HD_ + ds];
                KPs[ds + 0][kk] = kv.x; KPs[ds + 1][kk] = kv.y;
                KPs[ds + 2][kk] = kv.z; KPs[ds + 3][kk] = kv.w;
                float4 vv = *(const float4*)&v[((size_t)(t0 + kk) * KVH_ + kvh) * HD_ + ds];
                *(float4*)&Vs[kk][ds] = vv;
            }
            __syncthreads();

            float s_[4][4] = {};
#pragma unroll 4
            for (int kk = 0; kk < 64; ++kk) {
                float4 a4 = *(const float4*)&Qs[kk][ty << 2];
                float4 b4 = *(const float4*)&KPs[kk][tx << 2];
                float aa[4] = {a4.x, a4.y, a4.z, a4.w};
                float bb[4] = {b4.x, b4.y, b4.z, b4.w};
#pragma unroll
                for (int i = 0; i < 4; ++i)
#pragma unroll
                    for (int j = 0; j < 4; ++j)
                        s_[i][j] = fmaf(aa[i], bb[j], s_[i][j]);
            }
            bool diag = (t0 == q0);
#pragma unroll
            for (int i = 0; i < 4; ++i)
#pragma unroll
                for (int j = 0; j < 4; ++j) {
                    float sv = s_[i][j] * scale;
                    if (diag && (tx * 4 + j > ty * 4 + i)) sv = -1e30f;
                    s_[i][j] = sv;
                }
            float newm[4], resc[4];
#pragma unroll
            for (int i = 0; i < 4; ++i) {
                float rm = fmaxf(fmaxf(s_[i][0], s_[i][1]), fmaxf(s_[i][2], s_[i][3]));
#pragma unroll
                for (int off = 8; off > 0; off >>= 1) rm = fmaxf(rm, __shfl_xor(rm, off));
                newm[i] = fmaxf(m_[i], rm);
                resc[i] = __expf(m_[i] - newm[i]);
                float rs = 0.f;
#pragma unroll
                for (int j = 0; j < 4; ++j) {
                    float p = __expf(s_[i][j] - newm[i]);
                    s_[i][j] = p;
                    rs += p;
                }
#pragma unroll
                for (int off = 8; off > 0; off >>= 1) rs += __shfl_xor(rs, off);
                l_[i] = l_[i] * resc[i] + rs;
                m_[i] = newm[i];
#pragma unroll
                for (int j = 0; j < 4; ++j) o_[i][j] *= resc[i];
            }
            __syncthreads();
#pragma unroll
            for (int i = 0; i < 4; ++i)
#pragma unroll
                for (int j = 0; j < 4; ++j)
                    KPs[tx * 4 + j][ty * 4 + i] = s_[i][j];
            __syncthreads();

#pragma unroll 4
            for (int kk = 0; kk < 64; ++kk) {
                float4 p4 = *(const float4*)&KPs[kk][ty << 2];
                float4 v4 = *(const float4*)&Vs[kk][tx << 2];
                float pp[4] = {p4.x, p4.y, p4.z, p4.w};
                float vv[4] = {v4.x, v4.y, v4.z, v4.w};
#pragma unroll
                for (int i = 0; i < 4; ++i)
#pragma unroll
                    for (int j = 0; j < 4; ++j)
                        o_[i][j] = fmaf(pp[i], vv[j], o_[i][j]);
            }
        }
#pragma unroll
        for (int i = 0; i < 4; ++i) {
            float inv = 1.0f / l_[i];
            float4 st;
            st.x = o_[i][0] * inv; st.y = o_[i][1] * inv;
            st.z = o_[i][2] * inv; st.w = o_[i][3] * inv;
            *(float4*)&ctx[((size_t)(q0 + ty * 4 + i) * NH_ + h) * HD_ + tx * 4] = st;
        }
    }
}

// ---------------- Router
__global__ __launch_bounds__(64) void router_k(const float* __restrict__ x2,
                                               const float* __restrict__ gw,
                                               int* __restrict__ cnt,
                                               int* __restrict__ elist,
                                               int* __restrict__ eslot,
                                               float* __restrict__ wslot)
{
    int n = blockIdx.x, lane = threadIdx.x;
    float part[E_];
#pragma unroll
    for (int e = 0; e < E_; ++e) part[e] = 0.f;
    const float* xr = x2 + (size_t)n * H_;
    for (int j = lane; j < H_; j += 64) {
        float xv = xr[j];
#pragma unroll
        for (int e = 0; e < E_; ++e) part[e] = fmaf(xv, gw[e * H_ + j], part[e]);
    }
#pragma unroll
    for (int e = 0; e < E_; ++e)
#pragma unroll
        for (int off = 32; off > 0; off >>= 1) part[e] += __shfl_xor(part[e], off);
    if (lane == 0) {
        float mx = part[0];
#pragma unroll
        for (int e = 1; e < E_; ++e) mx = fmaxf(mx, part[e]);
        float rw[E_]; float ssum = 0.f;
#pragma unroll
        for (int e = 0; e < E_; ++e) { rw[e] = expf(part[e] - mx); ssum += rw[e]; }
#pragma unroll
        for (int e = 0; e < E_; ++e) rw[e] /= ssum;
        float best = -1.f; int ba = 0, bb = 1;
        for (int a = 0; a < E_; ++a)
            for (int b = a + 1; b < E_; ++b) {
                float scv = rw[a] + rw[b];
                if (scv > best) { best = scv; ba = a; bb = b; }
            }
        float wa = rw[ba], wb = rw[bb], wsum = wa + wb;
        wa /= wsum; wb /= wsum;
        int p = atomicAdd(&cnt[ba], 1);
        elist[ba * S_ + p] = n; eslot[ba * S_ + p] = 2 * n;
        p = atomicAdd(&cnt[bb], 1);
        elist[bb * S_ + p] = n; eslot[bb * S_ + p] = 2 * n + 1;
        wslot[2 * n] = wa; wslot[2 * n + 1] = wb;
    }
}

// ---------------- MoE up (bf16 MFMA): 128(M tokens) x 128(N) tile, BK=64.
template<bool WB>
__global__ __launch_bounds__(256) void moe_up_mfma(const float* __restrict__ x2,
                                                   const void* __restrict__ w1,
                                                   const void* __restrict__ w3,
                                                   const int* __restrict__ cnt,
                                                   const int* __restrict__ elist,
                                                   const int* __restrict__ eslot,
                                                   unsigned short* __restrict__ hbuf)
{
    int e = blockIdx.z;
    int c = cnt[e];
    int p0 = blockIdx.y * 128;
    if (p0 >= c) return;
    int i0 = blockIdx.x * 128;
    int tid = threadIdx.x;

    __shared__ char As[16384], B1s[16384], B3s[16384];
    __shared__ int rowtokS[128], rowslotS[128];
    if (tid < 128) {
        int p = min(p0 + tid, c - 1);
        rowtokS[tid]  = elist[e * S_ + p];
        rowslotS[tid] = eslot[e * S_ + p];
    }
    __syncthreads();

    int lane = tid & 63, w = tid >> 6, wm = w >> 1, wn = w & 1;
    int lm = lane & 15, lk = lane >> 4;
    size_t wbase = (size_t)e * I_ * H_;

    int4 rA[4], rB1[4], rB3[4];
    auto loadAll = [&](int kb) {
#pragma unroll
        for (int it = 0; it < 4; ++it) {
            int g = tid + it * 256, row = g >> 3, kg = g & 7;
            const float* s = x2 + (size_t)rowtokS[row] * H_ + kb + kg * 8;
            float4 f0 = *(const float4*)s, f1 = *(const float4*)(s + 4);
            rA[it] = make_int4(pkbf(f0.x, f0.y), pkbf(f0.z, f0.w),
                               pkbf(f1.x, f1.y), pkbf(f1.z, f1.w));
            size_t off = wbase + (size_t)(i0 + row) * H_ + kb + kg * 8;
            rB1[it] = loadW16<WB>(w1, off);
            rB3[it] = loadW16<WB>(w3, off);
        }
    };
    auto writeAll = [&]() {
#pragma unroll
        for (int it = 0; it < 4; ++it) {
            int g = tid + it * 256, row = g >> 3, kg = g & 7;
            int byte = row * 128 + ((kg * 16) ^ ((row & 7) << 4));
            *(int4*)(As + byte)  = rA[it];
            *(int4*)(B1s + byte) = rB1[it];
            *(int4*)(B3s + byte) = rB3[it];
        }
    };

    f32x4 z = {0.f, 0.f, 0.f, 0.f};
    f32x4 acc1[4][4], acc3[4][4];
#pragma unroll
    for (int mf = 0; mf < 4; ++mf)
#pragma unroll
        for (int nf = 0; nf < 4; ++nf) { acc1[mf][nf] = z; acc3[mf][nf] = z; }

    loadAll(0);
    for (int kt = 0; kt < H_ / 64; ++kt) {
        __syncthreads();
        writeAll();
        __syncthreads();
        if (kt + 1 < H_ / 64) loadAll((kt + 1) * 64);
#pragma unroll
        for (int ks = 0; ks < 2; ++ks) {
            bf16x8 af[4];
#pragma unroll
            for (int mf = 0; mf < 4; ++mf) {
                int row = wm * 64 + mf * 16 + lm;
                af[mf] = *(const bf16x8*)(As + row * 128 + ((ks * 64 + lk * 16) ^ ((row & 7) << 4)));
            }
#pragma unroll
            for (int nf = 0; nf < 4; ++nf) {
                int brow = wn * 64 + nf * 16 + lm;
                int bby = brow * 128 + ((ks * 64 + lk * 16) ^ ((brow & 7) << 4));
                bf16x8 b1 = *(const bf16x8*)(B1s + bby);
                bf16x8 b3 = *(const bf16x8*)(B3s + bby);
#pragma unroll
                for (int mf = 0; mf < 4; ++mf) {
                    acc1[mf][nf] = __builtin_amdgcn_mfma_f32_16x16x32_bf16(af[mf], b1, acc1[mf][nf], 0, 0, 0);
                    acc3[mf][nf] = __builtin_amdgcn_mfma_f32_16x16x32_bf16(af[mf], b3, acc3[mf][nf], 0, 0, 0);
                }
            }
        }
    }

#pragma unroll
    for (int mf = 0; mf < 4; ++mf)
#pragma unroll
        for (int nf = 0; nf < 4; ++nf) {
            int coli = i0 + wn * 64 + nf * 16 + lm;
#pragma unroll
            for (int j = 0; j < 4; ++j) {
                int rloc = wm * 64 + mf * 16 + lk * 4 + j;
                if (p0 + rloc < c) {
                    float h1 = acc1[mf][nf][j];
                    float val = h1 / (1.f + __expf(-h1)) * acc3[mf][nf][j];
                    hbuf[(size_t)rowslotS[rloc] * I_ + coli] = f2bf(val);
                }
            }
        }
}

// ---------------- MoE down (bf16 MFMA): 128 x 128 tile, BK=64, A = bf16 hbuf.
template<bool WB>
__global__ __launch_bounds__(256) void moe_dn_mfma(const unsigned short* __restrict__ hbuf,
                                                   const void* __restrict__ w2,
                                                   const int* __restrict__ cnt,
                                                   const int* __restrict__ eslot,
                                                   float* __restrict__ dbuf)
{
    int e = blockIdx.z;
    int c = cnt[e];
    int p0 = blockIdx.y * 128;
    if (p0 >= c) return;
    int h0 = blockIdx.x * 128;
    int tid = threadIdx.x;

    __shared__ char As[16384], Bs[16384];
    __shared__ int rowslotS[128];
    if (tid < 128) rowslotS[tid] = eslot[e * S_ + min(p0 + tid, c - 1)];
    __syncthreads();

    int lane = tid & 63, w = tid >> 6, wm = w >> 1, wn = w & 1;
    int lm = lane & 15, lk = lane >> 4;
    size_t wbase = (size_t)e * H_ * I_;

    int4 rA[4], rB[4];
    auto loadAll = [&](int kb) {
#pragma unroll
        for (int it = 0; it < 4; ++it) {
            int g = tid + it * 256, row = g >> 3, kg = g & 7;
            rA[it] = *(const int4*)(hbuf + (size_t)rowslotS[row] * I_ + kb + kg * 8);
            rB[it] = loadW16<WB>(w2, wbase + (size_t)(h0 + row) * I_ + kb + kg * 8);
        }
    };
    auto writeAll = [&]() {
#pragma unroll
        for (int it = 0; it < 4; ++it) {
            int g = tid + it * 256, row = g >> 3, kg = g & 7;
            int byte = row * 128 + ((kg * 16) ^ ((row & 7) << 4));
            *(int4*)(As + byte) = rA[it];
            *(int4*)(Bs + byte) = rB[it];
        }
    };

    f32x4 z = {0.f, 0.f, 0.f, 0.f};
    f32x4 acc[4][4];
#pragma unroll
    for (int mf = 0; mf < 4; ++mf)
#pragma unroll
        for (int nf = 0; nf < 4; ++nf) acc[mf][nf] = z;

    loadAll(0);
    for (int kt = 0; kt < I_ / 64; ++kt) {
        __syncthreads();
        writeAll();
        __syncthreads();
        if (kt + 1 < I_ / 64) loadAll((kt + 1) * 64);
#pragma unroll
        for (int ks = 0; ks < 2; ++ks) {
            bf16x8 af[4];
#pragma unroll
            for (int mf = 0; mf < 4; ++mf) {
                int row = wm * 64 + mf * 16 + lm;
                af[mf] = *(const bf16x8*)(As + row * 128 + ((ks * 64 + lk * 16) ^ ((row & 7) << 4)));
            }
#pragma unroll
            for (int nf = 0; nf < 4; ++nf) {
                int brow = wn * 64 + nf * 16 + lm;
                bf16x8 bf = *(const bf16x8*)(Bs + brow * 128 + ((ks * 64 + lk * 16) ^ ((brow & 7) << 4)));
#pragma unroll
                for (int mf = 0; mf < 4; ++mf)
                    acc[mf][nf] = __builtin_amdgcn_mfma_f32_16x16x32_bf16(af[mf], bf, acc[mf][nf], 0, 0, 0);
            }
        }
    }

#pragma unroll
    for (int mf = 0; mf < 4; ++mf)
#pragma unroll
        for (int nf = 0; nf < 4; ++nf) {
            int colh = h0 + wn * 64 + nf * 16 + lm;
#pragma unroll
            for (int j = 0; j < 4; ++j) {
                int rloc = wm * 64 + mf * 16 + lk * 4 + j;
                if (p0 + rloc < c)
                    dbuf[(size_t)rowslotS[rloc] * H_ + colh] = acc[mf][nf][j];
            }
        }
}

// ---------------- Final combine
__global__ __launch_bounds__(256) void combine_k(const float* __restrict__ hid2,
                                                 const float* __restrict__ dbuf,
                                                 const float* __restrict__ wslot,
                                                 float* __restrict__ out)
{
    int idx = blockIdx.x * 256 + threadIdx.x;
    if (idx >= S_ * H_) return;
    int n = idx >> 10;
    int hcol = idx & (H_ - 1);
    out[idx] = hid2[idx]
             + wslot[2 * n]     * dbuf[(size_t)(2 * n) * H_ + hcol]
             + wslot[2 * n + 1] * dbuf[(size_t)(2 * n + 1) * H_ + hcol];
}

extern "C" void kernel_launch(void* const* d_in, const int* in_sizes, int n_in,
                              void* d_out, int out_size, void* d_ws, size_t ws_size,
                              hipStream_t stream)
{
    const float* hidden = (const float*)d_in[0];
    const float* ln1    = (const float*)d_in[1];
    const float* ln2    = (const float*)d_in[2];
    const float* wq     = (const float*)d_in[3];
    const float* wk     = (const float*)d_in[4];
    const float* wv     = (const float*)d_in[5];
    const float* wo     = (const float*)d_in[6];
    const float* gw     = (const float*)d_in[7];
    const float* w1     = (const float*)d_in[8];
    const float* w2     = (const float*)d_in[9];
    const float* w3     = (const float*)d_in[10];
    float* out = (float*)d_out;

    char* p = (char*)d_ws;
    auto alignp = [&]() { p = (char*)(((uintptr_t)p + 255) & ~(uintptr_t)255); };
    auto alloc_f = [&](size_t n) { alignp(); float* r = (float*)p; p += n * 4; return r; };
    auto alloc_h = [&](size_t n) { alignp(); unsigned short* r = (unsigned short*)p; p += n * 2; return r; };
    auto alloc_i = [&](size_t n) { alignp(); int* r = (int*)p; p += n * 4; return r; };

    float* xb   = alloc_f((size_t)S_ * H_);
    float* q    = alloc_f((size_t)S_ * NH_ * HD_);
    float* kb   = alloc_f((size_t)S_ * KVH_ * HD_);
    float* vb   = alloc_f((size_t)S_ * KVH_ * HD_);
    float* hid2 = alloc_f((size_t)S_ * H_);
    float* x2   = alloc_f((size_t)S_ * H_);
    unsigned short* hbuf = alloc_h((size_t)S_ * 2 * I_);
    float* dbuf = alloc_f((size_t)S_ * 2 * H_);
    float* wslot= alloc_f((size_t)S_ * 2);
    int* cnt   = alloc_i(E_);
    int* elist = alloc_i((size_t)E_ * S_);
    int* eslot = alloc_i((size_t)E_ * S_);
    float* ctx = xb;

    size_t used = (size_t)(p - (char*)d_ws);
    const size_t nW = (size_t)E_ * I_ * H_;               // per MoE weight tensor
    size_t wbf_bytes = (3 * nW + (size_t)(NH_*HD_ + 2*KVH_*HD_ + H_) * H_) * 2 + 4096;
    bool WB = ws_size > used && (ws_size - used) >= wbf_bytes;

    unsigned short *w1b = nullptr, *w3b = nullptr, *w2b = nullptr;
    unsigned short *wqb = nullptr, *wkb = nullptr, *wvb = nullptr, *wob = nullptr;
    if (WB) {
        w1b = alloc_h(nW); w3b = alloc_h(nW); w2b = alloc_h(nW);
        wqb = alloc_h((size_t)NH_ * HD_ * H_);
        wkb = alloc_h((size_t)KVH_ * HD_ * H_);
        wvb = alloc_h((size_t)KVH_ * HD_ * H_);
        wob = alloc_h((size_t)H_ * NH_ * HD_);
    }

    hipMemsetAsync(cnt, 0, E_ * sizeof(int), stream);

    if (WB) {
        conv_bf16<<<2048, 256, 0, stream>>>(w1, w1b, (long)(nW / 8));
        conv_bf16<<<2048, 256, 0, stream>>>(w3, w3b, (long)(nW / 8));
        conv_bf16<<<2048, 256, 0, stream>>>(w2, w2b, (long)(nW / 8));
        conv_bf16<<<512, 256, 0, stream>>>(wq, wqb, (long)((size_t)NH_*HD_*H_ / 8));
        conv_bf16<<<512, 256, 0, stream>>>(wk, wkb, (long)((size_t)KVH_*HD_*H_ / 8));
        conv_bf16<<<512, 256, 0, stream>>>(wv, wvb, (long)((size_t)KVH_*HD_*H_ / 8));
        conv_bf16<<<512, 256, 0, stream>>>(wo, wob, (long)((size_t)H_*NH_*HD_ / 8));
    }

    rmsnorm_k<<<S_, 256, 0, stream>>>(hidden, ln1, xb);

    if (WB) {
        dense_mfma<true><<<dim3(8, 16),  256, 0, stream>>>(xb, wqb, nullptr, q,  S_, NH_ * HD_, H_);
        dense_mfma<true><<<dim3(4, 16),  256, 0, stream>>>(xb, wkb, nullptr, kb, S_, KVH_ * HD_, H_);
        dense_mfma<true><<<dim3(4, 16),  256, 0, stream>>>(xb, wvb, nullptr, vb, S_, KVH_ * HD_, H_);
    } else {
        dense_mfma<false><<<dim3(8, 16), 256, 0, stream>>>(xb, wq, nullptr, q,  S_, NH_ * HD_, H_);
        dense_mfma<false><<<dim3(4, 16), 256, 0, stream>>>(xb, wk, nullptr, kb, S_, KVH_ * HD_, H_);
        dense_mfma<false><<<dim3(4, 16), 256, 0, stream>>>(xb, wv, nullptr, vb, S_, KVH_ * HD_, H_);
    }
    {
        int tot = S_ * (NH_ + KVH_) * (HD_ / 2);
        rope_k<<<SDIV(tot, 256), 256, 0, stream>>>(q, kb);
    }
    attn_tiled<<<dim3(16, 16), 256, 0, stream>>>(q, kb, vb, ctx);
    if (WB)
        dense_mfma<true><<<dim3(8, 16),  256, 0, stream>>>(ctx, wob, hidden, hid2, S_, H_, NH_ * HD_);
    else
        dense_mfma<false><<<dim3(8, 16), 256, 0, stream>>>(ctx, wo, hidden, hid2, S_, H_, NH_ * HD_);

    rmsnorm_k<<<S_, 256, 0, stream>>>(hid2, ln2, x2);
    router_k<<<S_, 64, 0, stream>>>(x2, gw, cnt, elist, eslot, wslot);

    if (WB) {
        moe_up_mfma<true><<<dim3(I_ / 128, S_ / 128, E_), 256, 0, stream>>>(x2, w1b, w3b, cnt, elist, eslot, hbuf);
        moe_dn_mfma<true><<<dim3(H_ / 128, S_ / 128, E_), 256, 0, stream>>>(hbuf, w2b, cnt, eslot, dbuf);
    } else {
        moe_up_mfma<false><<<dim3(I_ / 128, S_ / 128, E_), 256, 0, stream>>>(x2, w1, w3, cnt, elist, eslot, hbuf);
        moe_dn_mfma<false><<<dim3(H_ / 128, S_ / 128, E_), 256, 0, stream>>>(hbuf, w2, cnt, eslot, dbuf);
    }
    combine_k<<<SDIV(S_ * H_, 256), 256, 0, stream>>>(hid2, dbuf, wslot, out);
}

// Round 5
// 714.497 us; speedup vs baseline: 4.5951x; 1.1764x over previous
//
#include <hip/hip_runtime.h>
#include <hip/hip_bf16.h>
#include <math.h>

constexpr int S_ = 2048, H_ = 1024, NH_ = 16, KVH_ = 8, HD_ = 64;
constexpr int E_ = 8, I_ = 3584;
constexpr float EPS_ = 1e-6f;
constexpr float THETA_ = 1000000.0f;

#define SDIV(a,b) (((a)+(b)-1)/(b))

typedef __attribute__((ext_vector_type(8))) short bf16x8;
typedef __attribute__((ext_vector_type(4))) float f32x4;

__device__ inline unsigned pkbf(float a, float b) {
    unsigned r;
    asm("v_cvt_pk_bf16_f32 %0, %1, %2" : "=v"(r) : "v"(a), "v"(b));
    return r;
}
__device__ inline unsigned short f2bf(float f) {
    unsigned u = __float_as_uint(f);
    u += 0x7FFF + ((u >> 16) & 1);
    return (unsigned short)(u >> 16);
}

template<bool WB>
__device__ inline int4 loadW16(const void* W, size_t elemOff) {
    if constexpr (WB) {
        return *(const int4*)((const unsigned short*)W + elemOff);
    } else {
        const float* s = (const float*)W + elemOff;
        float4 f0 = *(const float4*)s, f1 = *(const float4*)(s + 4);
        return make_int4(pkbf(f0.x, f0.y), pkbf(f0.z, f0.w),
                         pkbf(f1.x, f1.y), pkbf(f1.z, f1.w));
    }
}

// ---------------- fp32 -> bf16 bulk convert
__global__ __launch_bounds__(256) void conv_bf16(const float* __restrict__ in,
                                                 unsigned short* __restrict__ out, long n8)
{
    long i = (long)blockIdx.x * 256 + threadIdx.x;
    long stride = (long)gridDim.x * 256;
    for (; i < n8; i += stride) {
        const float* s = in + i * 8;
        float4 f0 = *(const float4*)s, f1 = *(const float4*)(s + 4);
        *(int4*)(out + i * 8) = make_int4(pkbf(f0.x, f0.y), pkbf(f0.z, f0.w),
                                          pkbf(f1.x, f1.y), pkbf(f1.z, f1.w));
    }
}

// ---------------- RMSNorm
__global__ __launch_bounds__(256) void rmsnorm_k(const float* __restrict__ x,
                                                 const float* __restrict__ w,
                                                 float* __restrict__ out)
{
    int row = blockIdx.x;
    int tid = threadIdx.x;
    const float* xr = x + (size_t)row * H_;
    float4 v = *(const float4*)&xr[tid * 4];
    float ss = v.x*v.x + v.y*v.y + v.z*v.z + v.w*v.w;
#pragma unroll
    for (int off = 32; off > 0; off >>= 1) ss += __shfl_xor(ss, off);
    __shared__ float red[4];
    if ((tid & 63) == 0) red[tid >> 6] = ss;
    __syncthreads();
    float tot = red[0] + red[1] + red[2] + red[3];
    float r = rsqrtf(tot / (float)H_ + EPS_);
    float4 wv = *(const float4*)&w[tid * 4];
    float4 o;
    o.x = v.x * r * wv.x; o.y = v.y * r * wv.y;
    o.z = v.z * r * wv.z; o.w = v.w * r * wv.w;
    *(float4*)&out[(size_t)row * H_ + tid * 4] = o;
}

// ---------------- Dense bf16-MFMA GEMM: C[M,N] = (Res?) + A[M,K]*B[N,K]^T
template<bool WB>
__global__ __launch_bounds__(256) void dense_mfma(const float* __restrict__ A,
                                                  const void* __restrict__ Bw,
                                                  const float* __restrict__ Res,
                                                  float* __restrict__ C,
                                                  int M, int N, int K)
{
    __shared__ char As[16384], Bs[16384];
    int tid = threadIdx.x;
    int m0 = blockIdx.y * 128, n0 = blockIdx.x * 128;
    int lane = tid & 63, w = tid >> 6, wm = w >> 1, wn = w & 1;
    int lm = lane & 15, lk = lane >> 4;

    int4 rA[4], rB[4];
    auto loadAll = [&](int kb) {
#pragma unroll
        for (int it = 0; it < 4; ++it) {
            int g = tid + it * 256, row = g >> 3, kg = g & 7;
            const float* s = A + (size_t)(m0 + row) * K + kb + kg * 8;
            float4 f0 = *(const float4*)s, f1 = *(const float4*)(s + 4);
            rA[it] = make_int4(pkbf(f0.x, f0.y), pkbf(f0.z, f0.w),
                               pkbf(f1.x, f1.y), pkbf(f1.z, f1.w));
            rB[it] = loadW16<WB>(Bw, (size_t)(n0 + row) * K + kb + kg * 8);
        }
    };
    auto writeAll = [&]() {
#pragma unroll
        for (int it = 0; it < 4; ++it) {
            int g = tid + it * 256, row = g >> 3, kg = g & 7;
            int byte = row * 128 + ((kg * 16) ^ ((row & 7) << 4));
            *(int4*)(As + byte) = rA[it];
            *(int4*)(Bs + byte) = rB[it];
        }
    };

    f32x4 z = {0.f, 0.f, 0.f, 0.f};
    f32x4 acc[4][4];
#pragma unroll
    for (int mf = 0; mf < 4; ++mf)
#pragma unroll
        for (int nf = 0; nf < 4; ++nf) acc[mf][nf] = z;

    loadAll(0);
    for (int kt = 0; kt < K / 64; ++kt) {
        __syncthreads();
        writeAll();
        __syncthreads();
        if (kt + 1 < K / 64) loadAll((kt + 1) * 64);
#pragma unroll
        for (int ks = 0; ks < 2; ++ks) {
            bf16x8 af[4];
#pragma unroll
            for (int mf = 0; mf < 4; ++mf) {
                int row = wm * 64 + mf * 16 + lm;
                af[mf] = *(const bf16x8*)(As + row * 128 + ((ks * 64 + lk * 16) ^ ((row & 7) << 4)));
            }
#pragma unroll
            for (int nf = 0; nf < 4; ++nf) {
                int brow = wn * 64 + nf * 16 + lm;
                bf16x8 bf = *(const bf16x8*)(Bs + brow * 128 + ((ks * 64 + lk * 16) ^ ((brow & 7) << 4)));
#pragma unroll
                for (int mf = 0; mf < 4; ++mf)
                    acc[mf][nf] = __builtin_amdgcn_mfma_f32_16x16x32_bf16(af[mf], bf, acc[mf][nf], 0, 0, 0);
            }
        }
    }

#pragma unroll
    for (int mf = 0; mf < 4; ++mf)
#pragma unroll
        for (int nf = 0; nf < 4; ++nf) {
            int col = n0 + wn * 64 + nf * 16 + lm;
#pragma unroll
            for (int j = 0; j < 4; ++j) {
                int row = m0 + wm * 64 + mf * 16 + lk * 4 + j;
                float r = Res ? Res[(size_t)row * N + col] : 0.0f;
                C[(size_t)row * N + col] = acc[mf][nf][j] + r;
            }
        }
}

// ---------------- RoPE + bf16 convert. Q pre-scaled by 1/sqrt(HD).
__global__ __launch_bounds__(256) void rope_conv(const float* __restrict__ q,
                                                 const float* __restrict__ k,
                                                 unsigned short* __restrict__ qbf,
                                                 unsigned short* __restrict__ kbf)
{
    int idx = blockIdx.x * 256 + threadIdx.x;
    const int totq = S_ * NH_ * 32;
    const int tot = totq + S_ * KVH_ * 32;
    if (idx >= tot) return;
    const float* base; unsigned short* obase; int s, di; float sc;
    if (idx < totq) {
        s = idx / (NH_ * 32); int r = idx % (NH_ * 32);
        size_t o = ((size_t)s * NH_ + (r >> 5)) * HD_;
        base = q + o; obase = qbf + o; di = r & 31; sc = 0.125f;
    } else {
        int j2 = idx - totq;
        s = j2 / (KVH_ * 32); int r = j2 % (KVH_ * 32);
        size_t o = ((size_t)s * KVH_ + (r >> 5)) * HD_;
        base = k + o; obase = kbf + o; di = r & 31; sc = 1.0f;
    }
    float invf = powf(THETA_, -(2.0f * di) / (float)HD_);
    float ang = (float)s * invf;
    float c = cosf(ang), sn = sinf(ang);
    float x0 = base[di], x1 = base[di + 32];
    obase[di]      = f2bf((x0 * c - x1 * sn) * sc);
    obase[di + 32] = f2bf((x1 * c + x0 * sn) * sc);
}

// ---------------- V transpose: vtb[kvh][d][t0+slot] = bf16(V[t0+key][kvh][d])
// slot = (key&15)*4 + (key>>4)  (matches P-fragment slot permutation)
__global__ __launch_bounds__(256) void v_trans(const float* __restrict__ v,
                                               unsigned short* __restrict__ vtb)
{
    int t0 = blockIdx.x * 64, kvh = blockIdx.y;
    __shared__ unsigned short T[64][64];
    int tid = threadIdx.x;
    int k = tid >> 2, d0 = (tid & 3) * 16;
    const float* src = v + ((size_t)(t0 + k) * KVH_ + kvh) * HD_ + d0;
#pragma unroll
    for (int x = 0; x < 4; ++x) {
        float4 f = *(const float4*)(src + x * 4);
        T[k][d0 + x*4 + 0] = f2bf(f.x);
        T[k][d0 + x*4 + 1] = f2bf(f.y);
        T[k][d0 + x*4 + 2] = f2bf(f.z);
        T[k][d0 + x*4 + 3] = f2bf(f.w);
    }
    __syncthreads();
    int d = tid >> 2, s0 = (tid & 3) * 16;
    unsigned short tmp[16] __attribute__((aligned(16)));
#pragma unroll
    for (int x = 0; x < 16; ++x) {
        int s = s0 + x;
        int key = 16 * (s & 3) + (s >> 2);
        tmp[x] = T[key][d];
    }
    unsigned short* dst = vtb + ((size_t)kvh * HD_ + d) * S_ + t0 + s0;
    *(int4*)(dst)     = *(int4*)(tmp);
    *(int4*)(dst + 8) = *(int4*)(tmp + 8);
}

// ---------------- MFMA flash attention.
// Grid (16 pairs, NH, 2): qb = z? 31-pair : pair. 256 thr = 4 waves, wave owns 16 queries.
// Q/K fragments direct from global bf16; P via per-wave 2KB LDS (no barriers).
__global__ __launch_bounds__(256) void attn_mfma(const unsigned short* __restrict__ qbf,
                                                 const unsigned short* __restrict__ kbf,
                                                 const unsigned short* __restrict__ vtb,
                                                 float* __restrict__ ctx)
{
    __shared__ char Ps[4 * 2048];
    int pair = blockIdx.x, h = blockIdx.y, z = blockIdx.z;
    int qb = z ? (31 - pair) : pair;
    int q0 = qb * 64;
    int kvh = h >> 1;
    int tid = threadIdx.x;
    int w = tid >> 6, lane = tid & 63;
    int lm = lane & 15, lk = lane >> 4;
    char* myP = Ps + w * 2048;

    bf16x8 qf[2];
    const unsigned short* qrow = qbf + ((size_t)(q0 + w * 16 + lm) * NH_ + h) * HD_;
#pragma unroll
    for (int ks = 0; ks < 2; ++ks)
        qf[ks] = *(const bf16x8*)(qrow + ks * 32 + lk * 8);

    float m_[4], l_[4];
    f32x4 o_[4];
#pragma unroll
    for (int j = 0; j < 4; ++j) { m_[j] = -1e30f; l_[j] = 0.f; }
    f32x4 zf = {0.f, 0.f, 0.f, 0.f};
#pragma unroll
    for (int nd = 0; nd < 4; ++nd) o_[nd] = zf;

    for (int t0 = 0; t0 <= q0; t0 += 64) {
        // ---- S = Q K^T (pre-scaled)
        f32x4 s[4];
#pragma unroll
        for (int nf = 0; nf < 4; ++nf) {
            const unsigned short* krow = kbf + ((size_t)(t0 + nf * 16 + lm) * KVH_ + kvh) * HD_;
            bf16x8 k0 = *(const bf16x8*)(krow + lk * 8);
            bf16x8 k1 = *(const bf16x8*)(krow + 32 + lk * 8);
            f32x4 acc = zf;
            acc = __builtin_amdgcn_mfma_f32_16x16x32_bf16(qf[0], k0, acc, 0, 0, 0);
            acc = __builtin_amdgcn_mfma_f32_16x16x32_bf16(qf[1], k1, acc, 0, 0, 0);
            s[nf] = acc;
        }
        if (t0 == q0) {
#pragma unroll
            for (int nf = 0; nf < 4; ++nf)
#pragma unroll
                for (int j = 0; j < 4; ++j) {
                    int key = nf * 16 + lm, qq = w * 16 + lk * 4 + j;
                    if (key > qq) s[nf][j] = -1e30f;
                }
        }
        // ---- online softmax (reduce across the 16-lane key group)
        float p_[4][4];
#pragma unroll
        for (int j = 0; j < 4; ++j) {
            float mx = fmaxf(fmaxf(s[0][j], s[1][j]), fmaxf(s[2][j], s[3][j]));
#pragma unroll
            for (int off = 8; off > 0; off >>= 1) mx = fmaxf(mx, __shfl_xor(mx, off));
            float nm = fmaxf(m_[j], mx);
            float rs = __expf(m_[j] - nm);
            float sum = 0.f;
#pragma unroll
            for (int nf = 0; nf < 4; ++nf) {
                float pv = __expf(s[nf][j] - nm);
                p_[nf][j] = pv; sum += pv;
            }
#pragma unroll
            for (int off = 8; off > 0; off >>= 1) sum += __shfl_xor(sum, off);
            l_[j] = l_[j] * rs + sum;
            m_[j] = nm;
#pragma unroll
            for (int nd = 0; nd < 4; ++nd) o_[nd][j] *= rs;
        }
        // ---- write P (permuted slots: slot = (key&15)*4 + key>>4; XOR row swizzle)
#pragma unroll
        for (int j = 0; j < 4; ++j) {
            int r = lk * 4 + j;
            unsigned lo = pkbf(p_[0][j], p_[1][j]);
            unsigned hi = pkbf(p_[2][j], p_[3][j]);
            int byte = (lm * 8) ^ ((r & 7) << 4);
            *(uint2*)(myP + r * 128 + byte) = make_uint2(lo, hi);
        }
        // ---- O += P V
#pragma unroll
        for (int ks = 0; ks < 2; ++ks) {
            int byte = (ks * 64 + lk * 16) ^ ((lm & 7) << 4);
            bf16x8 pA = *(const bf16x8*)(myP + lm * 128 + byte);
#pragma unroll
            for (int nd = 0; nd < 4; ++nd) {
                const unsigned short* vrow = vtb + ((size_t)kvh * HD_ + nd * 16 + lm) * S_ + t0 + ks * 32 + lk * 8;
                bf16x8 vB = *(const bf16x8*)vrow;
                o_[nd] = __builtin_amdgcn_mfma_f32_16x16x32_bf16(pA, vB, o_[nd], 0, 0, 0);
            }
        }
    }
#pragma unroll
    for (int nd = 0; nd < 4; ++nd)
#pragma unroll
        for (int j = 0; j < 4; ++j) {
            int r = lk * 4 + j;
            ctx[((size_t)(q0 + w * 16 + r) * NH_ + h) * HD_ + nd * 16 + lm] = o_[nd][j] / l_[j];
        }
}

// ---------------- Router
__global__ __launch_bounds__(64) void router_k(const float* __restrict__ x2,
                                               const float* __restrict__ gw,
                                               int* __restrict__ cnt,
                                               int* __restrict__ elist,
                                               int* __restrict__ eslot,
                                               float* __restrict__ wslot)
{
    int n = blockIdx.x, lane = threadIdx.x;
    float part[E_];
#pragma unroll
    for (int e = 0; e < E_; ++e) part[e] = 0.f;
    const float* xr = x2 + (size_t)n * H_;
    for (int j = lane; j < H_; j += 64) {
        float xv = xr[j];
#pragma unroll
        for (int e = 0; e < E_; ++e) part[e] = fmaf(xv, gw[e * H_ + j], part[e]);
    }
#pragma unroll
    for (int e = 0; e < E_; ++e)
#pragma unroll
        for (int off = 32; off > 0; off >>= 1) part[e] += __shfl_xor(part[e], off);
    if (lane == 0) {
        float mx = part[0];
#pragma unroll
        for (int e = 1; e < E_; ++e) mx = fmaxf(mx, part[e]);
        float rw[E_]; float ssum = 0.f;
#pragma unroll
        for (int e = 0; e < E_; ++e) { rw[e] = expf(part[e] - mx); ssum += rw[e]; }
#pragma unroll
        for (int e = 0; e < E_; ++e) rw[e] /= ssum;
        float best = -1.f; int ba = 0, bb = 1;
        for (int a = 0; a < E_; ++a)
            for (int b = a + 1; b < E_; ++b) {
                float scv = rw[a] + rw[b];
                if (scv > best) { best = scv; ba = a; bb = b; }
            }
        float wa = rw[ba], wb = rw[bb], wsum = wa + wb;
        wa /= wsum; wb /= wsum;
        int p = atomicAdd(&cnt[ba], 1);
        elist[ba * S_ + p] = n; eslot[ba * S_ + p] = 2 * n;
        p = atomicAdd(&cnt[bb], 1);
        elist[bb * S_ + p] = n; eslot[bb * S_ + p] = 2 * n + 1;
        wslot[2 * n] = wa; wslot[2 * n + 1] = wb;
    }
}

// ---------------- MoE up (bf16 MFMA)
template<bool WB>
__global__ __launch_bounds__(256) void moe_up_mfma(const float* __restrict__ x2,
                                                   const void* __restrict__ w1,
                                                   const void* __restrict__ w3,
                                                   const int* __restrict__ cnt,
                                                   const int* __restrict__ elist,
                                                   const int* __restrict__ eslot,
                                                   unsigned short* __restrict__ hbuf)
{
    int e = blockIdx.z;
    int c = cnt[e];
    int p0 = blockIdx.y * 128;
    if (p0 >= c) return;
    int i0 = blockIdx.x * 128;
    int tid = threadIdx.x;

    __shared__ char As[16384], B1s[16384], B3s[16384];
    __shared__ int rowtokS[128], rowslotS[128];
    if (tid < 128) {
        int p = min(p0 + tid, c - 1);
        rowtokS[tid]  = elist[e * S_ + p];
        rowslotS[tid] = eslot[e * S_ + p];
    }
    __syncthreads();

    int lane = tid & 63, w = tid >> 6, wm = w >> 1, wn = w & 1;
    int lm = lane & 15, lk = lane >> 4;
    size_t wbase = (size_t)e * I_ * H_;

    int4 rA[4], rB1[4], rB3[4];
    auto loadAll = [&](int kb) {
#pragma unroll
        for (int it = 0; it < 4; ++it) {
            int g = tid + it * 256, row = g >> 3, kg = g & 7;
            const float* s = x2 + (size_t)rowtokS[row] * H_ + kb + kg * 8;
            float4 f0 = *(const float4*)s, f1 = *(const float4*)(s + 4);
            rA[it] = make_int4(pkbf(f0.x, f0.y), pkbf(f0.z, f0.w),
                               pkbf(f1.x, f1.y), pkbf(f1.z, f1.w));
            size_t off = wbase + (size_t)(i0 + row) * H_ + kb + kg * 8;
            rB1[it] = loadW16<WB>(w1, off);
            rB3[it] = loadW16<WB>(w3, off);
        }
    };
    auto writeAll = [&]() {
#pragma unroll
        for (int it = 0; it < 4; ++it) {
            int g = tid + it * 256, row = g >> 3, kg = g & 7;
            int byte = row * 128 + ((kg * 16) ^ ((row & 7) << 4));
            *(int4*)(As + byte)  = rA[it];
            *(int4*)(B1s + byte) = rB1[it];
            *(int4*)(B3s + byte) = rB3[it];
        }
    };

    f32x4 z = {0.f, 0.f, 0.f, 0.f};
    f32x4 acc1[4][4], acc3[4][4];
#pragma unroll
    for (int mf = 0; mf < 4; ++mf)
#pragma unroll
        for (int nf = 0; nf < 4; ++nf) { acc1[mf][nf] = z; acc3[mf][nf] = z; }

    loadAll(0);
    for (int kt = 0; kt < H_ / 64; ++kt) {
        __syncthreads();
        writeAll();
        __syncthreads();
        if (kt + 1 < H_ / 64) loadAll((kt + 1) * 64);
#pragma unroll
        for (int ks = 0; ks < 2; ++ks) {
            bf16x8 af[4];
#pragma unroll
            for (int mf = 0; mf < 4; ++mf) {
                int row = wm * 64 + mf * 16 + lm;
                af[mf] = *(const bf16x8*)(As + row * 128 + ((ks * 64 + lk * 16) ^ ((row & 7) << 4)));
            }
#pragma unroll
            for (int nf = 0; nf < 4; ++nf) {
                int brow = wn * 64 + nf * 16 + lm;
                int bby = brow * 128 + ((ks * 64 + lk * 16) ^ ((brow & 7) << 4));
                bf16x8 b1 = *(const bf16x8*)(B1s + bby);
                bf16x8 b3 = *(const bf16x8*)(B3s + bby);
#pragma unroll
                for (int mf = 0; mf < 4; ++mf) {
                    acc1[mf][nf] = __builtin_amdgcn_mfma_f32_16x16x32_bf16(af[mf], b1, acc1[mf][nf], 0, 0, 0);
                    acc3[mf][nf] = __builtin_amdgcn_mfma_f32_16x16x32_bf16(af[mf], b3, acc3[mf][nf], 0, 0, 0);
                }
            }
        }
    }

#pragma unroll
    for (int mf = 0; mf < 4; ++mf)
#pragma unroll
        for (int nf = 0; nf < 4; ++nf) {
            int coli = i0 + wn * 64 + nf * 16 + lm;
#pragma unroll
            for (int j = 0; j < 4; ++j) {
                int rloc = wm * 64 + mf * 16 + lk * 4 + j;
                if (p0 + rloc < c) {
                    float h1 = acc1[mf][nf][j];
                    float val = h1 / (1.f + __expf(-h1)) * acc3[mf][nf][j];
                    hbuf[(size_t)rowslotS[rloc] * I_ + coli] = f2bf(val);
                }
            }
        }
}

// ---------------- MoE down (bf16 MFMA)
template<bool WB>
__global__ __launch_bounds__(256) void moe_dn_mfma(const unsigned short* __restrict__ hbuf,
                                                   const void* __restrict__ w2,
                                                   const int* __restrict__ cnt,
                                                   const int* __restrict__ eslot,
                                                   float* __restrict__ dbuf)
{
    int e = blockIdx.z;
    int c = cnt[e];
    int p0 = blockIdx.y * 128;
    if (p0 >= c) return;
    int h0 = blockIdx.x * 128;
    int tid = threadIdx.x;

    __shared__ char As[16384], Bs[16384];
    __shared__ int rowslotS[128];
    if (tid < 128) rowslotS[tid] = eslot[e * S_ + min(p0 + tid, c - 1)];
    __syncthreads();

    int lane = tid & 63, w = tid >> 6, wm = w >> 1, wn = w & 1;
    int lm = lane & 15, lk = lane >> 4;
    size_t wbase = (size_t)e * H_ * I_;

    int4 rA[4], rB[4];
    auto loadAll = [&](int kb) {
#pragma unroll
        for (int it = 0; it < 4; ++it) {
            int g = tid + it * 256, row = g >> 3, kg = g & 7;
            rA[it] = *(const int4*)(hbuf + (size_t)rowslotS[row] * I_ + kb + kg * 8);
            rB[it] = loadW16<WB>(w2, wbase + (size_t)(h0 + row) * I_ + kb + kg * 8);
        }
    };
    auto writeAll = [&]() {
#pragma unroll
        for (int it = 0; it < 4; ++it) {
            int g = tid + it * 256, row = g >> 3, kg = g & 7;
            int byte = row * 128 + ((kg * 16) ^ ((row & 7) << 4));
            *(int4*)(As + byte) = rA[it];
            *(int4*)(Bs + byte) = rB[it];
        }
    };

    f32x4 z = {0.f, 0.f, 0.f, 0.f};
    f32x4 acc[4][4];
#pragma unroll
    for (int mf = 0; mf < 4; ++mf)
#pragma unroll
        for (int nf = 0; nf < 4; ++nf) acc[mf][nf] = z;

    loadAll(0);
    for (int kt = 0; kt < I_ / 64; ++kt) {
        __syncthreads();
        writeAll();
        __syncthreads();
        if (kt + 1 < I_ / 64) loadAll((kt + 1) * 64);
#pragma unroll
        for (int ks = 0; ks < 2; ++ks) {
            bf16x8 af[4];
#pragma unroll
            for (int mf = 0; mf < 4; ++mf) {
                int row = wm * 64 + mf * 16 + lm;
                af[mf] = *(const bf16x8*)(As + row * 128 + ((ks * 64 + lk * 16) ^ ((row & 7) << 4)));
            }
#pragma unroll
            for (int nf = 0; nf < 4; ++nf) {
                int brow = wn * 64 + nf * 16 + lm;
                bf16x8 bf = *(const bf16x8*)(Bs + brow * 128 + ((ks * 64 + lk * 16) ^ ((brow & 7) << 4)));
#pragma unroll
                for (int mf = 0; mf < 4; ++mf)
                    acc[mf][nf] = __builtin_amdgcn_mfma_f32_16x16x32_bf16(af[mf], bf, acc[mf][nf], 0, 0, 0);
            }
        }
    }

#pragma unroll
    for (int mf = 0; mf < 4; ++mf)
#pragma unroll
        for (int nf = 0; nf < 4; ++nf) {
            int colh = h0 + wn * 64 + nf * 16 + lm;
#pragma unroll
            for (int j = 0; j < 4; ++j) {
                int rloc = wm * 64 + mf * 16 + lk * 4 + j;
                if (p0 + rloc < c)
                    dbuf[(size_t)rowslotS[rloc] * H_ + colh] = acc[mf][nf][j];
            }
        }
}

// ---------------- Final combine
__global__ __launch_bounds__(256) void combine_k(const float* __restrict__ hid2,
                                                 const float* __restrict__ dbuf,
                                                 const float* __restrict__ wslot,
                                                 float* __restrict__ out)
{
    int idx = blockIdx.x * 256 + threadIdx.x;
    if (idx >= S_ * H_) return;
    int n = idx >> 10;
    int hcol = idx & (H_ - 1);
    out[idx] = hid2[idx]
             + wslot[2 * n]     * dbuf[(size_t)(2 * n) * H_ + hcol]
             + wslot[2 * n + 1] * dbuf[(size_t)(2 * n + 1) * H_ + hcol];
}

extern "C" void kernel_launch(void* const* d_in, const int* in_sizes, int n_in,
                              void* d_out, int out_size, void* d_ws, size_t ws_size,
                              hipStream_t stream)
{
    const float* hidden = (const float*)d_in[0];
    const float* ln1    = (const float*)d_in[1];
    const float* ln2    = (const float*)d_in[2];
    const float* wq     = (const float*)d_in[3];
    const float* wk     = (const float*)d_in[4];
    const float* wv     = (const float*)d_in[5];
    const float* wo     = (const float*)d_in[6];
    const float* gw     = (const float*)d_in[7];
    const float* w1     = (const float*)d_in[8];
    const float* w2     = (const float*)d_in[9];
    const float* w3     = (const float*)d_in[10];
    float* out = (float*)d_out;

    char* p = (char*)d_ws;
    auto alignp = [&]() { p = (char*)(((uintptr_t)p + 255) & ~(uintptr_t)255); };
    auto alloc_f = [&](size_t n) { alignp(); float* r = (float*)p; p += n * 4; return r; };
    auto alloc_h = [&](size_t n) { alignp(); unsigned short* r = (unsigned short*)p; p += n * 2; return r; };
    auto alloc_i = [&](size_t n) { alignp(); int* r = (int*)p; p += n * 4; return r; };

    float* xb   = alloc_f((size_t)S_ * H_);
    float* q    = alloc_f((size_t)S_ * NH_ * HD_);
    float* kb   = alloc_f((size_t)S_ * KVH_ * HD_);
    float* vb   = alloc_f((size_t)S_ * KVH_ * HD_);
    float* hid2 = alloc_f((size_t)S_ * H_);
    float* x2   = alloc_f((size_t)S_ * H_);
    unsigned short* hbuf = alloc_h((size_t)S_ * 2 * I_);
    float* dbuf = alloc_f((size_t)S_ * 2 * H_);
    float* wslot= alloc_f((size_t)S_ * 2);
    unsigned short* qbf = alloc_h((size_t)S_ * NH_ * HD_);
    unsigned short* kbf = alloc_h((size_t)S_ * KVH_ * HD_);
    unsigned short* vtb = alloc_h((size_t)KVH_ * HD_ * S_);
    int* cnt   = alloc_i(E_);
    int* elist = alloc_i((size_t)E_ * S_);
    int* eslot = alloc_i((size_t)E_ * S_);
    float* ctx = xb;

    size_t used = (size_t)(p - (char*)d_ws);
    const size_t nW = (size_t)E_ * I_ * H_;
    size_t wbf_bytes = (3 * nW + (size_t)(NH_*HD_ + 2*KVH_*HD_ + H_) * H_) * 2 + 4096;
    bool WB = ws_size > used && (ws_size - used) >= wbf_bytes;

    unsigned short *w1b = nullptr, *w3b = nullptr, *w2b = nullptr;
    unsigned short *wqb = nullptr, *wkb = nullptr, *wvb = nullptr, *wob = nullptr;
    if (WB) {
        w1b = alloc_h(nW); w3b = alloc_h(nW); w2b = alloc_h(nW);
        wqb = alloc_h((size_t)NH_ * HD_ * H_);
        wkb = alloc_h((size_t)KVH_ * HD_ * H_);
        wvb = alloc_h((size_t)KVH_ * HD_ * H_);
        wob = alloc_h((size_t)H_ * NH_ * HD_);
    }

    hipMemsetAsync(cnt, 0, E_ * sizeof(int), stream);

    if (WB) {
        conv_bf16<<<2048, 256, 0, stream>>>(w1, w1b, (long)(nW / 8));
        conv_bf16<<<2048, 256, 0, stream>>>(w3, w3b, (long)(nW / 8));
        conv_bf16<<<2048, 256, 0, stream>>>(w2, w2b, (long)(nW / 8));
        conv_bf16<<<512, 256, 0, stream>>>(wq, wqb, (long)((size_t)NH_*HD_*H_ / 8));
        conv_bf16<<<512, 256, 0, stream>>>(wk, wkb, (long)((size_t)KVH_*HD_*H_ / 8));
        conv_bf16<<<512, 256, 0, stream>>>(wv, wvb, (long)((size_t)KVH_*HD_*H_ / 8));
        conv_bf16<<<512, 256, 0, stream>>>(wo, wob, (long)((size_t)H_*NH_*HD_ / 8));
    }

    rmsnorm_k<<<S_, 256, 0, stream>>>(hidden, ln1, xb);

    if (WB) {
        dense_mfma<true><<<dim3(8, 16),  256, 0, stream>>>(xb, wqb, nullptr, q,  S_, NH_ * HD_, H_);
        dense_mfma<true><<<dim3(4, 16),  256, 0, stream>>>(xb, wkb, nullptr, kb, S_, KVH_ * HD_, H_);
        dense_mfma<true><<<dim3(4, 16),  256, 0, stream>>>(xb, wvb, nullptr, vb, S_, KVH_ * HD_, H_);
    } else {
        dense_mfma<false><<<dim3(8, 16), 256, 0, stream>>>(xb, wq, nullptr, q,  S_, NH_ * HD_, H_);
        dense_mfma<false><<<dim3(4, 16), 256, 0, stream>>>(xb, wk, nullptr, kb, S_, KVH_ * HD_, H_);
        dense_mfma<false><<<dim3(4, 16), 256, 0, stream>>>(xb, wv, nullptr, vb, S_, KVH_ * HD_, H_);
    }
    {
        int tot = S_ * (NH_ + KVH_) * 32;
        rope_conv<<<SDIV(tot, 256), 256, 0, stream>>>(q, kb, qbf, kbf);
    }
    v_trans<<<dim3(S_ / 64, KVH_), 256, 0, stream>>>(vb, vtb);
    attn_mfma<<<dim3(16, NH_, 2), 256, 0, stream>>>(qbf, kbf, vtb, ctx);

    if (WB)
        dense_mfma<true><<<dim3(8, 16),  256, 0, stream>>>(ctx, wob, hidden, hid2, S_, H_, NH_ * HD_);
    else
        dense_mfma<false><<<dim3(8, 16), 256, 0, stream>>>(ctx, wo, hidden, hid2, S_, H_, NH_ * HD_);

    rmsnorm_k<<<S_, 256, 0, stream>>>(hid2, ln2, x2);
    router_k<<<S_, 64, 0, stream>>>(x2, gw, cnt, elist, eslot, wslot);

    if (WB) {
        moe_up_mfma<true><<<dim3(I_ / 128, S_ / 128, E_), 256, 0, stream>>>(x2, w1b, w3b, cnt, elist, eslot, hbuf);
        moe_dn_mfma<true><<<dim3(H_ / 128, S_ / 128, E_), 256, 0, stream>>>(hbuf, w2b, cnt, eslot, dbuf);
    } else {
        moe_up_mfma<false><<<dim3(I_ / 128, S_ / 128, E_), 256, 0, stream>>>(x2, w1, w3, cnt, elist, eslot, hbuf);
        moe_dn_mfma<false><<<dim3(H_ / 128, S_ / 128, E_), 256, 0, stream>>>(hbuf, w2, cnt, eslot, dbuf);
    }
    combine_k<<<SDIV(S_ * H_, 256), 256, 0, stream>>>(hid2, dbuf, wslot, out);
}

// Round 6
// 684.586 us; speedup vs baseline: 4.7959x; 1.0437x over previous
//
#include <hip/hip_runtime.h>
#include <hip/hip_bf16.h>
#include <math.h>

constexpr int S_ = 2048, H_ = 1024, NH_ = 16, KVH_ = 8, HD_ = 64;
constexpr int E_ = 8, I_ = 3584;
constexpr int KSLC = 4;                 // split-K slices for MoE down
constexpr float EPS_ = 1e-6f;
constexpr float THETA_ = 1000000.0f;

#define SDIV(a,b) (((a)+(b)-1)/(b))

typedef __attribute__((ext_vector_type(8))) short bf16x8;
typedef __attribute__((ext_vector_type(4))) float f32x4;

__device__ inline unsigned pkbf(float a, float b) {
    unsigned r;
    asm("v_cvt_pk_bf16_f32 %0, %1, %2" : "=v"(r) : "v"(a), "v"(b));
    return r;
}
__device__ inline unsigned short f2bf(float f) {
    unsigned u = __float_as_uint(f);
    u += 0x7FFF + ((u >> 16) & 1);
    return (unsigned short)(u >> 16);
}
__device__ inline float bf2f(unsigned short v) {
    return __uint_as_float((unsigned)v << 16);
}

template<bool WB>
__device__ inline int4 loadW16(const void* W, size_t elemOff) {
    if constexpr (WB) {
        return *(const int4*)((const unsigned short*)W + elemOff);
    } else {
        const float* s = (const float*)W + elemOff;
        float4 f0 = *(const float4*)s, f1 = *(const float4*)(s + 4);
        return make_int4(pkbf(f0.x, f0.y), pkbf(f0.z, f0.w),
                         pkbf(f1.x, f1.y), pkbf(f1.z, f1.w));
    }
}

// ---------------- fp32 -> bf16 bulk convert
__global__ __launch_bounds__(256) void conv_bf16(const float* __restrict__ in,
                                                 unsigned short* __restrict__ out, long n8)
{
    long i = (long)blockIdx.x * 256 + threadIdx.x;
    long stride = (long)gridDim.x * 256;
    for (; i < n8; i += stride) {
        const float* s = in + i * 8;
        float4 f0 = *(const float4*)s, f1 = *(const float4*)(s + 4);
        *(int4*)(out + i * 8) = make_int4(pkbf(f0.x, f0.y), pkbf(f0.z, f0.w),
                                          pkbf(f1.x, f1.y), pkbf(f1.z, f1.w));
    }
}

// ---------------- RMSNorm
__global__ __launch_bounds__(256) void rmsnorm_k(const float* __restrict__ x,
                                                 const float* __restrict__ w,
                                                 float* __restrict__ out)
{
    int row = blockIdx.x;
    int tid = threadIdx.x;
    const float* xr = x + (size_t)row * H_;
    float4 v = *(const float4*)&xr[tid * 4];
    float ss = v.x*v.x + v.y*v.y + v.z*v.z + v.w*v.w;
#pragma unroll
    for (int off = 32; off > 0; off >>= 1) ss += __shfl_xor(ss, off);
    __shared__ float red[4];
    if ((tid & 63) == 0) red[tid >> 6] = ss;
    __syncthreads();
    float tot = red[0] + red[1] + red[2] + red[3];
    float r = rsqrtf(tot / (float)H_ + EPS_);
    float4 wv = *(const float4*)&w[tid * 4];
    float4 o;
    o.x = v.x * r * wv.x; o.y = v.y * r * wv.y;
    o.z = v.z * r * wv.z; o.w = v.w * r * wv.w;
    *(float4*)&out[(size_t)row * H_ + tid * 4] = o;
}

// ---------------- Dense bf16-MFMA GEMM: C[M,N] = (Res?) + A[M,K]*B[N,K]^T
template<bool WB>
__global__ __launch_bounds__(256) void dense_mfma(const float* __restrict__ A,
                                                  const void* __restrict__ Bw,
                                                  const float* __restrict__ Res,
                                                  float* __restrict__ C,
                                                  int M, int N, int K)
{
    __shared__ char As[16384], Bs[16384];
    int tid = threadIdx.x;
    int m0 = blockIdx.y * 128, n0 = blockIdx.x * 128;
    int lane = tid & 63, w = tid >> 6, wm = w >> 1, wn = w & 1;
    int lm = lane & 15, lk = lane >> 4;

    int4 rA[4], rB[4];
    auto loadAll = [&](int kb) {
#pragma unroll
        for (int it = 0; it < 4; ++it) {
            int g = tid + it * 256, row = g >> 3, kg = g & 7;
            const float* s = A + (size_t)(m0 + row) * K + kb + kg * 8;
            float4 f0 = *(const float4*)s, f1 = *(const float4*)(s + 4);
            rA[it] = make_int4(pkbf(f0.x, f0.y), pkbf(f0.z, f0.w),
                               pkbf(f1.x, f1.y), pkbf(f1.z, f1.w));
            rB[it] = loadW16<WB>(Bw, (size_t)(n0 + row) * K + kb + kg * 8);
        }
    };
    auto writeAll = [&]() {
#pragma unroll
        for (int it = 0; it < 4; ++it) {
            int g = tid + it * 256, row = g >> 3, kg = g & 7;
            int byte = row * 128 + ((kg * 16) ^ ((row & 7) << 4));
            *(int4*)(As + byte) = rA[it];
            *(int4*)(Bs + byte) = rB[it];
        }
    };

    f32x4 z = {0.f, 0.f, 0.f, 0.f};
    f32x4 acc[4][4];
#pragma unroll
    for (int mf = 0; mf < 4; ++mf)
#pragma unroll
        for (int nf = 0; nf < 4; ++nf) acc[mf][nf] = z;

    loadAll(0);
    for (int kt = 0; kt < K / 64; ++kt) {
        __syncthreads();
        writeAll();
        __syncthreads();
        if (kt + 1 < K / 64) loadAll((kt + 1) * 64);
#pragma unroll
        for (int ks = 0; ks < 2; ++ks) {
            bf16x8 af[4];
#pragma unroll
            for (int mf = 0; mf < 4; ++mf) {
                int row = wm * 64 + mf * 16 + lm;
                af[mf] = *(const bf16x8*)(As + row * 128 + ((ks * 64 + lk * 16) ^ ((row & 7) << 4)));
            }
#pragma unroll
            for (int nf = 0; nf < 4; ++nf) {
                int brow = wn * 64 + nf * 16 + lm;
                bf16x8 bf = *(const bf16x8*)(Bs + brow * 128 + ((ks * 64 + lk * 16) ^ ((brow & 7) << 4)));
#pragma unroll
                for (int mf = 0; mf < 4; ++mf)
                    acc[mf][nf] = __builtin_amdgcn_mfma_f32_16x16x32_bf16(af[mf], bf, acc[mf][nf], 0, 0, 0);
            }
        }
    }

#pragma unroll
    for (int mf = 0; mf < 4; ++mf)
#pragma unroll
        for (int nf = 0; nf < 4; ++nf) {
            int col = n0 + wn * 64 + nf * 16 + lm;
#pragma unroll
            for (int j = 0; j < 4; ++j) {
                int row = m0 + wm * 64 + mf * 16 + lk * 4 + j;
                float r = Res ? Res[(size_t)row * N + col] : 0.0f;
                C[(size_t)row * N + col] = acc[mf][nf][j] + r;
            }
        }
}

// ---------------- RoPE + bf16 convert. Q pre-scaled by 1/sqrt(HD).
__global__ __launch_bounds__(256) void rope_conv(const float* __restrict__ q,
                                                 const float* __restrict__ k,
                                                 unsigned short* __restrict__ qbf,
                                                 unsigned short* __restrict__ kbf)
{
    int idx = blockIdx.x * 256 + threadIdx.x;
    const int totq = S_ * NH_ * 32;
    const int tot = totq + S_ * KVH_ * 32;
    if (idx >= tot) return;
    const float* base; unsigned short* obase; int s, di; float sc;
    if (idx < totq) {
        s = idx / (NH_ * 32); int r = idx % (NH_ * 32);
        size_t o = ((size_t)s * NH_ + (r >> 5)) * HD_;
        base = q + o; obase = qbf + o; di = r & 31; sc = 0.125f;
    } else {
        int j2 = idx - totq;
        s = j2 / (KVH_ * 32); int r = j2 % (KVH_ * 32);
        size_t o = ((size_t)s * KVH_ + (r >> 5)) * HD_;
        base = k + o; obase = kbf + o; di = r & 31; sc = 1.0f;
    }
    float invf = powf(THETA_, -(2.0f * di) / (float)HD_);
    float ang = (float)s * invf;
    float c = cosf(ang), sn = sinf(ang);
    float x0 = base[di], x1 = base[di + 32];
    obase[di]      = f2bf((x0 * c - x1 * sn) * sc);
    obase[di + 32] = f2bf((x1 * c + x0 * sn) * sc);
}

// ---------------- V transpose: vtb[kvh][d][t0+slot] = bf16(V[t0+key][kvh][d])
__global__ __launch_bounds__(256) void v_trans(const float* __restrict__ v,
                                               unsigned short* __restrict__ vtb)
{
    int t0 = blockIdx.x * 64, kvh = blockIdx.y;
    __shared__ unsigned short T[64][64];
    int tid = threadIdx.x;
    int k = tid >> 2, d0 = (tid & 3) * 16;
    const float* src = v + ((size_t)(t0 + k) * KVH_ + kvh) * HD_ + d0;
#pragma unroll
    for (int x = 0; x < 4; ++x) {
        float4 f = *(const float4*)(src + x * 4);
        T[k][d0 + x*4 + 0] = f2bf(f.x);
        T[k][d0 + x*4 + 1] = f2bf(f.y);
        T[k][d0 + x*4 + 2] = f2bf(f.z);
        T[k][d0 + x*4 + 3] = f2bf(f.w);
    }
    __syncthreads();
    int d = tid >> 2, s0 = (tid & 3) * 16;
    unsigned short tmp[16] __attribute__((aligned(16)));
#pragma unroll
    for (int x = 0; x < 16; ++x) {
        int s = s0 + x;
        int key = 16 * (s & 3) + (s >> 2);
        tmp[x] = T[key][d];
    }
    unsigned short* dst = vtb + ((size_t)kvh * HD_ + d) * S_ + t0 + s0;
    *(int4*)(dst)     = *(int4*)(tmp);
    *(int4*)(dst + 8) = *(int4*)(tmp + 8);
}

// ---------------- MFMA flash attention (unchanged from R5)
__global__ __launch_bounds__(256) void attn_mfma(const unsigned short* __restrict__ qbf,
                                                 const unsigned short* __restrict__ kbf,
                                                 const unsigned short* __restrict__ vtb,
                                                 float* __restrict__ ctx)
{
    __shared__ char Ps[4 * 2048];
    int pair = blockIdx.x, h = blockIdx.y, z = blockIdx.z;
    int qb = z ? (31 - pair) : pair;
    int q0 = qb * 64;
    int kvh = h >> 1;
    int tid = threadIdx.x;
    int w = tid >> 6, lane = tid & 63;
    int lm = lane & 15, lk = lane >> 4;
    char* myP = Ps + w * 2048;

    bf16x8 qf[2];
    const unsigned short* qrow = qbf + ((size_t)(q0 + w * 16 + lm) * NH_ + h) * HD_;
#pragma unroll
    for (int ks = 0; ks < 2; ++ks)
        qf[ks] = *(const bf16x8*)(qrow + ks * 32 + lk * 8);

    float m_[4], l_[4];
    f32x4 o_[4];
#pragma unroll
    for (int j = 0; j < 4; ++j) { m_[j] = -1e30f; l_[j] = 0.f; }
    f32x4 zf = {0.f, 0.f, 0.f, 0.f};
#pragma unroll
    for (int nd = 0; nd < 4; ++nd) o_[nd] = zf;

    for (int t0 = 0; t0 <= q0; t0 += 64) {
        f32x4 s[4];
#pragma unroll
        for (int nf = 0; nf < 4; ++nf) {
            const unsigned short* krow = kbf + ((size_t)(t0 + nf * 16 + lm) * KVH_ + kvh) * HD_;
            bf16x8 k0 = *(const bf16x8*)(krow + lk * 8);
            bf16x8 k1 = *(const bf16x8*)(krow + 32 + lk * 8);
            f32x4 acc = zf;
            acc = __builtin_amdgcn_mfma_f32_16x16x32_bf16(qf[0], k0, acc, 0, 0, 0);
            acc = __builtin_amdgcn_mfma_f32_16x16x32_bf16(qf[1], k1, acc, 0, 0, 0);
            s[nf] = acc;
        }
        if (t0 == q0) {
#pragma unroll
            for (int nf = 0; nf < 4; ++nf)
#pragma unroll
                for (int j = 0; j < 4; ++j) {
                    int key = nf * 16 + lm, qq = w * 16 + lk * 4 + j;
                    if (key > qq) s[nf][j] = -1e30f;
                }
        }
        float p_[4][4];
#pragma unroll
        for (int j = 0; j < 4; ++j) {
            float mx = fmaxf(fmaxf(s[0][j], s[1][j]), fmaxf(s[2][j], s[3][j]));
#pragma unroll
            for (int off = 8; off > 0; off >>= 1) mx = fmaxf(mx, __shfl_xor(mx, off));
            float nm = fmaxf(m_[j], mx);
            float rs = __expf(m_[j] - nm);
            float sum = 0.f;
#pragma unroll
            for (int nf = 0; nf < 4; ++nf) {
                float pv = __expf(s[nf][j] - nm);
                p_[nf][j] = pv; sum += pv;
            }
#pragma unroll
            for (int off = 8; off > 0; off >>= 1) sum += __shfl_xor(sum, off);
            l_[j] = l_[j] * rs + sum;
            m_[j] = nm;
#pragma unroll
            for (int nd = 0; nd < 4; ++nd) o_[nd][j] *= rs;
        }
#pragma unroll
        for (int j = 0; j < 4; ++j) {
            int r = lk * 4 + j;
            unsigned lo = pkbf(p_[0][j], p_[1][j]);
            unsigned hi = pkbf(p_[2][j], p_[3][j]);
            int byte = (lm * 8) ^ ((r & 7) << 4);
            *(uint2*)(myP + r * 128 + byte) = make_uint2(lo, hi);
        }
#pragma unroll
        for (int ks = 0; ks < 2; ++ks) {
            int byte = (ks * 64 + lk * 16) ^ ((lm & 7) << 4);
            bf16x8 pA = *(const bf16x8*)(myP + lm * 128 + byte);
#pragma unroll
            for (int nd = 0; nd < 4; ++nd) {
                const unsigned short* vrow = vtb + ((size_t)kvh * HD_ + nd * 16 + lm) * S_ + t0 + ks * 32 + lk * 8;
                bf16x8 vB = *(const bf16x8*)vrow;
                o_[nd] = __builtin_amdgcn_mfma_f32_16x16x32_bf16(pA, vB, o_[nd], 0, 0, 0);
            }
        }
    }
#pragma unroll
    for (int nd = 0; nd < 4; ++nd)
#pragma unroll
        for (int j = 0; j < 4; ++j) {
            int r = lk * 4 + j;
            ctx[((size_t)(q0 + w * 16 + r) * NH_ + h) * HD_ + nd * 16 + lm] = o_[nd][j] / l_[j];
        }
}

// ---------------- Router
__global__ __launch_bounds__(64) void router_k(const float* __restrict__ x2,
                                               const float* __restrict__ gw,
                                               int* __restrict__ cnt,
                                               int* __restrict__ elist,
                                               int* __restrict__ eslot,
                                               float* __restrict__ wslot)
{
    int n = blockIdx.x, lane = threadIdx.x;
    float part[E_];
#pragma unroll
    for (int e = 0; e < E_; ++e) part[e] = 0.f;
    const float* xr = x2 + (size_t)n * H_;
    for (int j = lane; j < H_; j += 64) {
        float xv = xr[j];
#pragma unroll
        for (int e = 0; e < E_; ++e) part[e] = fmaf(xv, gw[e * H_ + j], part[e]);
    }
#pragma unroll
    for (int e = 0; e < E_; ++e)
#pragma unroll
        for (int off = 32; off > 0; off >>= 1) part[e] += __shfl_xor(part[e], off);
    if (lane == 0) {
        float mx = part[0];
#pragma unroll
        for (int e = 1; e < E_; ++e) mx = fmaxf(mx, part[e]);
        float rw[E_]; float ssum = 0.f;
#pragma unroll
        for (int e = 0; e < E_; ++e) { rw[e] = expf(part[e] - mx); ssum += rw[e]; }
#pragma unroll
        for (int e = 0; e < E_; ++e) rw[e] /= ssum;
        float best = -1.f; int ba = 0, bb = 1;
        for (int a = 0; a < E_; ++a)
            for (int b = a + 1; b < E_; ++b) {
                float scv = rw[a] + rw[b];
                if (scv > best) { best = scv; ba = a; bb = b; }
            }
        float wa = rw[ba], wb = rw[bb], wsum = wa + wb;
        wa /= wsum; wb /= wsum;
        int p = atomicAdd(&cnt[ba], 1);
        elist[ba * S_ + p] = n; eslot[ba * S_ + p] = 2 * n;
        p = atomicAdd(&cnt[bb], 1);
        elist[bb * S_ + p] = n; eslot[bb * S_ + p] = 2 * n + 1;
        wslot[2 * n] = wa; wslot[2 * n + 1] = wb;
    }
}

// ---------------- MoE up (bf16 MFMA), 128x128, BK=64
template<bool WB>
__global__ __launch_bounds__(256) void moe_up_mfma(const float* __restrict__ x2,
                                                   const void* __restrict__ w1,
                                                   const void* __restrict__ w3,
                                                   const int* __restrict__ cnt,
                                                   const int* __restrict__ elist,
                                                   const int* __restrict__ eslot,
                                                   unsigned short* __restrict__ hbuf)
{
    int e = blockIdx.z;
    int c = cnt[e];
    int p0 = blockIdx.y * 128;
    if (p0 >= c) return;
    int i0 = blockIdx.x * 128;
    int tid = threadIdx.x;

    __shared__ char As[16384], B1s[16384], B3s[16384];
    __shared__ int rowtokS[128], rowslotS[128];
    if (tid < 128) {
        int p = min(p0 + tid, c - 1);
        rowtokS[tid]  = elist[e * S_ + p];
        rowslotS[tid] = eslot[e * S_ + p];
    }
    __syncthreads();

    int lane = tid & 63, w = tid >> 6, wm = w >> 1, wn = w & 1;
    int lm = lane & 15, lk = lane >> 4;
    size_t wbase = (size_t)e * I_ * H_;

    int4 rA[4], rB1[4], rB3[4];
    auto loadAll = [&](int kb) {
#pragma unroll
        for (int it = 0; it < 4; ++it) {
            int g = tid + it * 256, row = g >> 3, kg = g & 7;
            const float* s = x2 + (size_t)rowtokS[row] * H_ + kb + kg * 8;
            float4 f0 = *(const float4*)s, f1 = *(const float4*)(s + 4);
            rA[it] = make_int4(pkbf(f0.x, f0.y), pkbf(f0.z, f0.w),
                               pkbf(f1.x, f1.y), pkbf(f1.z, f1.w));
            size_t off = wbase + (size_t)(i0 + row) * H_ + kb + kg * 8;
            rB1[it] = loadW16<WB>(w1, off);
            rB3[it] = loadW16<WB>(w3, off);
        }
    };
    auto writeAll = [&]() {
#pragma unroll
        for (int it = 0; it < 4; ++it) {
            int g = tid + it * 256, row = g >> 3, kg = g & 7;
            int byte = row * 128 + ((kg * 16) ^ ((row & 7) << 4));
            *(int4*)(As + byte)  = rA[it];
            *(int4*)(B1s + byte) = rB1[it];
            *(int4*)(B3s + byte) = rB3[it];
        }
    };

    f32x4 z = {0.f, 0.f, 0.f, 0.f};
    f32x4 acc1[4][4], acc3[4][4];
#pragma unroll
    for (int mf = 0; mf < 4; ++mf)
#pragma unroll
        for (int nf = 0; nf < 4; ++nf) { acc1[mf][nf] = z; acc3[mf][nf] = z; }

    loadAll(0);
    for (int kt = 0; kt < H_ / 64; ++kt) {
        __syncthreads();
        writeAll();
        __syncthreads();
        if (kt + 1 < H_ / 64) loadAll((kt + 1) * 64);
#pragma unroll
        for (int ks = 0; ks < 2; ++ks) {
            bf16x8 af[4];
#pragma unroll
            for (int mf = 0; mf < 4; ++mf) {
                int row = wm * 64 + mf * 16 + lm;
                af[mf] = *(const bf16x8*)(As + row * 128 + ((ks * 64 + lk * 16) ^ ((row & 7) << 4)));
            }
#pragma unroll
            for (int nf = 0; nf < 4; ++nf) {
                int brow = wn * 64 + nf * 16 + lm;
                int bby = brow * 128 + ((ks * 64 + lk * 16) ^ ((brow & 7) << 4));
                bf16x8 b1 = *(const bf16x8*)(B1s + bby);
                bf16x8 b3 = *(const bf16x8*)(B3s + bby);
#pragma unroll
                for (int mf = 0; mf < 4; ++mf) {
                    acc1[mf][nf] = __builtin_amdgcn_mfma_f32_16x16x32_bf16(af[mf], b1, acc1[mf][nf], 0, 0, 0);
                    acc3[mf][nf] = __builtin_amdgcn_mfma_f32_16x16x32_bf16(af[mf], b3, acc3[mf][nf], 0, 0, 0);
                }
            }
        }
    }

#pragma unroll
    for (int mf = 0; mf < 4; ++mf)
#pragma unroll
        for (int nf = 0; nf < 4; ++nf) {
            int coli = i0 + wn * 64 + nf * 16 + lm;
#pragma unroll
            for (int j = 0; j < 4; ++j) {
                int rloc = wm * 64 + mf * 16 + lk * 4 + j;
                if (p0 + rloc < c) {
                    float h1 = acc1[mf][nf][j];
                    float val = h1 / (1.f + __expf(-h1)) * acc3[mf][nf][j];
                    hbuf[(size_t)rowslotS[rloc] * I_ + coli] = f2bf(val);
                }
            }
        }
}

// ---------------- MoE down (bf16 MFMA), 128x128, BK=64, SPLIT-K over KSLC slices.
// Partials written as bf16 to dbuf[slice][slot][H]; combine sums slices.
template<bool WB>
__global__ __launch_bounds__(256) void moe_dn_mfma(const unsigned short* __restrict__ hbuf,
                                                   const void* __restrict__ w2,
                                                   const int* __restrict__ cnt,
                                                   const int* __restrict__ eslot,
                                                   unsigned short* __restrict__ dbuf)
{
    int e = blockIdx.z >> 2;           // KSLC == 4
    int slice = blockIdx.z & 3;
    int c = cnt[e];
    int p0 = blockIdx.y * 128;
    if (p0 >= c) return;
    int h0 = blockIdx.x * 128;
    int tid = threadIdx.x;
    const int kb0 = slice * (I_ / KSLC);     // 896-wide slice

    __shared__ char As[16384], Bs[16384];
    __shared__ int rowslotS[128];
    if (tid < 128) rowslotS[tid] = eslot[e * S_ + min(p0 + tid, c - 1)];
    __syncthreads();

    int lane = tid & 63, w = tid >> 6, wm = w >> 1, wn = w & 1;
    int lm = lane & 15, lk = lane >> 4;
    size_t wbase = (size_t)e * H_ * I_;

    int4 rA[4], rB[4];
    auto loadAll = [&](int kb) {
#pragma unroll
        for (int it = 0; it < 4; ++it) {
            int g = tid + it * 256, row = g >> 3, kg = g & 7;
            rA[it] = *(const int4*)(hbuf + (size_t)rowslotS[row] * I_ + kb + kg * 8);
            rB[it] = loadW16<WB>(w2, wbase + (size_t)(h0 + row) * I_ + kb + kg * 8);
        }
    };
    auto writeAll = [&]() {
#pragma unroll
        for (int it = 0; it < 4; ++it) {
            int g = tid + it * 256, row = g >> 3, kg = g & 7;
            int byte = row * 128 + ((kg * 16) ^ ((row & 7) << 4));
            *(int4*)(As + byte) = rA[it];
            *(int4*)(Bs + byte) = rB[it];
        }
    };

    f32x4 z = {0.f, 0.f, 0.f, 0.f};
    f32x4 acc[4][4];
#pragma unroll
    for (int mf = 0; mf < 4; ++mf)
#pragma unroll
        for (int nf = 0; nf < 4; ++nf) acc[mf][nf] = z;

    loadAll(kb0);
    const int NKT = (I_ / KSLC) / 64;        // 14
    for (int kt = 0; kt < NKT; ++kt) {
        __syncthreads();
        writeAll();
        __syncthreads();
        if (kt + 1 < NKT) loadAll(kb0 + (kt + 1) * 64);
#pragma unroll
        for (int ks = 0; ks < 2; ++ks) {
            bf16x8 af[4];
#pragma unroll
            for (int mf = 0; mf < 4; ++mf) {
                int row = wm * 64 + mf * 16 + lm;
                af[mf] = *(const bf16x8*)(As + row * 128 + ((ks * 64 + lk * 16) ^ ((row & 7) << 4)));
            }
#pragma unroll
            for (int nf = 0; nf < 4; ++nf) {
                int brow = wn * 64 + nf * 16 + lm;
                bf16x8 bf = *(const bf16x8*)(Bs + brow * 128 + ((ks * 64 + lk * 16) ^ ((brow & 7) << 4)));
#pragma unroll
                for (int mf = 0; mf < 4; ++mf)
                    acc[mf][nf] = __builtin_amdgcn_mfma_f32_16x16x32_bf16(af[mf], bf, acc[mf][nf], 0, 0, 0);
            }
        }
    }

    unsigned short* dslice = dbuf + (size_t)slice * S_ * 2 * H_;
#pragma unroll
    for (int mf = 0; mf < 4; ++mf)
#pragma unroll
        for (int nf = 0; nf < 4; ++nf) {
            int colh = h0 + wn * 64 + nf * 16 + lm;
#pragma unroll
            for (int j = 0; j < 4; ++j) {
                int rloc = wm * 64 + mf * 16 + lk * 4 + j;
                if (p0 + rloc < c)
                    dslice[(size_t)rowslotS[rloc] * H_ + colh] = f2bf(acc[mf][nf][j]);
            }
        }
}

// ---------------- Final combine: out = hid2 + Σ_slot w_slot * Σ_slice dbuf
__global__ __launch_bounds__(256) void combine_k(const float* __restrict__ hid2,
                                                 const unsigned short* __restrict__ dbuf,
                                                 const float* __restrict__ wslot,
                                                 float* __restrict__ out)
{
    int idx = blockIdx.x * 256 + threadIdx.x;
    if (idx >= S_ * H_) return;
    int n = idx >> 10;
    int hcol = idx & (H_ - 1);
    float s0 = 0.f, s1 = 0.f;
#pragma unroll
    for (int sl = 0; sl < KSLC; ++sl) {
        const unsigned short* base = dbuf + (size_t)sl * S_ * 2 * H_;
        s0 += bf2f(base[(size_t)(2 * n)     * H_ + hcol]);
        s1 += bf2f(base[(size_t)(2 * n + 1) * H_ + hcol]);
    }
    out[idx] = hid2[idx] + wslot[2 * n] * s0 + wslot[2 * n + 1] * s1;
}

extern "C" void kernel_launch(void* const* d_in, const int* in_sizes, int n_in,
                              void* d_out, int out_size, void* d_ws, size_t ws_size,
                              hipStream_t stream)
{
    const float* hidden = (const float*)d_in[0];
    const float* ln1    = (const float*)d_in[1];
    const float* ln2    = (const float*)d_in[2];
    const float* wq     = (const float*)d_in[3];
    const float* wk     = (const float*)d_in[4];
    const float* wv     = (const float*)d_in[5];
    const float* wo     = (const float*)d_in[6];
    const float* gw     = (const float*)d_in[7];
    const float* w1     = (const float*)d_in[8];
    const float* w2     = (const float*)d_in[9];
    const float* w3     = (const float*)d_in[10];
    float* out = (float*)d_out;

    char* p = (char*)d_ws;
    auto alignp = [&]() { p = (char*)(((uintptr_t)p + 255) & ~(uintptr_t)255); };
    auto alloc_f = [&](size_t n) { alignp(); float* r = (float*)p; p += n * 4; return r; };
    auto alloc_h = [&](size_t n) { alignp(); unsigned short* r = (unsigned short*)p; p += n * 2; return r; };
    auto alloc_i = [&](size_t n) { alignp(); int* r = (int*)p; p += n * 4; return r; };

    float* xb   = alloc_f((size_t)S_ * H_);
    float* q    = alloc_f((size_t)S_ * NH_ * HD_);
    float* kb   = alloc_f((size_t)S_ * KVH_ * HD_);
    float* vb   = alloc_f((size_t)S_ * KVH_ * HD_);
    float* hid2 = alloc_f((size_t)S_ * H_);
    float* x2   = alloc_f((size_t)S_ * H_);
    unsigned short* hbuf = alloc_h((size_t)S_ * 2 * I_);
    unsigned short* dbuf = alloc_h((size_t)KSLC * S_ * 2 * H_);
    float* wslot= alloc_f((size_t)S_ * 2);
    unsigned short* qbf = alloc_h((size_t)S_ * NH_ * HD_);
    unsigned short* kbf = alloc_h((size_t)S_ * KVH_ * HD_);
    unsigned short* vtb = alloc_h((size_t)KVH_ * HD_ * S_);
    int* cnt   = alloc_i(E_);
    int* elist = alloc_i((size_t)E_ * S_);
    int* eslot = alloc_i((size_t)E_ * S_);
    float* ctx = xb;

    size_t used = (size_t)(p - (char*)d_ws);
    const size_t nW = (size_t)E_ * I_ * H_;
    size_t wbf_bytes = (3 * nW + (size_t)(NH_*HD_ + 2*KVH_*HD_ + H_) * H_) * 2 + 4096;
    bool WB = ws_size > used && (ws_size - used) >= wbf_bytes;

    unsigned short *w1b = nullptr, *w3b = nullptr, *w2b = nullptr;
    unsigned short *wqb = nullptr, *wkb = nullptr, *wvb = nullptr, *wob = nullptr;
    if (WB) {
        w1b = alloc_h(nW); w3b = alloc_h(nW); w2b = alloc_h(nW);
        wqb = alloc_h((size_t)NH_ * HD_ * H_);
        wkb = alloc_h((size_t)KVH_ * HD_ * H_);
        wvb = alloc_h((size_t)KVH_ * HD_ * H_);
        wob = alloc_h((size_t)H_ * NH_ * HD_);
    }

    hipMemsetAsync(cnt, 0, E_ * sizeof(int), stream);

    if (WB) {
        conv_bf16<<<2048, 256, 0, stream>>>(w1, w1b, (long)(nW / 8));
        conv_bf16<<<2048, 256, 0, stream>>>(w3, w3b, (long)(nW / 8));
        conv_bf16<<<2048, 256, 0, stream>>>(w2, w2b, (long)(nW / 8));
        conv_bf16<<<512, 256, 0, stream>>>(wq, wqb, (long)((size_t)NH_*HD_*H_ / 8));
        conv_bf16<<<512, 256, 0, stream>>>(wk, wkb, (long)((size_t)KVH_*HD_*H_ / 8));
        conv_bf16<<<512, 256, 0, stream>>>(wv, wvb, (long)((size_t)KVH_*HD_*H_ / 8));
        conv_bf16<<<512, 256, 0, stream>>>(wo, wob, (long)((size_t)H_*NH_*HD_ / 8));
    }

    rmsnorm_k<<<S_, 256, 0, stream>>>(hidden, ln1, xb);

    if (WB) {
        dense_mfma<true><<<dim3(8, 16),  256, 0, stream>>>(xb, wqb, nullptr, q,  S_, NH_ * HD_, H_);
        dense_mfma<true><<<dim3(4, 16),  256, 0, stream>>>(xb, wkb, nullptr, kb, S_, KVH_ * HD_, H_);
        dense_mfma<true><<<dim3(4, 16),  256, 0, stream>>>(xb, wvb, nullptr, vb, S_, KVH_ * HD_, H_);
    } else {
        dense_mfma<false><<<dim3(8, 16), 256, 0, stream>>>(xb, wq, nullptr, q,  S_, NH_ * HD_, H_);
        dense_mfma<false><<<dim3(4, 16), 256, 0, stream>>>(xb, wk, nullptr, kb, S_, KVH_ * HD_, H_);
        dense_mfma<false><<<dim3(4, 16), 256, 0, stream>>>(xb, wv, nullptr, vb, S_, KVH_ * HD_, H_);
    }
    {
        int tot = S_ * (NH_ + KVH_) * 32;
        rope_conv<<<SDIV(tot, 256), 256, 0, stream>>>(q, kb, qbf, kbf);
    }
    v_trans<<<dim3(S_ / 64, KVH_), 256, 0, stream>>>(vb, vtb);
    attn_mfma<<<dim3(16, NH_, 2), 256, 0, stream>>>(qbf, kbf, vtb, ctx);

    if (WB)
        dense_mfma<true><<<dim3(8, 16),  256, 0, stream>>>(ctx, wob, hidden, hid2, S_, H_, NH_ * HD_);
    else
        dense_mfma<false><<<dim3(8, 16), 256, 0, stream>>>(ctx, wo, hidden, hid2, S_, H_, NH_ * HD_);

    rmsnorm_k<<<S_, 256, 0, stream>>>(hid2, ln2, x2);
    router_k<<<S_, 64, 0, stream>>>(x2, gw, cnt, elist, eslot, wslot);

    if (WB) {
        moe_up_mfma<true><<<dim3(I_ / 128, S_ / 128, E_), 256, 0, stream>>>(x2, w1b, w3b, cnt, elist, eslot, hbuf);
        moe_dn_mfma<true><<<dim3(H_ / 128, S_ / 128, E_ * KSLC), 256, 0, stream>>>(hbuf, w2b, cnt, eslot, dbuf);
    } else {
        moe_up_mfma<false><<<dim3(I_ / 128, S_ / 128, E_), 256, 0, stream>>>(x2, w1, w3, cnt, elist, eslot, hbuf);
        moe_dn_mfma<false><<<dim3(H_ / 128, S_ / 128, E_ * KSLC), 256, 0, stream>>>(hbuf, w2, cnt, eslot, dbuf);
    }
    combine_k<<<SDIV(S_ * H_, 256), 256, 0, stream>>>(hid2, dbuf, wslot, out);
}

// Round 7
// 639.681 us; speedup vs baseline: 5.1326x; 1.0702x over previous
//
#include <hip/hip_runtime.h>
#include <hip/hip_bf16.h>
#include <math.h>

constexpr int S_ = 2048, H_ = 1024, NH_ = 16, KVH_ = 8, HD_ = 64;
constexpr int E_ = 8, I_ = 3584;
constexpr int KSLC = 4;                 // split-K slices for MoE down
constexpr float EPS_ = 1e-6f;
constexpr float THETA_ = 1000000.0f;

#define SDIV(a,b) (((a)+(b)-1)/(b))

typedef __attribute__((ext_vector_type(8))) short bf16x8;
typedef __attribute__((ext_vector_type(4))) float f32x4;

__device__ inline unsigned pkbf(float a, float b) {
    unsigned r;
    asm("v_cvt_pk_bf16_f32 %0, %1, %2" : "=v"(r) : "v"(a), "v"(b));
    return r;
}
__device__ inline unsigned short f2bf(float f) {
    unsigned u = __float_as_uint(f);
    u += 0x7FFF + ((u >> 16) & 1);
    return (unsigned short)(u >> 16);
}
__device__ inline float bf2f(unsigned short v) {
    return __uint_as_float((unsigned)v << 16);
}

template<bool WB>
__device__ inline int4 loadW16(const void* W, size_t elemOff) {
    if constexpr (WB) {
        return *(const int4*)((const unsigned short*)W + elemOff);
    } else {
        const float* s = (const float*)W + elemOff;
        float4 f0 = *(const float4*)s, f1 = *(const float4*)(s + 4);
        return make_int4(pkbf(f0.x, f0.y), pkbf(f0.z, f0.w),
                         pkbf(f1.x, f1.y), pkbf(f1.z, f1.w));
    }
}

// ---------------- fp32 -> bf16 bulk convert
__global__ __launch_bounds__(256) void conv_bf16(const float* __restrict__ in,
                                                 unsigned short* __restrict__ out, long n8)
{
    long i = (long)blockIdx.x * 256 + threadIdx.x;
    long stride = (long)gridDim.x * 256;
    for (; i < n8; i += stride) {
        const float* s = in + i * 8;
        float4 f0 = *(const float4*)s, f1 = *(const float4*)(s + 4);
        *(int4*)(out + i * 8) = make_int4(pkbf(f0.x, f0.y), pkbf(f0.z, f0.w),
                                          pkbf(f1.x, f1.y), pkbf(f1.z, f1.w));
    }
}

// ---------------- RMSNorm
__global__ __launch_bounds__(256) void rmsnorm_k(const float* __restrict__ x,
                                                 const float* __restrict__ w,
                                                 float* __restrict__ out)
{
    int row = blockIdx.x;
    int tid = threadIdx.x;
    const float* xr = x + (size_t)row * H_;
    float4 v = *(const float4*)&xr[tid * 4];
    float ss = v.x*v.x + v.y*v.y + v.z*v.z + v.w*v.w;
#pragma unroll
    for (int off = 32; off > 0; off >>= 1) ss += __shfl_xor(ss, off);
    __shared__ float red[4];
    if ((tid & 63) == 0) red[tid >> 6] = ss;
    __syncthreads();
    float tot = red[0] + red[1] + red[2] + red[3];
    float r = rsqrtf(tot / (float)H_ + EPS_);
    float4 wv = *(const float4*)&w[tid * 4];
    float4 o;
    o.x = v.x * r * wv.x; o.y = v.y * r * wv.y;
    o.z = v.z * r * wv.z; o.w = v.w * r * wv.w;
    *(float4*)&out[(size_t)row * H_ + tid * 4] = o;
}

// ---------------- Dense bf16-MFMA GEMM: C[M,N] = (Res?) + A[M,K]*B[N,K]^T
template<bool WB>
__global__ __launch_bounds__(256) void dense_mfma(const float* __restrict__ A,
                                                  const void* __restrict__ Bw,
                                                  const float* __restrict__ Res,
                                                  float* __restrict__ C,
                                                  int M, int N, int K)
{
    __shared__ char As[16384], Bs[16384];
    int tid = threadIdx.x;
    int m0 = blockIdx.y * 128, n0 = blockIdx.x * 128;
    int lane = tid & 63, w = tid >> 6, wm = w >> 1, wn = w & 1;
    int lm = lane & 15, lk = lane >> 4;

    int4 rA[4], rB[4];
    auto loadAll = [&](int kb) {
#pragma unroll
        for (int it = 0; it < 4; ++it) {
            int g = tid + it * 256, row = g >> 3, kg = g & 7;
            const float* s = A + (size_t)(m0 + row) * K + kb + kg * 8;
            float4 f0 = *(const float4*)s, f1 = *(const float4*)(s + 4);
            rA[it] = make_int4(pkbf(f0.x, f0.y), pkbf(f0.z, f0.w),
                               pkbf(f1.x, f1.y), pkbf(f1.z, f1.w));
            rB[it] = loadW16<WB>(Bw, (size_t)(n0 + row) * K + kb + kg * 8);
        }
    };
    auto writeAll = [&]() {
#pragma unroll
        for (int it = 0; it < 4; ++it) {
            int g = tid + it * 256, row = g >> 3, kg = g & 7;
            int byte = row * 128 + ((kg * 16) ^ ((row & 7) << 4));
            *(int4*)(As + byte) = rA[it];
            *(int4*)(Bs + byte) = rB[it];
        }
    };

    f32x4 z = {0.f, 0.f, 0.f, 0.f};
    f32x4 acc[4][4];
#pragma unroll
    for (int mf = 0; mf < 4; ++mf)
#pragma unroll
        for (int nf = 0; nf < 4; ++nf) acc[mf][nf] = z;

    loadAll(0);
    for (int kt = 0; kt < K / 64; ++kt) {
        __syncthreads();
        writeAll();
        __syncthreads();
        if (kt + 1 < K / 64) loadAll((kt + 1) * 64);
#pragma unroll
        for (int ks = 0; ks < 2; ++ks) {
            bf16x8 af[4];
#pragma unroll
            for (int mf = 0; mf < 4; ++mf) {
                int row = wm * 64 + mf * 16 + lm;
                af[mf] = *(const bf16x8*)(As + row * 128 + ((ks * 64 + lk * 16) ^ ((row & 7) << 4)));
            }
#pragma unroll
            for (int nf = 0; nf < 4; ++nf) {
                int brow = wn * 64 + nf * 16 + lm;
                bf16x8 bf = *(const bf16x8*)(Bs + brow * 128 + ((ks * 64 + lk * 16) ^ ((brow & 7) << 4)));
#pragma unroll
                for (int mf = 0; mf < 4; ++mf)
                    acc[mf][nf] = __builtin_amdgcn_mfma_f32_16x16x32_bf16(af[mf], bf, acc[mf][nf], 0, 0, 0);
            }
        }
    }

#pragma unroll
    for (int mf = 0; mf < 4; ++mf)
#pragma unroll
        for (int nf = 0; nf < 4; ++nf) {
            int col = n0 + wn * 64 + nf * 16 + lm;
#pragma unroll
            for (int j = 0; j < 4; ++j) {
                int row = m0 + wm * 64 + mf * 16 + lk * 4 + j;
                float r = Res ? Res[(size_t)row * N + col] : 0.0f;
                C[(size_t)row * N + col] = acc[mf][nf][j] + r;
            }
        }
}

// ---------------- RoPE + bf16 convert. Q pre-scaled by 1/sqrt(HD).
__global__ __launch_bounds__(256) void rope_conv(const float* __restrict__ q,
                                                 const float* __restrict__ k,
                                                 unsigned short* __restrict__ qbf,
                                                 unsigned short* __restrict__ kbf)
{
    int idx = blockIdx.x * 256 + threadIdx.x;
    const int totq = S_ * NH_ * 32;
    const int tot = totq + S_ * KVH_ * 32;
    if (idx >= tot) return;
    const float* base; unsigned short* obase; int s, di; float sc;
    if (idx < totq) {
        s = idx / (NH_ * 32); int r = idx % (NH_ * 32);
        size_t o = ((size_t)s * NH_ + (r >> 5)) * HD_;
        base = q + o; obase = qbf + o; di = r & 31; sc = 0.125f;
    } else {
        int j2 = idx - totq;
        s = j2 / (KVH_ * 32); int r = j2 % (KVH_ * 32);
        size_t o = ((size_t)s * KVH_ + (r >> 5)) * HD_;
        base = k + o; obase = kbf + o; di = r & 31; sc = 1.0f;
    }
    float invf = powf(THETA_, -(2.0f * di) / (float)HD_);
    float ang = (float)s * invf;
    float c = cosf(ang), sn = sinf(ang);
    float x0 = base[di], x1 = base[di + 32];
    obase[di]      = f2bf((x0 * c - x1 * sn) * sc);
    obase[di + 32] = f2bf((x1 * c + x0 * sn) * sc);
}

// ---------------- V transpose: vtb[kvh][d][t0+slot] = bf16(V[t0+key][kvh][d])
__global__ __launch_bounds__(256) void v_trans(const float* __restrict__ v,
                                               unsigned short* __restrict__ vtb)
{
    int t0 = blockIdx.x * 64, kvh = blockIdx.y;
    __shared__ unsigned short T[64][64];
    int tid = threadIdx.x;
    int k = tid >> 2, d0 = (tid & 3) * 16;
    const float* src = v + ((size_t)(t0 + k) * KVH_ + kvh) * HD_ + d0;
#pragma unroll
    for (int x = 0; x < 4; ++x) {
        float4 f = *(const float4*)(src + x * 4);
        T[k][d0 + x*4 + 0] = f2bf(f.x);
        T[k][d0 + x*4 + 1] = f2bf(f.y);
        T[k][d0 + x*4 + 2] = f2bf(f.z);
        T[k][d0 + x*4 + 3] = f2bf(f.w);
    }
    __syncthreads();
    int d = tid >> 2, s0 = (tid & 3) * 16;
    unsigned short tmp[16] __attribute__((aligned(16)));
#pragma unroll
    for (int x = 0; x < 16; ++x) {
        int s = s0 + x;
        int key = 16 * (s & 3) + (s >> 2);
        tmp[x] = T[key][d];
    }
    unsigned short* dst = vtb + ((size_t)kvh * HD_ + d) * S_ + t0 + s0;
    *(int4*)(dst)     = *(int4*)(tmp);
    *(int4*)(dst + 8) = *(int4*)(tmp + 8);
}

// ---------------- MFMA flash attention
__global__ __launch_bounds__(256) void attn_mfma(const unsigned short* __restrict__ qbf,
                                                 const unsigned short* __restrict__ kbf,
                                                 const unsigned short* __restrict__ vtb,
                                                 float* __restrict__ ctx)
{
    __shared__ char Ps[4 * 2048];
    int pair = blockIdx.x, h = blockIdx.y, z = blockIdx.z;
    int qb = z ? (31 - pair) : pair;
    int q0 = qb * 64;
    int kvh = h >> 1;
    int tid = threadIdx.x;
    int w = tid >> 6, lane = tid & 63;
    int lm = lane & 15, lk = lane >> 4;
    char* myP = Ps + w * 2048;

    bf16x8 qf[2];
    const unsigned short* qrow = qbf + ((size_t)(q0 + w * 16 + lm) * NH_ + h) * HD_;
#pragma unroll
    for (int ks = 0; ks < 2; ++ks)
        qf[ks] = *(const bf16x8*)(qrow + ks * 32 + lk * 8);

    float m_[4], l_[4];
    f32x4 o_[4];
#pragma unroll
    for (int j = 0; j < 4; ++j) { m_[j] = -1e30f; l_[j] = 0.f; }
    f32x4 zf = {0.f, 0.f, 0.f, 0.f};
#pragma unroll
    for (int nd = 0; nd < 4; ++nd) o_[nd] = zf;

    for (int t0 = 0; t0 <= q0; t0 += 64) {
        f32x4 s[4];
#pragma unroll
        for (int nf = 0; nf < 4; ++nf) {
            const unsigned short* krow = kbf + ((size_t)(t0 + nf * 16 + lm) * KVH_ + kvh) * HD_;
            bf16x8 k0 = *(const bf16x8*)(krow + lk * 8);
            bf16x8 k1 = *(const bf16x8*)(krow + 32 + lk * 8);
            f32x4 acc = zf;
            acc = __builtin_amdgcn_mfma_f32_16x16x32_bf16(qf[0], k0, acc, 0, 0, 0);
            acc = __builtin_amdgcn_mfma_f32_16x16x32_bf16(qf[1], k1, acc, 0, 0, 0);
            s[nf] = acc;
        }
        if (t0 == q0) {
#pragma unroll
            for (int nf = 0; nf < 4; ++nf)
#pragma unroll
                for (int j = 0; j < 4; ++j) {
                    int key = nf * 16 + lm, qq = w * 16 + lk * 4 + j;
                    if (key > qq) s[nf][j] = -1e30f;
                }
        }
        float p_[4][4];
#pragma unroll
        for (int j = 0; j < 4; ++j) {
            float mx = fmaxf(fmaxf(s[0][j], s[1][j]), fmaxf(s[2][j], s[3][j]));
#pragma unroll
            for (int off = 8; off > 0; off >>= 1) mx = fmaxf(mx, __shfl_xor(mx, off));
            float nm = fmaxf(m_[j], mx);
            float rs = __expf(m_[j] - nm);
            float sum = 0.f;
#pragma unroll
            for (int nf = 0; nf < 4; ++nf) {
                float pv = __expf(s[nf][j] - nm);
                p_[nf][j] = pv; sum += pv;
            }
#pragma unroll
            for (int off = 8; off > 0; off >>= 1) sum += __shfl_xor(sum, off);
            l_[j] = l_[j] * rs + sum;
            m_[j] = nm;
#pragma unroll
            for (int nd = 0; nd < 4; ++nd) o_[nd][j] *= rs;
        }
#pragma unroll
        for (int j = 0; j < 4; ++j) {
            int r = lk * 4 + j;
            unsigned lo = pkbf(p_[0][j], p_[1][j]);
            unsigned hi = pkbf(p_[2][j], p_[3][j]);
            int byte = (lm * 8) ^ ((r & 7) << 4);
            *(uint2*)(myP + r * 128 + byte) = make_uint2(lo, hi);
        }
#pragma unroll
        for (int ks = 0; ks < 2; ++ks) {
            int byte = (ks * 64 + lk * 16) ^ ((lm & 7) << 4);
            bf16x8 pA = *(const bf16x8*)(myP + lm * 128 + byte);
#pragma unroll
            for (int nd = 0; nd < 4; ++nd) {
                const unsigned short* vrow = vtb + ((size_t)kvh * HD_ + nd * 16 + lm) * S_ + t0 + ks * 32 + lk * 8;
                bf16x8 vB = *(const bf16x8*)vrow;
                o_[nd] = __builtin_amdgcn_mfma_f32_16x16x32_bf16(pA, vB, o_[nd], 0, 0, 0);
            }
        }
    }
#pragma unroll
    for (int nd = 0; nd < 4; ++nd)
#pragma unroll
        for (int j = 0; j < 4; ++j) {
            int r = lk * 4 + j;
            ctx[((size_t)(q0 + w * 16 + r) * NH_ + h) * HD_ + nd * 16 + lm] = o_[nd][j] / l_[j];
        }
}

// ---------------- Router
__global__ __launch_bounds__(64) void router_k(const float* __restrict__ x2,
                                               const float* __restrict__ gw,
                                               int* __restrict__ cnt,
                                               int* __restrict__ elist,
                                               int* __restrict__ eslot,
                                               float* __restrict__ wslot)
{
    int n = blockIdx.x, lane = threadIdx.x;
    float part[E_];
#pragma unroll
    for (int e = 0; e < E_; ++e) part[e] = 0.f;
    const float* xr = x2 + (size_t)n * H_;
    for (int j = lane; j < H_; j += 64) {
        float xv = xr[j];
#pragma unroll
        for (int e = 0; e < E_; ++e) part[e] = fmaf(xv, gw[e * H_ + j], part[e]);
    }
#pragma unroll
    for (int e = 0; e < E_; ++e)
#pragma unroll
        for (int off = 32; off > 0; off >>= 1) part[e] += __shfl_xor(part[e], off);
    if (lane == 0) {
        float mx = part[0];
#pragma unroll
        for (int e = 1; e < E_; ++e) mx = fmaxf(mx, part[e]);
        float rw[E_]; float ssum = 0.f;
#pragma unroll
        for (int e = 0; e < E_; ++e) { rw[e] = expf(part[e] - mx); ssum += rw[e]; }
#pragma unroll
        for (int e = 0; e < E_; ++e) rw[e] /= ssum;
        float best = -1.f; int ba = 0, bb = 1;
        for (int a = 0; a < E_; ++a)
            for (int b = a + 1; b < E_; ++b) {
                float scv = rw[a] + rw[b];
                if (scv > best) { best = scv; ba = a; bb = b; }
            }
        float wa = rw[ba], wb = rw[bb], wsum = wa + wb;
        wa /= wsum; wb /= wsum;
        int p = atomicAdd(&cnt[ba], 1);
        elist[ba * S_ + p] = n; eslot[ba * S_ + p] = 2 * n;
        p = atomicAdd(&cnt[bb], 1);
        elist[bb * S_ + p] = n; eslot[bb * S_ + p] = 2 * n + 1;
        wslot[2 * n] = wa; wslot[2 * n + 1] = wb;
    }
}

// ---------------- MoE up (bf16 MFMA), 128(M) x 64(N) tile, BK=64.
// Narrow N-tile: acc1[4][2]+acc3[4][2] = 64 regs -> higher occupancy.
template<bool WB>
__global__ __launch_bounds__(256) void moe_up_mfma(const float* __restrict__ x2,
                                                   const void* __restrict__ w1,
                                                   const void* __restrict__ w3,
                                                   const int* __restrict__ cnt,
                                                   const int* __restrict__ elist,
                                                   const int* __restrict__ eslot,
                                                   unsigned short* __restrict__ hbuf)
{
    int e = blockIdx.z;
    int c = cnt[e];
    int p0 = blockIdx.y * 128;
    if (p0 >= c) return;
    int i0 = blockIdx.x * 64;
    int tid = threadIdx.x;

    __shared__ char As[16384], B1s[8192], B3s[8192];
    __shared__ int rowtokS[128], rowslotS[128];
    if (tid < 128) {
        int p = min(p0 + tid, c - 1);
        rowtokS[tid]  = elist[e * S_ + p];
        rowslotS[tid] = eslot[e * S_ + p];
    }
    __syncthreads();

    int lane = tid & 63, w = tid >> 6, wm = w >> 1, wn = w & 1;
    int lm = lane & 15, lk = lane >> 4;
    size_t wbase = (size_t)e * I_ * H_;

    int4 rA[4], rB1[2], rB3[2];
    auto loadAll = [&](int kb) {
#pragma unroll
        for (int it = 0; it < 4; ++it) {
            int g = tid + it * 256, row = g >> 3, kg = g & 7;
            const float* s = x2 + (size_t)rowtokS[row] * H_ + kb + kg * 8;
            float4 f0 = *(const float4*)s, f1 = *(const float4*)(s + 4);
            rA[it] = make_int4(pkbf(f0.x, f0.y), pkbf(f0.z, f0.w),
                               pkbf(f1.x, f1.y), pkbf(f1.z, f1.w));
        }
#pragma unroll
        for (int it = 0; it < 2; ++it) {
            int g = tid + it * 256, row = g >> 3, kg = g & 7;
            size_t off = wbase + (size_t)(i0 + row) * H_ + kb + kg * 8;
            rB1[it] = loadW16<WB>(w1, off);
            rB3[it] = loadW16<WB>(w3, off);
        }
    };
    auto writeAll = [&]() {
#pragma unroll
        for (int it = 0; it < 4; ++it) {
            int g = tid + it * 256, row = g >> 3, kg = g & 7;
            int byte = row * 128 + ((kg * 16) ^ ((row & 7) << 4));
            *(int4*)(As + byte) = rA[it];
        }
#pragma unroll
        for (int it = 0; it < 2; ++it) {
            int g = tid + it * 256, row = g >> 3, kg = g & 7;
            int byte = row * 128 + ((kg * 16) ^ ((row & 7) << 4));
            *(int4*)(B1s + byte) = rB1[it];
            *(int4*)(B3s + byte) = rB3[it];
        }
    };

    f32x4 z = {0.f, 0.f, 0.f, 0.f};
    f32x4 acc1[4][2], acc3[4][2];
#pragma unroll
    for (int mf = 0; mf < 4; ++mf)
#pragma unroll
        for (int nf = 0; nf < 2; ++nf) { acc1[mf][nf] = z; acc3[mf][nf] = z; }

    loadAll(0);
    for (int kt = 0; kt < H_ / 64; ++kt) {
        __syncthreads();
        writeAll();
        __syncthreads();
        if (kt + 1 < H_ / 64) loadAll((kt + 1) * 64);
#pragma unroll
        for (int ks = 0; ks < 2; ++ks) {
            bf16x8 af[4];
#pragma unroll
            for (int mf = 0; mf < 4; ++mf) {
                int row = wm * 64 + mf * 16 + lm;
                af[mf] = *(const bf16x8*)(As + row * 128 + ((ks * 64 + lk * 16) ^ ((row & 7) << 4)));
            }
#pragma unroll
            for (int nf = 0; nf < 2; ++nf) {
                int brow = wn * 32 + nf * 16 + lm;
                int bby = brow * 128 + ((ks * 64 + lk * 16) ^ ((brow & 7) << 4));
                bf16x8 b1 = *(const bf16x8*)(B1s + bby);
                bf16x8 b3 = *(const bf16x8*)(B3s + bby);
#pragma unroll
                for (int mf = 0; mf < 4; ++mf) {
                    acc1[mf][nf] = __builtin_amdgcn_mfma_f32_16x16x32_bf16(af[mf], b1, acc1[mf][nf], 0, 0, 0);
                    acc3[mf][nf] = __builtin_amdgcn_mfma_f32_16x16x32_bf16(af[mf], b3, acc3[mf][nf], 0, 0, 0);
                }
            }
        }
    }

#pragma unroll
    for (int mf = 0; mf < 4; ++mf)
#pragma unroll
        for (int nf = 0; nf < 2; ++nf) {
            int coli = i0 + wn * 32 + nf * 16 + lm;
#pragma unroll
            for (int j = 0; j < 4; ++j) {
                int rloc = wm * 64 + mf * 16 + lk * 4 + j;
                if (p0 + rloc < c) {
                    float h1 = acc1[mf][nf][j];
                    float val = h1 / (1.f + __expf(-h1)) * acc3[mf][nf][j];
                    hbuf[(size_t)rowslotS[rloc] * I_ + coli] = f2bf(val);
                }
            }
        }
}

// ---------------- MoE down (bf16 MFMA), 128x128, BK=64, SPLIT-K over KSLC slices.
template<bool WB>
__global__ __launch_bounds__(256) void moe_dn_mfma(const unsigned short* __restrict__ hbuf,
                                                   const void* __restrict__ w2,
                                                   const int* __restrict__ cnt,
                                                   const int* __restrict__ eslot,
                                                   unsigned short* __restrict__ dbuf)
{
    int e = blockIdx.z >> 2;           // KSLC == 4
    int slice = blockIdx.z & 3;
    int c = cnt[e];
    int p0 = blockIdx.y * 128;
    if (p0 >= c) return;
    int h0 = blockIdx.x * 128;
    int tid = threadIdx.x;
    const int kb0 = slice * (I_ / KSLC);     // 896-wide slice

    __shared__ char As[16384], Bs[16384];
    __shared__ int rowslotS[128];
    if (tid < 128) rowslotS[tid] = eslot[e * S_ + min(p0 + tid, c - 1)];
    __syncthreads();

    int lane = tid & 63, w = tid >> 6, wm = w >> 1, wn = w & 1;
    int lm = lane & 15, lk = lane >> 4;
    size_t wbase = (size_t)e * H_ * I_;

    int4 rA[4], rB[4];
    auto loadAll = [&](int kb) {
#pragma unroll
        for (int it = 0; it < 4; ++it) {
            int g = tid + it * 256, row = g >> 3, kg = g & 7;
            rA[it] = *(const int4*)(hbuf + (size_t)rowslotS[row] * I_ + kb + kg * 8);
            rB[it] = loadW16<WB>(w2, wbase + (size_t)(h0 + row) * I_ + kb + kg * 8);
        }
    };
    auto writeAll = [&]() {
#pragma unroll
        for (int it = 0; it < 4; ++it) {
            int g = tid + it * 256, row = g >> 3, kg = g & 7;
            int byte = row * 128 + ((kg * 16) ^ ((row & 7) << 4));
            *(int4*)(As + byte) = rA[it];
            *(int4*)(Bs + byte) = rB[it];
        }
    };

    f32x4 z = {0.f, 0.f, 0.f, 0.f};
    f32x4 acc[4][4];
#pragma unroll
    for (int mf = 0; mf < 4; ++mf)
#pragma unroll
        for (int nf = 0; nf < 4; ++nf) acc[mf][nf] = z;

    loadAll(kb0);
    const int NKT = (I_ / KSLC) / 64;        // 14
    for (int kt = 0; kt < NKT; ++kt) {
        __syncthreads();
        writeAll();
        __syncthreads();
        if (kt + 1 < NKT) loadAll(kb0 + (kt + 1) * 64);
#pragma unroll
        for (int ks = 0; ks < 2; ++ks) {
            bf16x8 af[4];
#pragma unroll
            for (int mf = 0; mf < 4; ++mf) {
                int row = wm * 64 + mf * 16 + lm;
                af[mf] = *(const bf16x8*)(As + row * 128 + ((ks * 64 + lk * 16) ^ ((row & 7) << 4)));
            }
#pragma unroll
            for (int nf = 0; nf < 4; ++nf) {
                int brow = wn * 64 + nf * 16 + lm;
                bf16x8 bf = *(const bf16x8*)(Bs + brow * 128 + ((ks * 64 + lk * 16) ^ ((brow & 7) << 4)));
#pragma unroll
                for (int mf = 0; mf < 4; ++mf)
                    acc[mf][nf] = __builtin_amdgcn_mfma_f32_16x16x32_bf16(af[mf], bf, acc[mf][nf], 0, 0, 0);
            }
        }
    }

    unsigned short* dslice = dbuf + (size_t)slice * S_ * 2 * H_;
#pragma unroll
    for (int mf = 0; mf < 4; ++mf)
#pragma unroll
        for (int nf = 0; nf < 4; ++nf) {
            int colh = h0 + wn * 64 + nf * 16 + lm;
#pragma unroll
            for (int j = 0; j < 4; ++j) {
                int rloc = wm * 64 + mf * 16 + lk * 4 + j;
                if (p0 + rloc < c)
                    dslice[(size_t)rowslotS[rloc] * H_ + colh] = f2bf(acc[mf][nf][j]);
            }
        }
}

// ---------------- Final combine: out = hid2 + Σ_slot w_slot * Σ_slice dbuf
__global__ __launch_bounds__(256) void combine_k(const float* __restrict__ hid2,
                                                 const unsigned short* __restrict__ dbuf,
                                                 const float* __restrict__ wslot,
                                                 float* __restrict__ out)
{
    int idx = blockIdx.x * 256 + threadIdx.x;
    if (idx >= S_ * H_) return;
    int n = idx >> 10;
    int hcol = idx & (H_ - 1);
    float s0 = 0.f, s1 = 0.f;
#pragma unroll
    for (int sl = 0; sl < KSLC; ++sl) {
        const unsigned short* base = dbuf + (size_t)sl * S_ * 2 * H_;
        s0 += bf2f(base[(size_t)(2 * n)     * H_ + hcol]);
        s1 += bf2f(base[(size_t)(2 * n + 1) * H_ + hcol]);
    }
    out[idx] = hid2[idx] + wslot[2 * n] * s0 + wslot[2 * n + 1] * s1;
}

extern "C" void kernel_launch(void* const* d_in, const int* in_sizes, int n_in,
                              void* d_out, int out_size, void* d_ws, size_t ws_size,
                              hipStream_t stream)
{
    const float* hidden = (const float*)d_in[0];
    const float* ln1    = (const float*)d_in[1];
    const float* ln2    = (const float*)d_in[2];
    const float* wq     = (const float*)d_in[3];
    const float* wk     = (const float*)d_in[4];
    const float* wv     = (const float*)d_in[5];
    const float* wo     = (const float*)d_in[6];
    const float* gw     = (const float*)d_in[7];
    const float* w1     = (const float*)d_in[8];
    const float* w2     = (const float*)d_in[9];
    const float* w3     = (const float*)d_in[10];
    float* out = (float*)d_out;

    char* p = (char*)d_ws;
    auto alignp = [&]() { p = (char*)(((uintptr_t)p + 255) & ~(uintptr_t)255); };
    auto alloc_f = [&](size_t n) { alignp(); float* r = (float*)p; p += n * 4; return r; };
    auto alloc_h = [&](size_t n) { alignp(); unsigned short* r = (unsigned short*)p; p += n * 2; return r; };
    auto alloc_i = [&](size_t n) { alignp(); int* r = (int*)p; p += n * 4; return r; };

    float* xb   = alloc_f((size_t)S_ * H_);
    float* q    = alloc_f((size_t)S_ * NH_ * HD_);
    float* kb   = alloc_f((size_t)S_ * KVH_ * HD_);
    float* vb   = alloc_f((size_t)S_ * KVH_ * HD_);
    float* hid2 = alloc_f((size_t)S_ * H_);
    float* x2   = alloc_f((size_t)S_ * H_);
    unsigned short* hbuf = alloc_h((size_t)S_ * 2 * I_);
    unsigned short* dbuf = alloc_h((size_t)KSLC * S_ * 2 * H_);
    float* wslot= alloc_f((size_t)S_ * 2);
    unsigned short* qbf = alloc_h((size_t)S_ * NH_ * HD_);
    unsigned short* kbf = alloc_h((size_t)S_ * KVH_ * HD_);
    unsigned short* vtb = alloc_h((size_t)KVH_ * HD_ * S_);
    int* cnt   = alloc_i(E_);
    int* elist = alloc_i((size_t)E_ * S_);
    int* eslot = alloc_i((size_t)E_ * S_);
    float* ctx = xb;

    size_t used = (size_t)(p - (char*)d_ws);
    const size_t nW = (size_t)E_ * I_ * H_;
    size_t wbf_bytes = (3 * nW + (size_t)(NH_*HD_ + 2*KVH_*HD_ + H_) * H_) * 2 + 4096;
    bool WB = ws_size > used && (ws_size - used) >= wbf_bytes;

    unsigned short *w1b = nullptr, *w3b = nullptr, *w2b = nullptr;
    unsigned short *wqb = nullptr, *wkb = nullptr, *wvb = nullptr, *wob = nullptr;
    if (WB) {
        w1b = alloc_h(nW); w3b = alloc_h(nW); w2b = alloc_h(nW);
        wqb = alloc_h((size_t)NH_ * HD_ * H_);
        wkb = alloc_h((size_t)KVH_ * HD_ * H_);
        wvb = alloc_h((size_t)KVH_ * HD_ * H_);
        wob = alloc_h((size_t)H_ * NH_ * HD_);
    }

    hipMemsetAsync(cnt, 0, E_ * sizeof(int), stream);

    if (WB) {
        conv_bf16<<<2048, 256, 0, stream>>>(w1, w1b, (long)(nW / 8));
        conv_bf16<<<2048, 256, 0, stream>>>(w3, w3b, (long)(nW / 8));
        conv_bf16<<<2048, 256, 0, stream>>>(w2, w2b, (long)(nW / 8));
        conv_bf16<<<512, 256, 0, stream>>>(wq, wqb, (long)((size_t)NH_*HD_*H_ / 8));
        conv_bf16<<<512, 256, 0, stream>>>(wk, wkb, (long)((size_t)KVH_*HD_*H_ / 8));
        conv_bf16<<<512, 256, 0, stream>>>(wv, wvb, (long)((size_t)KVH_*HD_*H_ / 8));
        conv_bf16<<<512, 256, 0, stream>>>(wo, wob, (long)((size_t)H_*NH_*HD_ / 8));
    }

    rmsnorm_k<<<S_, 256, 0, stream>>>(hidden, ln1, xb);

    if (WB) {
        dense_mfma<true><<<dim3(8, 16),  256, 0, stream>>>(xb, wqb, nullptr, q,  S_, NH_ * HD_, H_);
        dense_mfma<true><<<dim3(4, 16),  256, 0, stream>>>(xb, wkb, nullptr, kb, S_, KVH_ * HD_, H_);
        dense_mfma<true><<<dim3(4, 16),  256, 0, stream>>>(xb, wvb, nullptr, vb, S_, KVH_ * HD_, H_);
    } else {
        dense_mfma<false><<<dim3(8, 16), 256, 0, stream>>>(xb, wq, nullptr, q,  S_, NH_ * HD_, H_);
        dense_mfma<false><<<dim3(4, 16), 256, 0, stream>>>(xb, wk, nullptr, kb, S_, KVH_ * HD_, H_);
        dense_mfma<false><<<dim3(4, 16), 256, 0, stream>>>(xb, wv, nullptr, vb, S_, KVH_ * HD_, H_);
    }
    {
        int tot = S_ * (NH_ + KVH_) * 32;
        rope_conv<<<SDIV(tot, 256), 256, 0, stream>>>(q, kb, qbf, kbf);
    }
    v_trans<<<dim3(S_ / 64, KVH_), 256, 0, stream>>>(vb, vtb);
    attn_mfma<<<dim3(16, NH_, 2), 256, 0, stream>>>(qbf, kbf, vtb, ctx);

    if (WB)
        dense_mfma<true><<<dim3(8, 16),  256, 0, stream>>>(ctx, wob, hidden, hid2, S_, H_, NH_ * HD_);
    else
        dense_mfma<false><<<dim3(8, 16), 256, 0, stream>>>(ctx, wo, hidden, hid2, S_, H_, NH_ * HD_);

    rmsnorm_k<<<S_, 256, 0, stream>>>(hid2, ln2, x2);
    router_k<<<S_, 64, 0, stream>>>(x2, gw, cnt, elist, eslot, wslot);

    if (WB) {
        moe_up_mfma<true><<<dim3(I_ / 64, S_ / 128, E_), 256, 0, stream>>>(x2, w1b, w3b, cnt, elist, eslot, hbuf);
        moe_dn_mfma<true><<<dim3(H_ / 128, S_ / 128, E_ * KSLC), 256, 0, stream>>>(hbuf, w2b, cnt, eslot, dbuf);
    } else {
        moe_up_mfma<false><<<dim3(I_ / 64, S_ / 128, E_), 256, 0, stream>>>(x2, w1, w3, cnt, elist, eslot, hbuf);
        moe_dn_mfma<false><<<dim3(H_ / 128, S_ / 128, E_ * KSLC), 256, 0, stream>>>(hbuf, w2, cnt, eslot, dbuf);
    }
    combine_k<<<SDIV(S_ * H_, 256), 256, 0, stream>>>(hid2, dbuf, wslot, out);
}

// Round 9
// 567.643 us; speedup vs baseline: 5.7839x; 1.1269x over previous
//
#include <hip/hip_runtime.h>
#include <hip/hip_bf16.h>
#include <math.h>

constexpr int S_ = 2048, H_ = 1024, NH_ = 16, KVH_ = 8, HD_ = 64;
constexpr int E_ = 8, I_ = 3584;
constexpr int KSLC = 4;                 // split-K slices for MoE down
constexpr float EPS_ = 1e-6f;
constexpr float THETA_ = 1000000.0f;

#define SDIV(a,b) (((a)+(b)-1)/(b))

typedef __attribute__((ext_vector_type(8))) short bf16x8;
typedef __attribute__((ext_vector_type(4))) float f32x4;

__device__ inline unsigned pkbf(float a, float b) {
    unsigned r;
    asm("v_cvt_pk_bf16_f32 %0, %1, %2" : "=v"(r) : "v"(a), "v"(b));
    return r;
}
__device__ inline unsigned short f2bf(float f) {
    unsigned u = __float_as_uint(f);
    u += 0x7FFF + ((u >> 16) & 1);
    return (unsigned short)(u >> 16);
}
__device__ inline float bf2f(unsigned short v) {
    return __uint_as_float((unsigned)v << 16);
}

// async global->LDS, 16B/lane. LDS base FORCED wave-uniform via readfirstlane;
// lane l lands at base + l*16 (m104 semantics). Global src stays per-lane.
__device__ inline void gload16u(const void* gsrc, char* ldsArr, int uoff) {
    int off = __builtin_amdgcn_readfirstlane(uoff);
    __builtin_amdgcn_global_load_lds(
        (__attribute__((address_space(1))) void*)(gsrc),
        (__attribute__((address_space(3))) void*)(ldsArr + off), 16, 0, 0);
}
// explicit vmcnt drain (belt-and-suspenders before barrier)
__device__ inline void vmdrain() {
    asm volatile("s_waitcnt vmcnt(0)" ::: "memory");
}

template<bool WB>
__device__ inline int4 loadW16(const void* W, size_t elemOff) {
    if constexpr (WB) {
        return *(const int4*)((const unsigned short*)W + elemOff);
    } else {
        const float* s = (const float*)W + elemOff;
        float4 f0 = *(const float4*)s, f1 = *(const float4*)(s + 4);
        return make_int4(pkbf(f0.x, f0.y), pkbf(f0.z, f0.w),
                         pkbf(f1.x, f1.y), pkbf(f1.z, f1.w));
    }
}

// ---------------- fp32 -> bf16 bulk convert
__global__ __launch_bounds__(256) void conv_bf16(const float* __restrict__ in,
                                                 unsigned short* __restrict__ out, long n8)
{
    long i = (long)blockIdx.x * 256 + threadIdx.x;
    long stride = (long)gridDim.x * 256;
    for (; i < n8; i += stride) {
        const float* s = in + i * 8;
        float4 f0 = *(const float4*)s, f1 = *(const float4*)(s + 4);
        *(int4*)(out + i * 8) = make_int4(pkbf(f0.x, f0.y), pkbf(f0.z, f0.w),
                                          pkbf(f1.x, f1.y), pkbf(f1.z, f1.w));
    }
}

// ---------------- RMSNorm (optionally also emits bf16 copy)
__global__ __launch_bounds__(256) void rmsnorm_k(const float* __restrict__ x,
                                                 const float* __restrict__ w,
                                                 float* __restrict__ out,
                                                 unsigned short* __restrict__ outb)
{
    int row = blockIdx.x;
    int tid = threadIdx.x;
    const float* xr = x + (size_t)row * H_;
    float4 v = *(const float4*)&xr[tid * 4];
    float ss = v.x*v.x + v.y*v.y + v.z*v.z + v.w*v.w;
#pragma unroll
    for (int off = 32; off > 0; off >>= 1) ss += __shfl_xor(ss, off);
    __shared__ float red[4];
    if ((tid & 63) == 0) red[tid >> 6] = ss;
    __syncthreads();
    float tot = red[0] + red[1] + red[2] + red[3];
    float r = rsqrtf(tot / (float)H_ + EPS_);
    float4 wv = *(const float4*)&w[tid * 4];
    float4 o;
    o.x = v.x * r * wv.x; o.y = v.y * r * wv.y;
    o.z = v.z * r * wv.z; o.w = v.w * r * wv.w;
    *(float4*)&out[(size_t)row * H_ + tid * 4] = o;
    if (outb) {
        uint2 pk = make_uint2(pkbf(o.x, o.y), pkbf(o.z, o.w));
        *(uint2*)&outb[(size_t)row * H_ + tid * 4] = pk;
    }
}

// ---------------- Dense bf16-MFMA GEMM: C[M,N] = (Res?) + A[M,K]*B[N,K]^T
template<bool WB>
__global__ __launch_bounds__(256) void dense_mfma(const float* __restrict__ A,
                                                  const void* __restrict__ Bw,
                                                  const float* __restrict__ Res,
                                                  float* __restrict__ C,
                                                  int M, int N, int K)
{
    __shared__ char As[16384], Bs[16384];
    int tid = threadIdx.x;
    int m0 = blockIdx.y * 128, n0 = blockIdx.x * 128;
    int lane = tid & 63, w = tid >> 6, wm = w >> 1, wn = w & 1;
    int lm = lane & 15, lk = lane >> 4;

    int4 rA[4], rB[4];
    auto loadAll = [&](int kb) {
#pragma unroll
        for (int it = 0; it < 4; ++it) {
            int g = tid + it * 256, row = g >> 3, kg = g & 7;
            const float* s = A + (size_t)(m0 + row) * K + kb + kg * 8;
            float4 f0 = *(const float4*)s, f1 = *(const float4*)(s + 4);
            rA[it] = make_int4(pkbf(f0.x, f0.y), pkbf(f0.z, f0.w),
                               pkbf(f1.x, f1.y), pkbf(f1.z, f1.w));
            rB[it] = loadW16<WB>(Bw, (size_t)(n0 + row) * K + kb + kg * 8);
        }
    };
    auto writeAll = [&]() {
#pragma unroll
        for (int it = 0; it < 4; ++it) {
            int g = tid + it * 256, row = g >> 3, kg = g & 7;
            int byte = row * 128 + ((kg * 16) ^ ((row & 7) << 4));
            *(int4*)(As + byte) = rA[it];
            *(int4*)(Bs + byte) = rB[it];
        }
    };

    f32x4 z = {0.f, 0.f, 0.f, 0.f};
    f32x4 acc[4][4];
#pragma unroll
    for (int mf = 0; mf < 4; ++mf)
#pragma unroll
        for (int nf = 0; nf < 4; ++nf) acc[mf][nf] = z;

    loadAll(0);
    for (int kt = 0; kt < K / 64; ++kt) {
        __syncthreads();
        writeAll();
        __syncthreads();
        if (kt + 1 < K / 64) loadAll((kt + 1) * 64);
#pragma unroll
        for (int ks = 0; ks < 2; ++ks) {
            bf16x8 af[4];
#pragma unroll
            for (int mf = 0; mf < 4; ++mf) {
                int row = wm * 64 + mf * 16 + lm;
                af[mf] = *(const bf16x8*)(As + row * 128 + ((ks * 64 + lk * 16) ^ ((row & 7) << 4)));
            }
#pragma unroll
            for (int nf = 0; nf < 4; ++nf) {
                int brow = wn * 64 + nf * 16 + lm;
                bf16x8 bf = *(const bf16x8*)(Bs + brow * 128 + ((ks * 64 + lk * 16) ^ ((brow & 7) << 4)));
#pragma unroll
                for (int mf = 0; mf < 4; ++mf)
                    acc[mf][nf] = __builtin_amdgcn_mfma_f32_16x16x32_bf16(af[mf], bf, acc[mf][nf], 0, 0, 0);
            }
        }
    }

#pragma unroll
    for (int mf = 0; mf < 4; ++mf)
#pragma unroll
        for (int nf = 0; nf < 4; ++nf) {
            int col = n0 + wn * 64 + nf * 16 + lm;
#pragma unroll
            for (int j = 0; j < 4; ++j) {
                int row = m0 + wm * 64 + mf * 16 + lk * 4 + j;
                float r = Res ? Res[(size_t)row * N + col] : 0.0f;
                C[(size_t)row * N + col] = acc[mf][nf][j] + r;
            }
        }
}

// ---------------- RoPE + bf16 convert. Q pre-scaled by 1/sqrt(HD).
__global__ __launch_bounds__(256) void rope_conv(const float* __restrict__ q,
                                                 const float* __restrict__ k,
                                                 unsigned short* __restrict__ qbf,
                                                 unsigned short* __restrict__ kbf)
{
    int idx = blockIdx.x * 256 + threadIdx.x;
    const int totq = S_ * NH_ * 32;
    const int tot = totq + S_ * KVH_ * 32;
    if (idx >= tot) return;
    const float* base; unsigned short* obase; int s, di; float sc;
    if (idx < totq) {
        s = idx / (NH_ * 32); int r = idx % (NH_ * 32);
        size_t o = ((size_t)s * NH_ + (r >> 5)) * HD_;
        base = q + o; obase = qbf + o; di = r & 31; sc = 0.125f;
    } else {
        int j2 = idx - totq;
        s = j2 / (KVH_ * 32); int r = j2 % (KVH_ * 32);
        size_t o = ((size_t)s * KVH_ + (r >> 5)) * HD_;
        base = k + o; obase = kbf + o; di = r & 31; sc = 1.0f;
    }
    float invf = powf(THETA_, -(2.0f * di) / (float)HD_);
    float ang = (float)s * invf;
    float c = cosf(ang), sn = sinf(ang);
    float x0 = base[di], x1 = base[di + 32];
    obase[di]      = f2bf((x0 * c - x1 * sn) * sc);
    obase[di + 32] = f2bf((x1 * c + x0 * sn) * sc);
}

// ---------------- V transpose: vtb[kvh][d][t0+slot] = bf16(V[t0+key][kvh][d])
__global__ __launch_bounds__(256) void v_trans(const float* __restrict__ v,
                                               unsigned short* __restrict__ vtb)
{
    int t0 = blockIdx.x * 64, kvh = blockIdx.y;
    __shared__ unsigned short T[64][64];
    int tid = threadIdx.x;
    int k = tid >> 2, d0 = (tid & 3) * 16;
    const float* src = v + ((size_t)(t0 + k) * KVH_ + kvh) * HD_ + d0;
#pragma unroll
    for (int x = 0; x < 4; ++x) {
        float4 f = *(const float4*)(src + x * 4);
        T[k][d0 + x*4 + 0] = f2bf(f.x);
        T[k][d0 + x*4 + 1] = f2bf(f.y);
        T[k][d0 + x*4 + 2] = f2bf(f.z);
        T[k][d0 + x*4 + 3] = f2bf(f.w);
    }
    __syncthreads();
    int d = tid >> 2, s0 = (tid & 3) * 16;
    unsigned short tmp[16] __attribute__((aligned(16)));
#pragma unroll
    for (int x = 0; x < 16; ++x) {
        int s = s0 + x;
        int key = 16 * (s & 3) + (s >> 2);
        tmp[x] = T[key][d];
    }
    unsigned short* dst = vtb + ((size_t)kvh * HD_ + d) * S_ + t0 + s0;
    *(int4*)(dst)     = *(int4*)(tmp);
    *(int4*)(dst + 8) = *(int4*)(tmp + 8);
}

// ---------------- MFMA flash attention
__global__ __launch_bounds__(256) void attn_mfma(const unsigned short* __restrict__ qbf,
                                                 const unsigned short* __restrict__ kbf,
                                                 const unsigned short* __restrict__ vtb,
                                                 float* __restrict__ ctx)
{
    __shared__ char Ps[4 * 2048];
    int pair = blockIdx.x, h = blockIdx.y, z = blockIdx.z;
    int qb = z ? (31 - pair) : pair;
    int q0 = qb * 64;
    int kvh = h >> 1;
    int tid = threadIdx.x;
    int w = tid >> 6, lane = tid & 63;
    int lm = lane & 15, lk = lane >> 4;
    char* myP = Ps + w * 2048;

    bf16x8 qf[2];
    const unsigned short* qrow = qbf + ((size_t)(q0 + w * 16 + lm) * NH_ + h) * HD_;
#pragma unroll
    for (int ks = 0; ks < 2; ++ks)
        qf[ks] = *(const bf16x8*)(qrow + ks * 32 + lk * 8);

    float m_[4], l_[4];
    f32x4 o_[4];
#pragma unroll
    for (int j = 0; j < 4; ++j) { m_[j] = -1e30f; l_[j] = 0.f; }
    f32x4 zf = {0.f, 0.f, 0.f, 0.f};
#pragma unroll
    for (int nd = 0; nd < 4; ++nd) o_[nd] = zf;

    for (int t0 = 0; t0 <= q0; t0 += 64) {
        f32x4 s[4];
#pragma unroll
        for (int nf = 0; nf < 4; ++nf) {
            const unsigned short* krow = kbf + ((size_t)(t0 + nf * 16 + lm) * KVH_ + kvh) * HD_;
            bf16x8 k0 = *(const bf16x8*)(krow + lk * 8);
            bf16x8 k1 = *(const bf16x8*)(krow + 32 + lk * 8);
            f32x4 acc = zf;
            acc = __builtin_amdgcn_mfma_f32_16x16x32_bf16(qf[0], k0, acc, 0, 0, 0);
            acc = __builtin_amdgcn_mfma_f32_16x16x32_bf16(qf[1], k1, acc, 0, 0, 0);
            s[nf] = acc;
        }
        if (t0 == q0) {
#pragma unroll
            for (int nf = 0; nf < 4; ++nf)
#pragma unroll
                for (int j = 0; j < 4; ++j) {
                    int key = nf * 16 + lm, qq = w * 16 + lk * 4 + j;
                    if (key > qq) s[nf][j] = -1e30f;
                }
        }
        float p_[4][4];
#pragma unroll
        for (int j = 0; j < 4; ++j) {
            float mx = fmaxf(fmaxf(s[0][j], s[1][j]), fmaxf(s[2][j], s[3][j]));
#pragma unroll
            for (int off = 8; off > 0; off >>= 1) mx = fmaxf(mx, __shfl_xor(mx, off));
            float nm = fmaxf(m_[j], mx);
            float rs = __expf(m_[j] - nm);
            float sum = 0.f;
#pragma unroll
            for (int nf = 0; nf < 4; ++nf) {
                float pv = __expf(s[nf][j] - nm);
                p_[nf][j] = pv; sum += pv;
            }
#pragma unroll
            for (int off = 8; off > 0; off >>= 1) sum += __shfl_xor(sum, off);
            l_[j] = l_[j] * rs + sum;
            m_[j] = nm;
#pragma unroll
            for (int nd = 0; nd < 4; ++nd) o_[nd][j] *= rs;
        }
#pragma unroll
        for (int j = 0; j < 4; ++j) {
            int r = lk * 4 + j;
            unsigned lo = pkbf(p_[0][j], p_[1][j]);
            unsigned hi = pkbf(p_[2][j], p_[3][j]);
            int byte = (lm * 8) ^ ((r & 7) << 4);
            *(uint2*)(myP + r * 128 + byte) = make_uint2(lo, hi);
        }
#pragma unroll
        for (int ks = 0; ks < 2; ++ks) {
            int byte = (ks * 64 + lk * 16) ^ ((lm & 7) << 4);
            bf16x8 pA = *(const bf16x8*)(myP + lm * 128 + byte);
#pragma unroll
            for (int nd = 0; nd < 4; ++nd) {
                const unsigned short* vrow = vtb + ((size_t)kvh * HD_ + nd * 16 + lm) * S_ + t0 + ks * 32 + lk * 8;
                bf16x8 vB = *(const bf16x8*)vrow;
                o_[nd] = __builtin_amdgcn_mfma_f32_16x16x32_bf16(pA, vB, o_[nd], 0, 0, 0);
            }
        }
    }
#pragma unroll
    for (int nd = 0; nd < 4; ++nd)
#pragma unroll
        for (int j = 0; j < 4; ++j) {
            int r = lk * 4 + j;
            ctx[((size_t)(q0 + w * 16 + r) * NH_ + h) * HD_ + nd * 16 + lm] = o_[nd][j] / l_[j];
        }
}

// ---------------- Router
__global__ __launch_bounds__(64) void router_k(const float* __restrict__ x2,
                                               const float* __restrict__ gw,
                                               int* __restrict__ cnt,
                                               int* __restrict__ elist,
                                               int* __restrict__ eslot,
                                               float* __restrict__ wslot)
{
    int n = blockIdx.x, lane = threadIdx.x;
    float part[E_];
#pragma unroll
    for (int e = 0; e < E_; ++e) part[e] = 0.f;
    const float* xr = x2 + (size_t)n * H_;
    for (int j = lane; j < H_; j += 64) {
        float xv = xr[j];
#pragma unroll
        for (int e = 0; e < E_; ++e) part[e] = fmaf(xv, gw[e * H_ + j], part[e]);
    }
#pragma unroll
    for (int e = 0; e < E_; ++e)
#pragma unroll
        for (int off = 32; off > 0; off >>= 1) part[e] += __shfl_xor(part[e], off);
    if (lane == 0) {
        float mx = part[0];
#pragma unroll
        for (int e = 1; e < E_; ++e) mx = fmaxf(mx, part[e]);
        float rw[E_]; float ssum = 0.f;
#pragma unroll
        for (int e = 0; e < E_; ++e) { rw[e] = expf(part[e] - mx); ssum += rw[e]; }
#pragma unroll
        for (int e = 0; e < E_; ++e) rw[e] /= ssum;
        float best = -1.f; int ba = 0, bb = 1;
        for (int a = 0; a < E_; ++a)
            for (int b = a + 1; b < E_; ++b) {
                float scv = rw[a] + rw[b];
                if (scv > best) { best = scv; ba = a; bb = b; }
            }
        float wa = rw[ba], wb = rw[bb], wsum = wa + wb;
        wa /= wsum; wb /= wsum;
        int p = atomicAdd(&cnt[ba], 1);
        elist[ba * S_ + p] = n; eslot[ba * S_ + p] = 2 * n;
        p = atomicAdd(&cnt[bb], 1);
        elist[bb * S_ + p] = n; eslot[bb * S_ + p] = 2 * n + 1;
        wslot[2 * n] = wa; wslot[2 * n + 1] = wb;
    }
}

// ---------------- MoE up via global_load_lds (WB path): 128(M) x 64(N), BK=64.
__global__ __launch_bounds__(256) void moe_up_g(const unsigned short* __restrict__ x2b,
                                                const unsigned short* __restrict__ w1b,
                                                const unsigned short* __restrict__ w3b,
                                                const int* __restrict__ cnt,
                                                const int* __restrict__ elist,
                                                const int* __restrict__ eslot,
                                                unsigned short* __restrict__ hbuf)
{
    int e = blockIdx.z;
    int c = cnt[e];
    int p0 = blockIdx.y * 128;
    if (p0 >= c) return;
    int i0 = blockIdx.x * 64;
    int tid = threadIdx.x;

    __shared__ char As[16384], B1s[8192], B3s[8192];   // 32 KB
    __shared__ int rowtokS[128], rowslotS[128];
    if (tid < 128) {
        int p = min(p0 + tid, c - 1);
        rowtokS[tid]  = elist[e * S_ + p];
        rowslotS[tid] = eslot[e * S_ + p];
    }
    __syncthreads();

    int lane = tid & 63, w = tid >> 6, wm = w >> 1, wn = w & 1;
    int lm = lane & 15, lk = lane >> 4;
    int wb16 = (tid & ~63) * 16;      // wave-uniform LDS base term
    size_t wbase = (size_t)e * I_ * H_;

    f32x4 z = {0.f, 0.f, 0.f, 0.f};
    f32x4 acc1[4][2], acc3[4][2];
#pragma unroll
    for (int mf = 0; mf < 4; ++mf)
#pragma unroll
        for (int nf = 0; nf < 2; ++nf) { acc1[mf][nf] = z; acc3[mf][nf] = z; }

    for (int kt = 0; kt < H_ / 64; ++kt) {
        int kb = kt * 64;
#pragma unroll
        for (int it = 0; it < 4; ++it) {
            int g = tid + it * 256, row = g >> 3, kg = g & 7;
            gload16u(x2b + (size_t)rowtokS[row] * H_ + kb + kg * 8, As, wb16 + it * 4096);
        }
#pragma unroll
        for (int it = 0; it < 2; ++it) {
            int g = tid + it * 256, row = g >> 3, kg = g & 7;
            size_t off = wbase + (size_t)(i0 + row) * H_ + kb + kg * 8;
            gload16u(w1b + off, B1s, wb16 + it * 4096);
            gload16u(w3b + off, B3s, wb16 + it * 4096);
        }
        vmdrain();
        __syncthreads();   // all loads landed across all waves
#pragma unroll
        for (int ks = 0; ks < 2; ++ks) {
            bf16x8 af[4];
#pragma unroll
            for (int mf = 0; mf < 4; ++mf) {
                int row = wm * 64 + mf * 16 + lm;
                af[mf] = *(const bf16x8*)(As + row * 128 + ks * 64 + lk * 16);
            }
#pragma unroll
            for (int nf = 0; nf < 2; ++nf) {
                int brow = wn * 32 + nf * 16 + lm;
                int bby = brow * 128 + ks * 64 + lk * 16;
                bf16x8 b1 = *(const bf16x8*)(B1s + bby);
                bf16x8 b3 = *(const bf16x8*)(B3s + bby);
#pragma unroll
                for (int mf = 0; mf < 4; ++mf) {
                    acc1[mf][nf] = __builtin_amdgcn_mfma_f32_16x16x32_bf16(af[mf], b1, acc1[mf][nf], 0, 0, 0);
                    acc3[mf][nf] = __builtin_amdgcn_mfma_f32_16x16x32_bf16(af[mf], b3, acc3[mf][nf], 0, 0, 0);
                }
            }
        }
        __syncthreads();   // reads done before next overwrite
    }

#pragma unroll
    for (int mf = 0; mf < 4; ++mf)
#pragma unroll
        for (int nf = 0; nf < 2; ++nf) {
            int coli = i0 + wn * 32 + nf * 16 + lm;
#pragma unroll
            for (int j = 0; j < 4; ++j) {
                int rloc = wm * 64 + mf * 16 + lk * 4 + j;
                if (p0 + rloc < c) {
                    float h1 = acc1[mf][nf][j];
                    float val = h1 / (1.f + __expf(-h1)) * acc3[mf][nf][j];
                    hbuf[(size_t)rowslotS[rloc] * I_ + coli] = f2bf(val);
                }
            }
        }
}

// ---------------- MoE down via global_load_lds (WB path): 128x128, BK=64, split-K.
__global__ __launch_bounds__(256) void moe_dn_g(const unsigned short* __restrict__ hbuf,
                                                const unsigned short* __restrict__ w2b,
                                                const int* __restrict__ cnt,
                                                const int* __restrict__ eslot,
                                                unsigned short* __restrict__ dbuf)
{
    int e = blockIdx.z >> 2;           // KSLC == 4
    int slice = blockIdx.z & 3;
    int c = cnt[e];
    int p0 = blockIdx.y * 128;
    if (p0 >= c) return;
    int h0 = blockIdx.x * 128;
    int tid = threadIdx.x;
    const int kb0 = slice * (I_ / KSLC);

    __shared__ char As[16384], Bs[16384];   // 32 KB
    __shared__ int rowslotS[128];
    if (tid < 128) rowslotS[tid] = eslot[e * S_ + min(p0 + tid, c - 1)];
    __syncthreads();

    int lane = tid & 63, w = tid >> 6, wm = w >> 1, wn = w & 1;
    int lm = lane & 15, lk = lane >> 4;
    int wb16 = (tid & ~63) * 16;
    size_t wbase = (size_t)e * H_ * I_;

    f32x4 z = {0.f, 0.f, 0.f, 0.f};
    f32x4 acc[4][4];
#pragma unroll
    for (int mf = 0; mf < 4; ++mf)
#pragma unroll
        for (int nf = 0; nf < 4; ++nf) acc[mf][nf] = z;

    const int NKT = (I_ / KSLC) / 64;        // 14
    for (int kt = 0; kt < NKT; ++kt) {
        int kb = kb0 + kt * 64;
#pragma unroll
        for (int it = 0; it < 4; ++it) {
            int g = tid + it * 256, row = g >> 3, kg = g & 7;
            gload16u(hbuf + (size_t)rowslotS[row] * I_ + kb + kg * 8, As, wb16 + it * 4096);
            gload16u(w2b + wbase + (size_t)(h0 + row) * I_ + kb + kg * 8, Bs, wb16 + it * 4096);
        }
        vmdrain();
        __syncthreads();
#pragma unroll
        for (int ks = 0; ks < 2; ++ks) {
            bf16x8 af[4];
#pragma unroll
            for (int mf = 0; mf < 4; ++mf) {
                int row = wm * 64 + mf * 16 + lm;
                af[mf] = *(const bf16x8*)(As + row * 128 + ks * 64 + lk * 16);
            }
#pragma unroll
            for (int nf = 0; nf < 4; ++nf) {
                int brow = wn * 64 + nf * 16 + lm;
                bf16x8 bf = *(const bf16x8*)(Bs + brow * 128 + ks * 64 + lk * 16);
#pragma unroll
                for (int mf = 0; mf < 4; ++mf)
                    acc[mf][nf] = __builtin_amdgcn_mfma_f32_16x16x32_bf16(af[mf], bf, acc[mf][nf], 0, 0, 0);
            }
        }
        __syncthreads();
    }

    unsigned short* dslice = dbuf + (size_t)slice * S_ * 2 * H_;
#pragma unroll
    for (int mf = 0; mf < 4; ++mf)
#pragma unroll
        for (int nf = 0; nf < 4; ++nf) {
            int colh = h0 + wn * 64 + nf * 16 + lm;
#pragma unroll
            for (int j = 0; j < 4; ++j) {
                int rloc = wm * 64 + mf * 16 + lk * 4 + j;
                if (p0 + rloc < c)
                    dslice[(size_t)rowslotS[rloc] * H_ + colh] = f2bf(acc[mf][nf][j]);
            }
        }
}

// ---------------- MoE up (reg-staged, WB=false fallback), 128x64, BK=64
template<bool WB>
__global__ __launch_bounds__(256) void moe_up_mfma(const float* __restrict__ x2,
                                                   const void* __restrict__ w1,
                                                   const void* __restrict__ w3,
                                                   const int* __restrict__ cnt,
                                                   const int* __restrict__ elist,
                                                   const int* __restrict__ eslot,
                                                   unsigned short* __restrict__ hbuf)
{
    int e = blockIdx.z;
    int c = cnt[e];
    int p0 = blockIdx.y * 128;
    if (p0 >= c) return;
    int i0 = blockIdx.x * 64;
    int tid = threadIdx.x;

    __shared__ char As[16384], B1s[8192], B3s[8192];
    __shared__ int rowtokS[128], rowslotS[128];
    if (tid < 128) {
        int p = min(p0 + tid, c - 1);
        rowtokS[tid]  = elist[e * S_ + p];
        rowslotS[tid] = eslot[e * S_ + p];
    }
    __syncthreads();

    int lane = tid & 63, w = tid >> 6, wm = w >> 1, wn = w & 1;
    int lm = lane & 15, lk = lane >> 4;
    size_t wbase = (size_t)e * I_ * H_;

    int4 rA[4], rB1[2], rB3[2];
    auto loadAll = [&](int kb) {
#pragma unroll
        for (int it = 0; it < 4; ++it) {
            int g = tid + it * 256, row = g >> 3, kg = g & 7;
            const float* s = x2 + (size_t)rowtokS[row] * H_ + kb + kg * 8;
            float4 f0 = *(const float4*)s, f1 = *(const float4*)(s + 4);
            rA[it] = make_int4(pkbf(f0.x, f0.y), pkbf(f0.z, f0.w),
                               pkbf(f1.x, f1.y), pkbf(f1.z, f1.w));
        }
#pragma unroll
        for (int it = 0; it < 2; ++it) {
            int g = tid + it * 256, row = g >> 3, kg = g & 7;
            size_t off = wbase + (size_t)(i0 + row) * H_ + kb + kg * 8;
            rB1[it] = loadW16<WB>(w1, off);
            rB3[it] = loadW16<WB>(w3, off);
        }
    };
    auto writeAll = [&]() {
#pragma unroll
        for (int it = 0; it < 4; ++it) {
            int g = tid + it * 256, row = g >> 3, kg = g & 7;
            int byte = row * 128 + ((kg * 16) ^ ((row & 7) << 4));
            *(int4*)(As + byte) = rA[it];
        }
#pragma unroll
        for (int it = 0; it < 2; ++it) {
            int g = tid + it * 256, row = g >> 3, kg = g & 7;
            int byte = row * 128 + ((kg * 16) ^ ((row & 7) << 4));
            *(int4*)(B1s + byte) = rB1[it];
            *(int4*)(B3s + byte) = rB3[it];
        }
    };

    f32x4 z = {0.f, 0.f, 0.f, 0.f};
    f32x4 acc1[4][2], acc3[4][2];
#pragma unroll
    for (int mf = 0; mf < 4; ++mf)
#pragma unroll
        for (int nf = 0; nf < 2; ++nf) { acc1[mf][nf] = z; acc3[mf][nf] = z; }

    loadAll(0);
    for (int kt = 0; kt < H_ / 64; ++kt) {
        __syncthreads();
        writeAll();
        __syncthreads();
        if (kt + 1 < H_ / 64) loadAll((kt + 1) * 64);
#pragma unroll
        for (int ks = 0; ks < 2; ++ks) {
            bf16x8 af[4];
#pragma unroll
            for (int mf = 0; mf < 4; ++mf) {
                int row = wm * 64 + mf * 16 + lm;
                af[mf] = *(const bf16x8*)(As + row * 128 + ((ks * 64 + lk * 16) ^ ((row & 7) << 4)));
            }
#pragma unroll
            for (int nf = 0; nf < 2; ++nf) {
                int brow = wn * 32 + nf * 16 + lm;
                int bby = brow * 128 + ((ks * 64 + lk * 16) ^ ((brow & 7) << 4));
                bf16x8 b1 = *(const bf16x8*)(B1s + bby);
                bf16x8 b3 = *(const bf16x8*)(B3s + bby);
#pragma unroll
                for (int mf = 0; mf < 4; ++mf) {
                    acc1[mf][nf] = __builtin_amdgcn_mfma_f32_16x16x32_bf16(af[mf], b1, acc1[mf][nf], 0, 0, 0);
                    acc3[mf][nf] = __builtin_amdgcn_mfma_f32_16x16x32_bf16(af[mf], b3, acc3[mf][nf], 0, 0, 0);
                }
            }
        }
    }

#pragma unroll
    for (int mf = 0; mf < 4; ++mf)
#pragma unroll
        for (int nf = 0; nf < 2; ++nf) {
            int coli = i0 + wn * 32 + nf * 16 + lm;
#pragma unroll
            for (int j = 0; j < 4; ++j) {
                int rloc = wm * 64 + mf * 16 + lk * 4 + j;
                if (p0 + rloc < c) {
                    float h1 = acc1[mf][nf][j];
                    float val = h1 / (1.f + __expf(-h1)) * acc3[mf][nf][j];
                    hbuf[(size_t)rowslotS[rloc] * I_ + coli] = f2bf(val);
                }
            }
        }
}

// ---------------- MoE down (reg-staged, WB=false fallback), 128x128, BK=64, split-K
template<bool WB>
__global__ __launch_bounds__(256) void moe_dn_mfma(const unsigned short* __restrict__ hbuf,
                                                   const void* __restrict__ w2,
                                                   const int* __restrict__ cnt,
                                                   const int* __restrict__ eslot,
                                                   unsigned short* __restrict__ dbuf)
{
    int e = blockIdx.z >> 2;
    int slice = blockIdx.z & 3;
    int c = cnt[e];
    int p0 = blockIdx.y * 128;
    if (p0 >= c) return;
    int h0 = blockIdx.x * 128;
    int tid = threadIdx.x;
    const int kb0 = slice * (I_ / KSLC);

    __shared__ char As[16384], Bs[16384];
    __shared__ int rowslotS[128];
    if (tid < 128) rowslotS[tid] = eslot[e * S_ + min(p0 + tid, c - 1)];
    __syncthreads();

    int lane = tid & 63, w = tid >> 6, wm = w >> 1, wn = w & 1;
    int lm = lane & 15, lk = lane >> 4;
    size_t wbase = (size_t)e * H_ * I_;

    int4 rA[4], rB[4];
    auto loadAll = [&](int kb) {
#pragma unroll
        for (int it = 0; it < 4; ++it) {
            int g = tid + it * 256, row = g >> 3, kg = g & 7;
            rA[it] = *(const int4*)(hbuf + (size_t)rowslotS[row] * I_ + kb + kg * 8);
            rB[it] = loadW16<WB>(w2, wbase + (size_t)(h0 + row) * I_ + kb + kg * 8);
        }
    };
    auto writeAll = [&]() {
#pragma unroll
        for (int it = 0; it < 4; ++it) {
            int g = tid + it * 256, row = g >> 3, kg = g & 7;
            int byte = row * 128 + ((kg * 16) ^ ((row & 7) << 4));
            *(int4*)(As + byte) = rA[it];
            *(int4*)(Bs + byte) = rB[it];
        }
    };

    f32x4 z = {0.f, 0.f, 0.f, 0.f};
    f32x4 acc[4][4];
#pragma unroll
    for (int mf = 0; mf < 4; ++mf)
#pragma unroll
        for (int nf = 0; nf < 4; ++nf) acc[mf][nf] = z;

    loadAll(kb0);
    const int NKT = (I_ / KSLC) / 64;
    for (int kt = 0; kt < NKT; ++kt) {
        __syncthreads();
        writeAll();
        __syncthreads();
        if (kt + 1 < NKT) loadAll(kb0 + (kt + 1) * 64);
#pragma unroll
        for (int ks = 0; ks < 2; ++ks) {
            bf16x8 af[4];
#pragma unroll
            for (int mf = 0; mf < 4; ++mf) {
                int row = wm * 64 + mf * 16 + lm;
                af[mf] = *(const bf16x8*)(As + row * 128 + ((ks * 64 + lk * 16) ^ ((row & 7) << 4)));
            }
#pragma unroll
            for (int nf = 0; nf < 4; ++nf) {
                int brow = wn * 64 + nf * 16 + lm;
                bf16x8 bf = *(const bf16x8*)(Bs + brow * 128 + ((ks * 64 + lk * 16) ^ ((brow & 7) << 4)));
#pragma unroll
                for (int mf = 0; mf < 4; ++mf)
                    acc[mf][nf] = __builtin_amdgcn_mfma_f32_16x16x32_bf16(af[mf], bf, acc[mf][nf], 0, 0, 0);
            }
        }
    }

    unsigned short* dslice = dbuf + (size_t)slice * S_ * 2 * H_;
#pragma unroll
    for (int mf = 0; mf < 4; ++mf)
#pragma unroll
        for (int nf = 0; nf < 4; ++nf) {
            int colh = h0 + wn * 64 + nf * 16 + lm;
#pragma unroll
            for (int j = 0; j < 4; ++j) {
                int rloc = wm * 64 + mf * 16 + lk * 4 + j;
                if (p0 + rloc < c)
                    dslice[(size_t)rowslotS[rloc] * H_ + colh] = f2bf(acc[mf][nf][j]);
            }
        }
}

// ---------------- Final combine
__global__ __launch_bounds__(256) void combine_k(const float* __restrict__ hid2,
                                                 const unsigned short* __restrict__ dbuf,
                                                 const float* __restrict__ wslot,
                                                 float* __restrict__ out)
{
    int idx = blockIdx.x * 256 + threadIdx.x;
    if (idx >= S_ * H_) return;
    int n = idx >> 10;
    int hcol = idx & (H_ - 1);
    float s0 = 0.f, s1 = 0.f;
#pragma unroll
    for (int sl = 0; sl < KSLC; ++sl) {
        const unsigned short* base = dbuf + (size_t)sl * S_ * 2 * H_;
        s0 += bf2f(base[(size_t)(2 * n)     * H_ + hcol]);
        s1 += bf2f(base[(size_t)(2 * n + 1) * H_ + hcol]);
    }
    out[idx] = hid2[idx] + wslot[2 * n] * s0 + wslot[2 * n + 1] * s1;
}

extern "C" void kernel_launch(void* const* d_in, const int* in_sizes, int n_in,
                              void* d_out, int out_size, void* d_ws, size_t ws_size,
                              hipStream_t stream)
{
    const float* hidden = (const float*)d_in[0];
    const float* ln1    = (const float*)d_in[1];
    const float* ln2    = (const float*)d_in[2];
    const float* wq     = (const float*)d_in[3];
    const float* wk     = (const float*)d_in[4];
    const float* wv     = (const float*)d_in[5];
    const float* wo     = (const float*)d_in[6];
    const float* gw     = (const float*)d_in[7];
    const float* w1     = (const float*)d_in[8];
    const float* w2     = (const float*)d_in[9];
    const float* w3     = (const float*)d_in[10];
    float* out = (float*)d_out;

    char* p = (char*)d_ws;
    auto alignp = [&]() { p = (char*)(((uintptr_t)p + 255) & ~(uintptr_t)255); };
    auto alloc_f = [&](size_t n) { alignp(); float* r = (float*)p; p += n * 4; return r; };
    auto alloc_h = [&](size_t n) { alignp(); unsigned short* r = (unsigned short*)p; p += n * 2; return r; };
    auto alloc_i = [&](size_t n) { alignp(); int* r = (int*)p; p += n * 4; return r; };

    float* xb   = alloc_f((size_t)S_ * H_);
    float* q    = alloc_f((size_t)S_ * NH_ * HD_);
    float* kb   = alloc_f((size_t)S_ * KVH_ * HD_);
    float* vb   = alloc_f((size_t)S_ * KVH_ * HD_);
    float* hid2 = alloc_f((size_t)S_ * H_);
    float* x2   = alloc_f((size_t)S_ * H_);
    unsigned short* x2b  = alloc_h((size_t)S_ * H_);
    unsigned short* hbuf = alloc_h((size_t)S_ * 2 * I_);
    unsigned short* dbuf = alloc_h((size_t)KSLC * S_ * 2 * H_);
    float* wslot= alloc_f((size_t)S_ * 2);
    unsigned short* qbf = alloc_h((size_t)S_ * NH_ * HD_);
    unsigned short* kbf = alloc_h((size_t)S_ * KVH_ * HD_);
    unsigned short* vtb = alloc_h((size_t)KVH_ * HD_ * S_);
    int* cnt   = alloc_i(E_);
    int* elist = alloc_i((size_t)E_ * S_);
    int* eslot = alloc_i((size_t)E_ * S_);
    float* ctx = xb;

    size_t used = (size_t)(p - (char*)d_ws);
    const size_t nW = (size_t)E_ * I_ * H_;
    size_t wbf_bytes = (3 * nW + (size_t)(NH_*HD_ + 2*KVH_*HD_ + H_) * H_) * 2 + 4096;
    bool WB = ws_size > used && (ws_size - used) >= wbf_bytes;

    unsigned short *w1b = nullptr, *w3b = nullptr, *w2b = nullptr;
    unsigned short *wqb = nullptr, *wkb = nullptr, *wvb = nullptr, *wob = nullptr;
    if (WB) {
        w1b = alloc_h(nW); w3b = alloc_h(nW); w2b = alloc_h(nW);
        wqb = alloc_h((size_t)NH_ * HD_ * H_);
        wkb = alloc_h((size_t)KVH_ * HD_ * H_);
        wvb = alloc_h((size_t)KVH_ * HD_ * H_);
        wob = alloc_h((size_t)H_ * NH_ * HD_);
    }

    hipMemsetAsync(cnt, 0, E_ * sizeof(int), stream);

    if (WB) {
        conv_bf16<<<2048, 256, 0, stream>>>(w1, w1b, (long)(nW / 8));
        conv_bf16<<<2048, 256, 0, stream>>>(w3, w3b, (long)(nW / 8));
        conv_bf16<<<2048, 256, 0, stream>>>(w2, w2b, (long)(nW / 8));
        conv_bf16<<<512, 256, 0, stream>>>(wq, wqb, (long)((size_t)NH_*HD_*H_ / 8));
        conv_bf16<<<512, 256, 0, stream>>>(wk, wkb, (long)((size_t)KVH_*HD_*H_ / 8));
        conv_bf16<<<512, 256, 0, stream>>>(wv, wvb, (long)((size_t)KVH_*HD_*H_ / 8));
        conv_bf16<<<512, 256, 0, stream>>>(wo, wob, (long)((size_t)H_*NH_*HD_ / 8));
    }

    rmsnorm_k<<<S_, 256, 0, stream>>>(hidden, ln1, xb, nullptr);

    if (WB) {
        dense_mfma<true><<<dim3(8, 16),  256, 0, stream>>>(xb, wqb, nullptr, q,  S_, NH_ * HD_, H_);
        dense_mfma<true><<<dim3(4, 16),  256, 0, stream>>>(xb, wkb, nullptr, kb, S_, KVH_ * HD_, H_);
        dense_mfma<true><<<dim3(4, 16),  256, 0, stream>>>(xb, wvb, nullptr, vb, S_, KVH_ * HD_, H_);
    } else {
        dense_mfma<false><<<dim3(8, 16), 256, 0, stream>>>(xb, wq, nullptr, q,  S_, NH_ * HD_, H_);
        dense_mfma<false><<<dim3(4, 16), 256, 0, stream>>>(xb, wk, nullptr, kb, S_, KVH_ * HD_, H_);
        dense_mfma<false><<<dim3(4, 16), 256, 0, stream>>>(xb, wv, nullptr, vb, S_, KVH_ * HD_, H_);
    }
    {
        int tot = S_ * (NH_ + KVH_) * 32;
        rope_conv<<<SDIV(tot, 256), 256, 0, stream>>>(q, kb, qbf, kbf);
    }
    v_trans<<<dim3(S_ / 64, KVH_), 256, 0, stream>>>(vb, vtb);
    attn_mfma<<<dim3(16, NH_, 2), 256, 0, stream>>>(qbf, kbf, vtb, ctx);

    if (WB)
        dense_mfma<true><<<dim3(8, 16),  256, 0, stream>>>(ctx, wob, hidden, hid2, S_, H_, NH_ * HD_);
    else
        dense_mfma<false><<<dim3(8, 16), 256, 0, stream>>>(ctx, wo, hidden, hid2, S_, H_, NH_ * HD_);

    rmsnorm_k<<<S_, 256, 0, stream>>>(hid2, ln2, x2, x2b);
    router_k<<<S_, 64, 0, stream>>>(x2, gw, cnt, elist, eslot, wslot);

    if (WB) {
        moe_up_g<<<dim3(I_ / 64, S_ / 128, E_), 256, 0, stream>>>(x2b, w1b, w3b, cnt, elist, eslot, hbuf);
        moe_dn_g<<<dim3(H_ / 128, S_ / 128, E_ * KSLC), 256, 0, stream>>>(hbuf, w2b, cnt, eslot, dbuf);
    } else {
        moe_up_mfma<false><<<dim3(I_ / 64, S_ / 128, E_), 256, 0, stream>>>(x2, w1, w3, cnt, elist, eslot, hbuf);
        moe_dn_mfma<false><<<dim3(H_ / 128, S_ / 128, E_ * KSLC), 256, 0, stream>>>(hbuf, w2, cnt, eslot, dbuf);
    }
    combine_k<<<SDIV(S_ * H_, 256), 256, 0, stream>>>(hid2, dbuf, wslot, out);
}

// Round 10
// 539.087 us; speedup vs baseline: 6.0903x; 1.0530x over previous
//
#include <hip/hip_runtime.h>
#include <hip/hip_bf16.h>
#include <math.h>

constexpr int S_ = 2048, H_ = 1024, NH_ = 16, KVH_ = 8, HD_ = 64;
constexpr int E_ = 8, I_ = 3584;
constexpr int KSLC = 4;                 // split-K slices for MoE down
constexpr float EPS_ = 1e-6f;
constexpr float THETA_ = 1000000.0f;

#define SDIV(a,b) (((a)+(b)-1)/(b))

typedef __attribute__((ext_vector_type(8))) short bf16x8;
typedef __attribute__((ext_vector_type(4))) float f32x4;

__device__ inline unsigned pkbf(float a, float b) {
    unsigned r;
    asm("v_cvt_pk_bf16_f32 %0, %1, %2" : "=v"(r) : "v"(a), "v"(b));
    return r;
}
__device__ inline unsigned short f2bf(float f) {
    unsigned u = __float_as_uint(f);
    u += 0x7FFF + ((u >> 16) & 1);
    return (unsigned short)(u >> 16);
}
__device__ inline float bf2f(unsigned short v) {
    return __uint_as_float((unsigned)v << 16);
}

// async global->LDS, 16B/lane. LDS base FORCED wave-uniform via readfirstlane;
// lane l lands at base + l*16 (m104 semantics). Global src stays per-lane.
__device__ inline void gload16u(const void* gsrc, char* ldsArr, int uoff) {
    int off = __builtin_amdgcn_readfirstlane(uoff);
    __builtin_amdgcn_global_load_lds(
        (__attribute__((address_space(1))) void*)(gsrc),
        (__attribute__((address_space(3))) void*)(ldsArr + off), 16, 0, 0);
}
// explicit vmcnt drain (belt-and-suspenders before barrier)
__device__ inline void vmdrain() {
    asm volatile("s_waitcnt vmcnt(0)" ::: "memory");
}

template<bool WB>
__device__ inline int4 loadW16(const void* W, size_t elemOff) {
    if constexpr (WB) {
        return *(const int4*)((const unsigned short*)W + elemOff);
    } else {
        const float* s = (const float*)W + elemOff;
        float4 f0 = *(const float4*)s, f1 = *(const float4*)(s + 4);
        return make_int4(pkbf(f0.x, f0.y), pkbf(f0.z, f0.w),
                         pkbf(f1.x, f1.y), pkbf(f1.z, f1.w));
    }
}

// ---------------- fp32 -> bf16 bulk convert
__global__ __launch_bounds__(256) void conv_bf16(const float* __restrict__ in,
                                                 unsigned short* __restrict__ out, long n8)
{
    long i = (long)blockIdx.x * 256 + threadIdx.x;
    long stride = (long)gridDim.x * 256;
    for (; i < n8; i += stride) {
        const float* s = in + i * 8;
        float4 f0 = *(const float4*)s, f1 = *(const float4*)(s + 4);
        *(int4*)(out + i * 8) = make_int4(pkbf(f0.x, f0.y), pkbf(f0.z, f0.w),
                                          pkbf(f1.x, f1.y), pkbf(f1.z, f1.w));
    }
}

// ---------------- RMSNorm (optionally also emits bf16 copy)
__global__ __launch_bounds__(256) void rmsnorm_k(const float* __restrict__ x,
                                                 const float* __restrict__ w,
                                                 float* __restrict__ out,
                                                 unsigned short* __restrict__ outb)
{
    int row = blockIdx.x;
    int tid = threadIdx.x;
    const float* xr = x + (size_t)row * H_;
    float4 v = *(const float4*)&xr[tid * 4];
    float ss = v.x*v.x + v.y*v.y + v.z*v.z + v.w*v.w;
#pragma unroll
    for (int off = 32; off > 0; off >>= 1) ss += __shfl_xor(ss, off);
    __shared__ float red[4];
    if ((tid & 63) == 0) red[tid >> 6] = ss;
    __syncthreads();
    float tot = red[0] + red[1] + red[2] + red[3];
    float r = rsqrtf(tot / (float)H_ + EPS_);
    float4 wv = *(const float4*)&w[tid * 4];
    float4 o;
    o.x = v.x * r * wv.x; o.y = v.y * r * wv.y;
    o.z = v.z * r * wv.z; o.w = v.w * r * wv.w;
    *(float4*)&out[(size_t)row * H_ + tid * 4] = o;
    if (outb) {
        uint2 pk = make_uint2(pkbf(o.x, o.y), pkbf(o.z, o.w));
        *(uint2*)&outb[(size_t)row * H_ + tid * 4] = pk;
    }
}

// ---------------- Dense bf16-MFMA GEMM: C[M,N] = (Res?) + A[M,K]*B[N,K]^T
template<bool WB>
__global__ __launch_bounds__(256) void dense_mfma(const float* __restrict__ A,
                                                  const void* __restrict__ Bw,
                                                  const float* __restrict__ Res,
                                                  float* __restrict__ C,
                                                  int M, int N, int K)
{
    __shared__ char As[16384], Bs[16384];
    int tid = threadIdx.x;
    int m0 = blockIdx.y * 128, n0 = blockIdx.x * 128;
    int lane = tid & 63, w = tid >> 6, wm = w >> 1, wn = w & 1;
    int lm = lane & 15, lk = lane >> 4;

    int4 rA[4], rB[4];
    auto loadAll = [&](int kb) {
#pragma unroll
        for (int it = 0; it < 4; ++it) {
            int g = tid + it * 256, row = g >> 3, kg = g & 7;
            const float* s = A + (size_t)(m0 + row) * K + kb + kg * 8;
            float4 f0 = *(const float4*)s, f1 = *(const float4*)(s + 4);
            rA[it] = make_int4(pkbf(f0.x, f0.y), pkbf(f0.z, f0.w),
                               pkbf(f1.x, f1.y), pkbf(f1.z, f1.w));
            rB[it] = loadW16<WB>(Bw, (size_t)(n0 + row) * K + kb + kg * 8);
        }
    };
    auto writeAll = [&]() {
#pragma unroll
        for (int it = 0; it < 4; ++it) {
            int g = tid + it * 256, row = g >> 3, kg = g & 7;
            int byte = row * 128 + ((kg * 16) ^ ((row & 7) << 4));
            *(int4*)(As + byte) = rA[it];
            *(int4*)(Bs + byte) = rB[it];
        }
    };

    f32x4 z = {0.f, 0.f, 0.f, 0.f};
    f32x4 acc[4][4];
#pragma unroll
    for (int mf = 0; mf < 4; ++mf)
#pragma unroll
        for (int nf = 0; nf < 4; ++nf) acc[mf][nf] = z;

    loadAll(0);
    for (int kt = 0; kt < K / 64; ++kt) {
        __syncthreads();
        writeAll();
        __syncthreads();
        if (kt + 1 < K / 64) loadAll((kt + 1) * 64);
#pragma unroll
        for (int ks = 0; ks < 2; ++ks) {
            bf16x8 af[4];
#pragma unroll
            for (int mf = 0; mf < 4; ++mf) {
                int row = wm * 64 + mf * 16 + lm;
                af[mf] = *(const bf16x8*)(As + row * 128 + ((ks * 64 + lk * 16) ^ ((row & 7) << 4)));
            }
#pragma unroll
            for (int nf = 0; nf < 4; ++nf) {
                int brow = wn * 64 + nf * 16 + lm;
                bf16x8 bf = *(const bf16x8*)(Bs + brow * 128 + ((ks * 64 + lk * 16) ^ ((brow & 7) << 4)));
#pragma unroll
                for (int mf = 0; mf < 4; ++mf)
                    acc[mf][nf] = __builtin_amdgcn_mfma_f32_16x16x32_bf16(af[mf], bf, acc[mf][nf], 0, 0, 0);
            }
        }
    }

#pragma unroll
    for (int mf = 0; mf < 4; ++mf)
#pragma unroll
        for (int nf = 0; nf < 4; ++nf) {
            int col = n0 + wn * 64 + nf * 16 + lm;
#pragma unroll
            for (int j = 0; j < 4; ++j) {
                int row = m0 + wm * 64 + mf * 16 + lk * 4 + j;
                float r = Res ? Res[(size_t)row * N + col] : 0.0f;
                C[(size_t)row * N + col] = acc[mf][nf][j] + r;
            }
        }
}

// ---------------- RoPE + bf16 convert. Q pre-scaled by 1/sqrt(HD).
__global__ __launch_bounds__(256) void rope_conv(const float* __restrict__ q,
                                                 const float* __restrict__ k,
                                                 unsigned short* __restrict__ qbf,
                                                 unsigned short* __restrict__ kbf)
{
    int idx = blockIdx.x * 256 + threadIdx.x;
    const int totq = S_ * NH_ * 32;
    const int tot = totq + S_ * KVH_ * 32;
    if (idx >= tot) return;
    const float* base; unsigned short* obase; int s, di; float sc;
    if (idx < totq) {
        s = idx / (NH_ * 32); int r = idx % (NH_ * 32);
        size_t o = ((size_t)s * NH_ + (r >> 5)) * HD_;
        base = q + o; obase = qbf + o; di = r & 31; sc = 0.125f;
    } else {
        int j2 = idx - totq;
        s = j2 / (KVH_ * 32); int r = j2 % (KVH_ * 32);
        size_t o = ((size_t)s * KVH_ + (r >> 5)) * HD_;
        base = k + o; obase = kbf + o; di = r & 31; sc = 1.0f;
    }
    float invf = powf(THETA_, -(2.0f * di) / (float)HD_);
    float ang = (float)s * invf;
    float c = cosf(ang), sn = sinf(ang);
    float x0 = base[di], x1 = base[di + 32];
    obase[di]      = f2bf((x0 * c - x1 * sn) * sc);
    obase[di + 32] = f2bf((x1 * c + x0 * sn) * sc);
}

// ---------------- V transpose: vtb[kvh][d][t0+slot] = bf16(V[t0+key][kvh][d])
__global__ __launch_bounds__(256) void v_trans(const float* __restrict__ v,
                                               unsigned short* __restrict__ vtb)
{
    int t0 = blockIdx.x * 64, kvh = blockIdx.y;
    __shared__ unsigned short T[64][64];
    int tid = threadIdx.x;
    int k = tid >> 2, d0 = (tid & 3) * 16;
    const float* src = v + ((size_t)(t0 + k) * KVH_ + kvh) * HD_ + d0;
#pragma unroll
    for (int x = 0; x < 4; ++x) {
        float4 f = *(const float4*)(src + x * 4);
        T[k][d0 + x*4 + 0] = f2bf(f.x);
        T[k][d0 + x*4 + 1] = f2bf(f.y);
        T[k][d0 + x*4 + 2] = f2bf(f.z);
        T[k][d0 + x*4 + 3] = f2bf(f.w);
    }
    __syncthreads();
    int d = tid >> 2, s0 = (tid & 3) * 16;
    unsigned short tmp[16] __attribute__((aligned(16)));
#pragma unroll
    for (int x = 0; x < 16; ++x) {
        int s = s0 + x;
        int key = 16 * (s & 3) + (s >> 2);
        tmp[x] = T[key][d];
    }
    unsigned short* dst = vtb + ((size_t)kvh * HD_ + d) * S_ + t0 + s0;
    *(int4*)(dst)     = *(int4*)(tmp);
    *(int4*)(dst + 8) = *(int4*)(tmp + 8);
}

// ---------------- MFMA flash attention
__global__ __launch_bounds__(256) void attn_mfma(const unsigned short* __restrict__ qbf,
                                                 const unsigned short* __restrict__ kbf,
                                                 const unsigned short* __restrict__ vtb,
                                                 float* __restrict__ ctx)
{
    __shared__ char Ps[4 * 2048];
    int pair = blockIdx.x, h = blockIdx.y, z = blockIdx.z;
    int qb = z ? (31 - pair) : pair;
    int q0 = qb * 64;
    int kvh = h >> 1;
    int tid = threadIdx.x;
    int w = tid >> 6, lane = tid & 63;
    int lm = lane & 15, lk = lane >> 4;
    char* myP = Ps + w * 2048;

    bf16x8 qf[2];
    const unsigned short* qrow = qbf + ((size_t)(q0 + w * 16 + lm) * NH_ + h) * HD_;
#pragma unroll
    for (int ks = 0; ks < 2; ++ks)
        qf[ks] = *(const bf16x8*)(qrow + ks * 32 + lk * 8);

    float m_[4], l_[4];
    f32x4 o_[4];
#pragma unroll
    for (int j = 0; j < 4; ++j) { m_[j] = -1e30f; l_[j] = 0.f; }
    f32x4 zf = {0.f, 0.f, 0.f, 0.f};
#pragma unroll
    for (int nd = 0; nd < 4; ++nd) o_[nd] = zf;

    for (int t0 = 0; t0 <= q0; t0 += 64) {
        f32x4 s[4];
#pragma unroll
        for (int nf = 0; nf < 4; ++nf) {
            const unsigned short* krow = kbf + ((size_t)(t0 + nf * 16 + lm) * KVH_ + kvh) * HD_;
            bf16x8 k0 = *(const bf16x8*)(krow + lk * 8);
            bf16x8 k1 = *(const bf16x8*)(krow + 32 + lk * 8);
            f32x4 acc = zf;
            acc = __builtin_amdgcn_mfma_f32_16x16x32_bf16(qf[0], k0, acc, 0, 0, 0);
            acc = __builtin_amdgcn_mfma_f32_16x16x32_bf16(qf[1], k1, acc, 0, 0, 0);
            s[nf] = acc;
        }
        if (t0 == q0) {
#pragma unroll
            for (int nf = 0; nf < 4; ++nf)
#pragma unroll
                for (int j = 0; j < 4; ++j) {
                    int key = nf * 16 + lm, qq = w * 16 + lk * 4 + j;
                    if (key > qq) s[nf][j] = -1e30f;
                }
        }
        float p_[4][4];
#pragma unroll
        for (int j = 0; j < 4; ++j) {
            float mx = fmaxf(fmaxf(s[0][j], s[1][j]), fmaxf(s[2][j], s[3][j]));
#pragma unroll
            for (int off = 8; off > 0; off >>= 1) mx = fmaxf(mx, __shfl_xor(mx, off));
            float nm = fmaxf(m_[j], mx);
            float rs = __expf(m_[j] - nm);
            float sum = 0.f;
#pragma unroll
            for (int nf = 0; nf < 4; ++nf) {
                float pv = __expf(s[nf][j] - nm);
                p_[nf][j] = pv; sum += pv;
            }
#pragma unroll
            for (int off = 8; off > 0; off >>= 1) sum += __shfl_xor(sum, off);
            l_[j] = l_[j] * rs + sum;
            m_[j] = nm;
#pragma unroll
            for (int nd = 0; nd < 4; ++nd) o_[nd][j] *= rs;
        }
#pragma unroll
        for (int j = 0; j < 4; ++j) {
            int r = lk * 4 + j;
            unsigned lo = pkbf(p_[0][j], p_[1][j]);
            unsigned hi = pkbf(p_[2][j], p_[3][j]);
            int byte = (lm * 8) ^ ((r & 7) << 4);
            *(uint2*)(myP + r * 128 + byte) = make_uint2(lo, hi);
        }
#pragma unroll
        for (int ks = 0; ks < 2; ++ks) {
            int byte = (ks * 64 + lk * 16) ^ ((lm & 7) << 4);
            bf16x8 pA = *(const bf16x8*)(myP + lm * 128 + byte);
#pragma unroll
            for (int nd = 0; nd < 4; ++nd) {
                const unsigned short* vrow = vtb + ((size_t)kvh * HD_ + nd * 16 + lm) * S_ + t0 + ks * 32 + lk * 8;
                bf16x8 vB = *(const bf16x8*)vrow;
                o_[nd] = __builtin_amdgcn_mfma_f32_16x16x32_bf16(pA, vB, o_[nd], 0, 0, 0);
            }
        }
    }
#pragma unroll
    for (int nd = 0; nd < 4; ++nd)
#pragma unroll
        for (int j = 0; j < 4; ++j) {
            int r = lk * 4 + j;
            ctx[((size_t)(q0 + w * 16 + r) * NH_ + h) * HD_ + nd * 16 + lm] = o_[nd][j] / l_[j];
        }
}

// ---------------- Router
__global__ __launch_bounds__(64) void router_k(const float* __restrict__ x2,
                                               const float* __restrict__ gw,
                                               int* __restrict__ cnt,
                                               int* __restrict__ elist,
                                               int* __restrict__ eslot,
                                               float* __restrict__ wslot)
{
    int n = blockIdx.x, lane = threadIdx.x;
    float part[E_];
#pragma unroll
    for (int e = 0; e < E_; ++e) part[e] = 0.f;
    const float* xr = x2 + (size_t)n * H_;
    for (int j = lane; j < H_; j += 64) {
        float xv = xr[j];
#pragma unroll
        for (int e = 0; e < E_; ++e) part[e] = fmaf(xv, gw[e * H_ + j], part[e]);
    }
#pragma unroll
    for (int e = 0; e < E_; ++e)
#pragma unroll
        for (int off = 32; off > 0; off >>= 1) part[e] += __shfl_xor(part[e], off);
    if (lane == 0) {
        float mx = part[0];
#pragma unroll
        for (int e = 1; e < E_; ++e) mx = fmaxf(mx, part[e]);
        float rw[E_]; float ssum = 0.f;
#pragma unroll
        for (int e = 0; e < E_; ++e) { rw[e] = expf(part[e] - mx); ssum += rw[e]; }
#pragma unroll
        for (int e = 0; e < E_; ++e) rw[e] /= ssum;
        float best = -1.f; int ba = 0, bb = 1;
        for (int a = 0; a < E_; ++a)
            for (int b = a + 1; b < E_; ++b) {
                float scv = rw[a] + rw[b];
                if (scv > best) { best = scv; ba = a; bb = b; }
            }
        float wa = rw[ba], wb = rw[bb], wsum = wa + wb;
        wa /= wsum; wb /= wsum;
        int p = atomicAdd(&cnt[ba], 1);
        elist[ba * S_ + p] = n; eslot[ba * S_ + p] = 2 * n;
        p = atomicAdd(&cnt[bb], 1);
        elist[bb * S_ + p] = n; eslot[bb * S_ + p] = 2 * n + 1;
        wslot[2 * n] = wa; wslot[2 * n + 1] = wb;
    }
}

// ---------------- MoE up via global_load_lds (WB path): 128(M) x 64(N), BK=64.
// LDS dest linear; global SOURCE chunk pre-swizzled (kg ^ row&7); reads re-apply XOR.
__global__ __launch_bounds__(256) void moe_up_g(const unsigned short* __restrict__ x2b,
                                                const unsigned short* __restrict__ w1b,
                                                const unsigned short* __restrict__ w3b,
                                                const int* __restrict__ cnt,
                                                const int* __restrict__ elist,
                                                const int* __restrict__ eslot,
                                                unsigned short* __restrict__ hbuf)
{
    int e = blockIdx.z;
    int c = cnt[e];
    int p0 = blockIdx.y * 128;
    if (p0 >= c) return;
    int i0 = blockIdx.x * 64;
    int tid = threadIdx.x;

    __shared__ char As[16384], B1s[8192], B3s[8192];   // 32 KB
    __shared__ int rowtokS[128], rowslotS[128];
    if (tid < 128) {
        int p = min(p0 + tid, c - 1);
        rowtokS[tid]  = elist[e * S_ + p];
        rowslotS[tid] = eslot[e * S_ + p];
    }
    __syncthreads();

    int lane = tid & 63, w = tid >> 6, wm = w >> 1, wn = w & 1;
    int lm = lane & 15, lk = lane >> 4;
    int wb16 = (tid & ~63) * 16;      // wave-uniform LDS base term
    size_t wbase = (size_t)e * I_ * H_;

    f32x4 z = {0.f, 0.f, 0.f, 0.f};
    f32x4 acc1[4][2], acc3[4][2];
#pragma unroll
    for (int mf = 0; mf < 4; ++mf)
#pragma unroll
        for (int nf = 0; nf < 2; ++nf) { acc1[mf][nf] = z; acc3[mf][nf] = z; }

    for (int kt = 0; kt < H_ / 64; ++kt) {
        int kb = kt * 64;
#pragma unroll
        for (int it = 0; it < 4; ++it) {
            int g = tid + it * 256, row = g >> 3, kg = g & 7;
            int kgs = kg ^ (row & 7);            // pre-swizzled source chunk
            gload16u(x2b + (size_t)rowtokS[row] * H_ + kb + kgs * 8, As, wb16 + it * 4096);
        }
#pragma unroll
        for (int it = 0; it < 2; ++it) {
            int g = tid + it * 256, row = g >> 3, kg = g & 7;
            int kgs = kg ^ (row & 7);
            size_t off = wbase + (size_t)(i0 + row) * H_ + kb + kgs * 8;
            gload16u(w1b + off, B1s, wb16 + it * 4096);
            gload16u(w3b + off, B3s, wb16 + it * 4096);
        }
        vmdrain();
        __syncthreads();   // all loads landed across all waves
#pragma unroll
        for (int ks = 0; ks < 2; ++ks) {
            bf16x8 af[4];
#pragma unroll
            for (int mf = 0; mf < 4; ++mf) {
                int row = wm * 64 + mf * 16 + lm;
                af[mf] = *(const bf16x8*)(As + row * 128 + ((ks * 64 + lk * 16) ^ ((row & 7) << 4)));
            }
#pragma unroll
            for (int nf = 0; nf < 2; ++nf) {
                int brow = wn * 32 + nf * 16 + lm;
                int bby = brow * 128 + ((ks * 64 + lk * 16) ^ ((brow & 7) << 4));
                bf16x8 b1 = *(const bf16x8*)(B1s + bby);
                bf16x8 b3 = *(const bf16x8*)(B3s + bby);
#pragma unroll
                for (int mf = 0; mf < 4; ++mf) {
                    acc1[mf][nf] = __builtin_amdgcn_mfma_f32_16x16x32_bf16(af[mf], b1, acc1[mf][nf], 0, 0, 0);
                    acc3[mf][nf] = __builtin_amdgcn_mfma_f32_16x16x32_bf16(af[mf], b3, acc3[mf][nf], 0, 0, 0);
                }
            }
        }
        __syncthreads();   // reads done before next overwrite
    }

#pragma unroll
    for (int mf = 0; mf < 4; ++mf)
#pragma unroll
        for (int nf = 0; nf < 2; ++nf) {
            int coli = i0 + wn * 32 + nf * 16 + lm;
#pragma unroll
            for (int j = 0; j < 4; ++j) {
                int rloc = wm * 64 + mf * 16 + lk * 4 + j;
                if (p0 + rloc < c) {
                    float h1 = acc1[mf][nf][j];
                    float val = h1 / (1.f + __expf(-h1)) * acc3[mf][nf][j];
                    hbuf[(size_t)rowslotS[rloc] * I_ + coli] = f2bf(val);
                }
            }
        }
}

// ---------------- MoE down via global_load_lds (WB path): 128x128, BK=64, split-K.
__global__ __launch_bounds__(256) void moe_dn_g(const unsigned short* __restrict__ hbuf,
                                                const unsigned short* __restrict__ w2b,
                                                const int* __restrict__ cnt,
                                                const int* __restrict__ eslot,
                                                unsigned short* __restrict__ dbuf)
{
    int e = blockIdx.z >> 2;           // KSLC == 4
    int slice = blockIdx.z & 3;
    int c = cnt[e];
    int p0 = blockIdx.y * 128;
    if (p0 >= c) return;
    int h0 = blockIdx.x * 128;
    int tid = threadIdx.x;
    const int kb0 = slice * (I_ / KSLC);

    __shared__ char As[16384], Bs[16384];   // 32 KB
    __shared__ int rowslotS[128];
    if (tid < 128) rowslotS[tid] = eslot[e * S_ + min(p0 + tid, c - 1)];
    __syncthreads();

    int lane = tid & 63, w = tid >> 6, wm = w >> 1, wn = w & 1;
    int lm = lane & 15, lk = lane >> 4;
    int wb16 = (tid & ~63) * 16;
    size_t wbase = (size_t)e * H_ * I_;

    f32x4 z = {0.f, 0.f, 0.f, 0.f};
    f32x4 acc[4][4];
#pragma unroll
    for (int mf = 0; mf < 4; ++mf)
#pragma unroll
        for (int nf = 0; nf < 4; ++nf) acc[mf][nf] = z;

    const int NKT = (I_ / KSLC) / 64;        // 14
    for (int kt = 0; kt < NKT; ++kt) {
        int kb = kb0 + kt * 64;
#pragma unroll
        for (int it = 0; it < 4; ++it) {
            int g = tid + it * 256, row = g >> 3, kg = g & 7;
            int kgs = kg ^ (row & 7);
            gload16u(hbuf + (size_t)rowslotS[row] * I_ + kb + kgs * 8, As, wb16 + it * 4096);
            gload16u(w2b + wbase + (size_t)(h0 + row) * I_ + kb + kgs * 8, Bs, wb16 + it * 4096);
        }
        vmdrain();
        __syncthreads();
#pragma unroll
        for (int ks = 0; ks < 2; ++ks) {
            bf16x8 af[4];
#pragma unroll
            for (int mf = 0; mf < 4; ++mf) {
                int row = wm * 64 + mf * 16 + lm;
                af[mf] = *(const bf16x8*)(As + row * 128 + ((ks * 64 + lk * 16) ^ ((row & 7) << 4)));
            }
#pragma unroll
            for (int nf = 0; nf < 4; ++nf) {
                int brow = wn * 64 + nf * 16 + lm;
                bf16x8 bf = *(const bf16x8*)(Bs + brow * 128 + ((ks * 64 + lk * 16) ^ ((brow & 7) << 4)));
#pragma unroll
                for (int mf = 0; mf < 4; ++mf)
                    acc[mf][nf] = __builtin_amdgcn_mfma_f32_16x16x32_bf16(af[mf], bf, acc[mf][nf], 0, 0, 0);
            }
        }
        __syncthreads();
    }

    unsigned short* dslice = dbuf + (size_t)slice * S_ * 2 * H_;
#pragma unroll
    for (int mf = 0; mf < 4; ++mf)
#pragma unroll
        for (int nf = 0; nf < 4; ++nf) {
            int colh = h0 + wn * 64 + nf * 16 + lm;
#pragma unroll
            for (int j = 0; j < 4; ++j) {
                int rloc = wm * 64 + mf * 16 + lk * 4 + j;
                if (p0 + rloc < c)
                    dslice[(size_t)rowslotS[rloc] * H_ + colh] = f2bf(acc[mf][nf][j]);
            }
        }
}

// ---------------- MoE up (reg-staged, WB=false fallback), 128x64, BK=64
template<bool WB>
__global__ __launch_bounds__(256) void moe_up_mfma(const float* __restrict__ x2,
                                                   const void* __restrict__ w1,
                                                   const void* __restrict__ w3,
                                                   const int* __restrict__ cnt,
                                                   const int* __restrict__ elist,
                                                   const int* __restrict__ eslot,
                                                   unsigned short* __restrict__ hbuf)
{
    int e = blockIdx.z;
    int c = cnt[e];
    int p0 = blockIdx.y * 128;
    if (p0 >= c) return;
    int i0 = blockIdx.x * 64;
    int tid = threadIdx.x;

    __shared__ char As[16384], B1s[8192], B3s[8192];
    __shared__ int rowtokS[128], rowslotS[128];
    if (tid < 128) {
        int p = min(p0 + tid, c - 1);
        rowtokS[tid]  = elist[e * S_ + p];
        rowslotS[tid] = eslot[e * S_ + p];
    }
    __syncthreads();

    int lane = tid & 63, w = tid >> 6, wm = w >> 1, wn = w & 1;
    int lm = lane & 15, lk = lane >> 4;
    size_t wbase = (size_t)e * I_ * H_;

    int4 rA[4], rB1[2], rB3[2];
    auto loadAll = [&](int kb) {
#pragma unroll
        for (int it = 0; it < 4; ++it) {
            int g = tid + it * 256, row = g >> 3, kg = g & 7;
            const float* s = x2 + (size_t)rowtokS[row] * H_ + kb + kg * 8;
            float4 f0 = *(const float4*)s, f1 = *(const float4*)(s + 4);
            rA[it] = make_int4(pkbf(f0.x, f0.y), pkbf(f0.z, f0.w),
                               pkbf(f1.x, f1.y), pkbf(f1.z, f1.w));
        }
#pragma unroll
        for (int it = 0; it < 2; ++it) {
            int g = tid + it * 256, row = g >> 3, kg = g & 7;
            size_t off = wbase + (size_t)(i0 + row) * H_ + kb + kg * 8;
            rB1[it] = loadW16<WB>(w1, off);
            rB3[it] = loadW16<WB>(w3, off);
        }
    };
    auto writeAll = [&]() {
#pragma unroll
        for (int it = 0; it < 4; ++it) {
            int g = tid + it * 256, row = g >> 3, kg = g & 7;
            int byte = row * 128 + ((kg * 16) ^ ((row & 7) << 4));
            *(int4*)(As + byte) = rA[it];
        }
#pragma unroll
        for (int it = 0; it < 2; ++it) {
            int g = tid + it * 256, row = g >> 3, kg = g & 7;
            int byte = row * 128 + ((kg * 16) ^ ((row & 7) << 4));
            *(int4*)(B1s + byte) = rB1[it];
            *(int4*)(B3s + byte) = rB3[it];
        }
    };

    f32x4 z = {0.f, 0.f, 0.f, 0.f};
    f32x4 acc1[4][2], acc3[4][2];
#pragma unroll
    for (int mf = 0; mf < 4; ++mf)
#pragma unroll
        for (int nf = 0; nf < 2; ++nf) { acc1[mf][nf] = z; acc3[mf][nf] = z; }

    loadAll(0);
    for (int kt = 0; kt < H_ / 64; ++kt) {
        __syncthreads();
        writeAll();
        __syncthreads();
        if (kt + 1 < H_ / 64) loadAll((kt + 1) * 64);
#pragma unroll
        for (int ks = 0; ks < 2; ++ks) {
            bf16x8 af[4];
#pragma unroll
            for (int mf = 0; mf < 4; ++mf) {
                int row = wm * 64 + mf * 16 + lm;
                af[mf] = *(const bf16x8*)(As + row * 128 + ((ks * 64 + lk * 16) ^ ((row & 7) << 4)));
            }
#pragma unroll
            for (int nf = 0; nf < 2; ++nf) {
                int brow = wn * 32 + nf * 16 + lm;
                int bby = brow * 128 + ((ks * 64 + lk * 16) ^ ((brow & 7) << 4));
                bf16x8 b1 = *(const bf16x8*)(B1s + bby);
                bf16x8 b3 = *(const bf16x8*)(B3s + bby);
#pragma unroll
                for (int mf = 0; mf < 4; ++mf) {
                    acc1[mf][nf] = __builtin_amdgcn_mfma_f32_16x16x32_bf16(af[mf], b1, acc1[mf][nf], 0, 0, 0);
                    acc3[mf][nf] = __builtin_amdgcn_mfma_f32_16x16x32_bf16(af[mf], b3, acc3[mf][nf], 0, 0, 0);
                }
            }
        }
    }

#pragma unroll
    for (int mf = 0; mf < 4; ++mf)
#pragma unroll
        for (int nf = 0; nf < 2; ++nf) {
            int coli = i0 + wn * 32 + nf * 16 + lm;
#pragma unroll
            for (int j = 0; j < 4; ++j) {
                int rloc = wm * 64 + mf * 16 + lk * 4 + j;
                if (p0 + rloc < c) {
                    float h1 = acc1[mf][nf][j];
                    float val = h1 / (1.f + __expf(-h1)) * acc3[mf][nf][j];
                    hbuf[(size_t)rowslotS[rloc] * I_ + coli] = f2bf(val);
                }
            }
        }
}

// ---------------- MoE down (reg-staged, WB=false fallback), 128x128, BK=64, split-K
template<bool WB>
__global__ __launch_bounds__(256) void moe_dn_mfma(const unsigned short* __restrict__ hbuf,
                                                   const void* __restrict__ w2,
                                                   const int* __restrict__ cnt,
                                                   const int* __restrict__ eslot,
                                                   unsigned short* __restrict__ dbuf)
{
    int e = blockIdx.z >> 2;
    int slice = blockIdx.z & 3;
    int c = cnt[e];
    int p0 = blockIdx.y * 128;
    if (p0 >= c) return;
    int h0 = blockIdx.x * 128;
    int tid = threadIdx.x;
    const int kb0 = slice * (I_ / KSLC);

    __shared__ char As[16384], Bs[16384];
    __shared__ int rowslotS[128];
    if (tid < 128) rowslotS[tid] = eslot[e * S_ + min(p0 + tid, c - 1)];
    __syncthreads();

    int lane = tid & 63, w = tid >> 6, wm = w >> 1, wn = w & 1;
    int lm = lane & 15, lk = lane >> 4;
    size_t wbase = (size_t)e * H_ * I_;

    int4 rA[4], rB[4];
    auto loadAll = [&](int kb) {
#pragma unroll
        for (int it = 0; it < 4; ++it) {
            int g = tid + it * 256, row = g >> 3, kg = g & 7;
            rA[it] = *(const int4*)(hbuf + (size_t)rowslotS[row] * I_ + kb + kg * 8);
            rB[it] = loadW16<WB>(w2, wbase + (size_t)(h0 + row) * I_ + kb + kg * 8);
        }
    };
    auto writeAll = [&]() {
#pragma unroll
        for (int it = 0; it < 4; ++it) {
            int g = tid + it * 256, row = g >> 3, kg = g & 7;
            int byte = row * 128 + ((kg * 16) ^ ((row & 7) << 4));
            *(int4*)(As + byte) = rA[it];
            *(int4*)(Bs + byte) = rB[it];
        }
    };

    f32x4 z = {0.f, 0.f, 0.f, 0.f};
    f32x4 acc[4][4];
#pragma unroll
    for (int mf = 0; mf < 4; ++mf)
#pragma unroll
        for (int nf = 0; nf < 4; ++nf) acc[mf][nf] = z;

    loadAll(kb0);
    const int NKT = (I_ / KSLC) / 64;
    for (int kt = 0; kt < NKT; ++kt) {
        __syncthreads();
        writeAll();
        __syncthreads();
        if (kt + 1 < NKT) loadAll(kb0 + (kt + 1) * 64);
#pragma unroll
        for (int ks = 0; ks < 2; ++ks) {
            bf16x8 af[4];
#pragma unroll
            for (int mf = 0; mf < 4; ++mf) {
                int row = wm * 64 + mf * 16 + lm;
                af[mf] = *(const bf16x8*)(As + row * 128 + ((ks * 64 + lk * 16) ^ ((row & 7) << 4)));
            }
#pragma unroll
            for (int nf = 0; nf < 4; ++nf) {
                int brow = wn * 64 + nf * 16 + lm;
                bf16x8 bf = *(const bf16x8*)(Bs + brow * 128 + ((ks * 64 + lk * 16) ^ ((brow & 7) << 4)));
#pragma unroll
                for (int mf = 0; mf < 4; ++mf)
                    acc[mf][nf] = __builtin_amdgcn_mfma_f32_16x16x32_bf16(af[mf], bf, acc[mf][nf], 0, 0, 0);
            }
        }
    }

    unsigned short* dslice = dbuf + (size_t)slice * S_ * 2 * H_;
#pragma unroll
    for (int mf = 0; mf < 4; ++mf)
#pragma unroll
        for (int nf = 0; nf < 4; ++nf) {
            int colh = h0 + wn * 64 + nf * 16 + lm;
#pragma unroll
            for (int j = 0; j < 4; ++j) {
                int rloc = wm * 64 + mf * 16 + lk * 4 + j;
                if (p0 + rloc < c)
                    dslice[(size_t)rowslotS[rloc] * H_ + colh] = f2bf(acc[mf][nf][j]);
            }
        }
}

// ---------------- Final combine
__global__ __launch_bounds__(256) void combine_k(const float* __restrict__ hid2,
                                                 const unsigned short* __restrict__ dbuf,
                                                 const float* __restrict__ wslot,
                                                 float* __restrict__ out)
{
    int idx = blockIdx.x * 256 + threadIdx.x;
    if (idx >= S_ * H_) return;
    int n = idx >> 10;
    int hcol = idx & (H_ - 1);
    float s0 = 0.f, s1 = 0.f;
#pragma unroll
    for (int sl = 0; sl < KSLC; ++sl) {
        const unsigned short* base = dbuf + (size_t)sl * S_ * 2 * H_;
        s0 += bf2f(base[(size_t)(2 * n)     * H_ + hcol]);
        s1 += bf2f(base[(size_t)(2 * n + 1) * H_ + hcol]);
    }
    out[idx] = hid2[idx] + wslot[2 * n] * s0 + wslot[2 * n + 1] * s1;
}

extern "C" void kernel_launch(void* const* d_in, const int* in_sizes, int n_in,
                              void* d_out, int out_size, void* d_ws, size_t ws_size,
                              hipStream_t stream)
{
    const float* hidden = (const float*)d_in[0];
    const float* ln1    = (const float*)d_in[1];
    const float* ln2    = (const float*)d_in[2];
    const float* wq     = (const float*)d_in[3];
    const float* wk     = (const float*)d_in[4];
    const float* wv     = (const float*)d_in[5];
    const float* wo     = (const float*)d_in[6];
    const float* gw     = (const float*)d_in[7];
    const float* w1     = (const float*)d_in[8];
    const float* w2     = (const float*)d_in[9];
    const float* w3     = (const float*)d_in[10];
    float* out = (float*)d_out;

    char* p = (char*)d_ws;
    auto alignp = [&]() { p = (char*)(((uintptr_t)p + 255) & ~(uintptr_t)255); };
    auto alloc_f = [&](size_t n) { alignp(); float* r = (float*)p; p += n * 4; return r; };
    auto alloc_h = [&](size_t n) { alignp(); unsigned short* r = (unsigned short*)p; p += n * 2; return r; };
    auto alloc_i = [&](size_t n) { alignp(); int* r = (int*)p; p += n * 4; return r; };

    float* xb   = alloc_f((size_t)S_ * H_);
    float* q    = alloc_f((size_t)S_ * NH_ * HD_);
    float* kb   = alloc_f((size_t)S_ * KVH_ * HD_);
    float* vb   = alloc_f((size_t)S_ * KVH_ * HD_);
    float* hid2 = alloc_f((size_t)S_ * H_);
    float* x2   = alloc_f((size_t)S_ * H_);
    unsigned short* x2b  = alloc_h((size_t)S_ * H_);
    unsigned short* hbuf = alloc_h((size_t)S_ * 2 * I_);
    unsigned short* dbuf = alloc_h((size_t)KSLC * S_ * 2 * H_);
    float* wslot= alloc_f((size_t)S_ * 2);
    unsigned short* qbf = alloc_h((size_t)S_ * NH_ * HD_);
    unsigned short* kbf = alloc_h((size_t)S_ * KVH_ * HD_);
    unsigned short* vtb = alloc_h((size_t)KVH_ * HD_ * S_);
    int* cnt   = alloc_i(E_);
    int* elist = alloc_i((size_t)E_ * S_);
    int* eslot = alloc_i((size_t)E_ * S_);
    float* ctx = xb;

    size_t used = (size_t)(p - (char*)d_ws);
    const size_t nW = (size_t)E_ * I_ * H_;
    size_t wbf_bytes = (3 * nW + (size_t)(NH_*HD_ + 2*KVH_*HD_ + H_) * H_) * 2 + 4096;
    bool WB = ws_size > used && (ws_size - used) >= wbf_bytes;

    unsigned short *w1b = nullptr, *w3b = nullptr, *w2b = nullptr;
    unsigned short *wqb = nullptr, *wkb = nullptr, *wvb = nullptr, *wob = nullptr;
    if (WB) {
        w1b = alloc_h(nW); w3b = alloc_h(nW); w2b = alloc_h(nW);
        wqb = alloc_h((size_t)NH_ * HD_ * H_);
        wkb = alloc_h((size_t)KVH_ * HD_ * H_);
        wvb = alloc_h((size_t)KVH_ * HD_ * H_);
        wob = alloc_h((size_t)H_ * NH_ * HD_);
    }

    hipMemsetAsync(cnt, 0, E_ * sizeof(int), stream);

    if (WB) {
        conv_bf16<<<2048, 256, 0, stream>>>(w1, w1b, (long)(nW / 8));
        conv_bf16<<<2048, 256, 0, stream>>>(w3, w3b, (long)(nW / 8));
        conv_bf16<<<2048, 256, 0, stream>>>(w2, w2b, (long)(nW / 8));
        conv_bf16<<<512, 256, 0, stream>>>(wq, wqb, (long)((size_t)NH_*HD_*H_ / 8));
        conv_bf16<<<512, 256, 0, stream>>>(wk, wkb, (long)((size_t)KVH_*HD_*H_ / 8));
        conv_bf16<<<512, 256, 0, stream>>>(wv, wvb, (long)((size_t)KVH_*HD_*H_ / 8));
        conv_bf16<<<512, 256, 0, stream>>>(wo, wob, (long)((size_t)H_*NH_*HD_ / 8));
    }

    rmsnorm_k<<<S_, 256, 0, stream>>>(hidden, ln1, xb, nullptr);

    if (WB) {
        dense_mfma<true><<<dim3(8, 16),  256, 0, stream>>>(xb, wqb, nullptr, q,  S_, NH_ * HD_, H_);
        dense_mfma<true><<<dim3(4, 16),  256, 0, stream>>>(xb, wkb, nullptr, kb, S_, KVH_ * HD_, H_);
        dense_mfma<true><<<dim3(4, 16),  256, 0, stream>>>(xb, wvb, nullptr, vb, S_, KVH_ * HD_, H_);
    } else {
        dense_mfma<false><<<dim3(8, 16), 256, 0, stream>>>(xb, wq, nullptr, q,  S_, NH_ * HD_, H_);
        dense_mfma<false><<<dim3(4, 16), 256, 0, stream>>>(xb, wk, nullptr, kb, S_, KVH_ * HD_, H_);
        dense_mfma<false><<<dim3(4, 16), 256, 0, stream>>>(xb, wv, nullptr, vb, S_, KVH_ * HD_, H_);
    }
    {
        int tot = S_ * (NH_ + KVH_) * 32;
        rope_conv<<<SDIV(tot, 256), 256, 0, stream>>>(q, kb, qbf, kbf);
    }
    v_trans<<<dim3(S_ / 64, KVH_), 256, 0, stream>>>(vb, vtb);
    attn_mfma<<<dim3(16, NH_, 2), 256, 0, stream>>>(qbf, kbf, vtb, ctx);

    if (WB)
        dense_mfma<true><<<dim3(8, 16),  256, 0, stream>>>(ctx, wob, hidden, hid2, S_, H_, NH_ * HD_);
    else
        dense_mfma<false><<<dim3(8, 16), 256, 0, stream>>>(ctx, wo, hidden, hid2, S_, H_, NH_ * HD_);

    rmsnorm_k<<<S_, 256, 0, stream>>>(hid2, ln2, x2, x2b);
    router_k<<<S_, 64, 0, stream>>>(x2, gw, cnt, elist, eslot, wslot);

    if (WB) {
        moe_up_g<<<dim3(I_ / 64, S_ / 128, E_), 256, 0, stream>>>(x2b, w1b, w3b, cnt, elist, eslot, hbuf);
        moe_dn_g<<<dim3(H_ / 128, S_ / 128, E_ * KSLC), 256, 0, stream>>>(hbuf, w2b, cnt, eslot, dbuf);
    } else {
        moe_up_mfma<false><<<dim3(I_ / 64, S_ / 128, E_), 256, 0, stream>>>(x2, w1, w3, cnt, elist, eslot, hbuf);
        moe_dn_mfma<false><<<dim3(H_ / 128, S_ / 128, E_ * KSLC), 256, 0, stream>>>(hbuf, w2, cnt, eslot, dbuf);
    }
    combine_k<<<SDIV(S_ * H_, 256), 256, 0, stream>>>(hid2, dbuf, wslot, out);
}

// Round 11
// 467.520 us; speedup vs baseline: 7.0226x; 1.1531x over previous
//
#include <hip/hip_runtime.h>
#include <hip/hip_bf16.h>
#include <math.h>

constexpr int S_ = 2048, H_ = 1024, NH_ = 16, KVH_ = 8, HD_ = 64;
constexpr int E_ = 8, I_ = 3584;
constexpr int KSLC = 4;                 // split-K slices for MoE down
constexpr float EPS_ = 1e-6f;
constexpr float THETA_ = 1000000.0f;

#define SDIV(a,b) (((a)+(b)-1)/(b))

typedef __attribute__((ext_vector_type(8))) short bf16x8;
typedef __attribute__((ext_vector_type(4))) float f32x4;

__device__ inline unsigned pkbf(float a, float b) {
    unsigned r;
    asm("v_cvt_pk_bf16_f32 %0, %1, %2" : "=v"(r) : "v"(a), "v"(b));
    return r;
}
__device__ inline unsigned short f2bf(float f) {
    unsigned u = __float_as_uint(f);
    u += 0x7FFF + ((u >> 16) & 1);
    return (unsigned short)(u >> 16);
}
__device__ inline float bf2f(unsigned short v) {
    return __uint_as_float((unsigned)v << 16);
}

// async global->LDS, 16B/lane. LDS base FORCED wave-uniform via readfirstlane;
// lane l lands at base + l*16 (m104 semantics). Global src stays per-lane.
__device__ inline void gload16u(const void* gsrc, char* ldsArr, int uoff) {
    int off = __builtin_amdgcn_readfirstlane(uoff);
    __builtin_amdgcn_global_load_lds(
        (__attribute__((address_space(1))) void*)(gsrc),
        (__attribute__((address_space(3))) void*)(ldsArr + off), 16, 0, 0);
}
__device__ inline void vmdrain() {
    asm volatile("s_waitcnt vmcnt(0)" ::: "memory");
}

template<bool WB>
__device__ inline int4 loadW16(const void* W, size_t elemOff) {
    if constexpr (WB) {
        return *(const int4*)((const unsigned short*)W + elemOff);
    } else {
        const float* s = (const float*)W + elemOff;
        float4 f0 = *(const float4*)s, f1 = *(const float4*)(s + 4);
        return make_int4(pkbf(f0.x, f0.y), pkbf(f0.z, f0.w),
                         pkbf(f1.x, f1.y), pkbf(f1.z, f1.w));
    }
}

// ---------------- fp32 -> bf16 bulk convert
__global__ __launch_bounds__(256) void conv_bf16(const float* __restrict__ in,
                                                 unsigned short* __restrict__ out, long n8)
{
    long i = (long)blockIdx.x * 256 + threadIdx.x;
    long stride = (long)gridDim.x * 256;
    for (; i < n8; i += stride) {
        const float* s = in + i * 8;
        float4 f0 = *(const float4*)s, f1 = *(const float4*)(s + 4);
        *(int4*)(out + i * 8) = make_int4(pkbf(f0.x, f0.y), pkbf(f0.z, f0.w),
                                          pkbf(f1.x, f1.y), pkbf(f1.z, f1.w));
    }
}

// ---------------- RMSNorm (optionally also emits bf16 copy)
__global__ __launch_bounds__(256) void rmsnorm_k(const float* __restrict__ x,
                                                 const float* __restrict__ w,
                                                 float* __restrict__ out,
                                                 unsigned short* __restrict__ outb)
{
    int row = blockIdx.x;
    int tid = threadIdx.x;
    const float* xr = x + (size_t)row * H_;
    float4 v = *(const float4*)&xr[tid * 4];
    float ss = v.x*v.x + v.y*v.y + v.z*v.z + v.w*v.w;
#pragma unroll
    for (int off = 32; off > 0; off >>= 1) ss += __shfl_xor(ss, off);
    __shared__ float red[4];
    if ((tid & 63) == 0) red[tid >> 6] = ss;
    __syncthreads();
    float tot = red[0] + red[1] + red[2] + red[3];
    float r = rsqrtf(tot / (float)H_ + EPS_);
    float4 wv = *(const float4*)&w[tid * 4];
    float4 o;
    o.x = v.x * r * wv.x; o.y = v.y * r * wv.y;
    o.z = v.z * r * wv.z; o.w = v.w * r * wv.w;
    *(float4*)&out[(size_t)row * H_ + tid * 4] = o;
    if (outb) {
        uint2 pk = make_uint2(pkbf(o.x, o.y), pkbf(o.z, o.w));
        *(uint2*)&outb[(size_t)row * H_ + tid * 4] = pk;
    }
}

// ---------------- Dense g-style GEMM (WB path): 128(M) x 64(N), BK=64.
// A,B bf16; OUTF32: fp32 out (+Res); else bf16 out. Pre-swizzled source + swizzled read.
template<bool OUTF32>
__global__ __launch_bounds__(256) void dense_g(const unsigned short* __restrict__ A,
                                               const unsigned short* __restrict__ B,
                                               const float* __restrict__ Res,
                                               void* __restrict__ C,
                                               int K, int ldC)
{
    int m0 = blockIdx.y * 128, n0 = blockIdx.x * 64;
    int tid = threadIdx.x;
    __shared__ char As[16384], Bs[8192];
    int lane = tid & 63, w = tid >> 6, wm = w >> 1, wn = w & 1;
    int lm = lane & 15, lk = lane >> 4;
    int wb16 = (tid & ~63) * 16;

    f32x4 z = {0.f, 0.f, 0.f, 0.f};
    f32x4 acc[4][2];
#pragma unroll
    for (int mf = 0; mf < 4; ++mf)
#pragma unroll
        for (int nf = 0; nf < 2; ++nf) acc[mf][nf] = z;

    for (int kt = 0; kt < K / 64; ++kt) {
        int kb = kt * 64;
#pragma unroll
        for (int it = 0; it < 4; ++it) {
            int g = tid + it * 256, row = g >> 3, kg = g & 7;
            int kgs = kg ^ (row & 7);
            gload16u(A + (size_t)(m0 + row) * K + kb + kgs * 8, As, wb16 + it * 4096);
        }
#pragma unroll
        for (int it = 0; it < 2; ++it) {
            int g = tid + it * 256, row = g >> 3, kg = g & 7;
            int kgs = kg ^ (row & 7);
            gload16u(B + (size_t)(n0 + row) * K + kb + kgs * 8, Bs, wb16 + it * 4096);
        }
        vmdrain();
        __syncthreads();
#pragma unroll
        for (int ks = 0; ks < 2; ++ks) {
            bf16x8 af[4];
#pragma unroll
            for (int mf = 0; mf < 4; ++mf) {
                int row = wm * 64 + mf * 16 + lm;
                af[mf] = *(const bf16x8*)(As + row * 128 + ((ks * 64 + lk * 16) ^ ((row & 7) << 4)));
            }
#pragma unroll
            for (int nf = 0; nf < 2; ++nf) {
                int brow = wn * 32 + nf * 16 + lm;
                bf16x8 bf = *(const bf16x8*)(Bs + brow * 128 + ((ks * 64 + lk * 16) ^ ((brow & 7) << 4)));
#pragma unroll
                for (int mf = 0; mf < 4; ++mf)
                    acc[mf][nf] = __builtin_amdgcn_mfma_f32_16x16x32_bf16(af[mf], bf, acc[mf][nf], 0, 0, 0);
            }
        }
        __syncthreads();
    }

#pragma unroll
    for (int mf = 0; mf < 4; ++mf)
#pragma unroll
        for (int nf = 0; nf < 2; ++nf) {
            int col = n0 + wn * 32 + nf * 16 + lm;
#pragma unroll
            for (int j = 0; j < 4; ++j) {
                int row = m0 + wm * 64 + mf * 16 + lk * 4 + j;
                float v = acc[mf][nf][j];
                if constexpr (OUTF32) {
                    float r = Res ? Res[(size_t)row * ldC + col] : 0.0f;
                    ((float*)C)[(size_t)row * ldC + col] = v + r;
                } else {
                    ((unsigned short*)C)[(size_t)row * ldC + col] = f2bf(v);
                }
            }
        }
}

// ---------------- Dense bf16-MFMA GEMM (reg-staged; WB=false fallback)
template<bool WB>
__global__ __launch_bounds__(256) void dense_mfma(const float* __restrict__ A,
                                                  const void* __restrict__ Bw,
                                                  const float* __restrict__ Res,
                                                  float* __restrict__ C,
                                                  int M, int N, int K)
{
    __shared__ char As[16384], Bs[16384];
    int tid = threadIdx.x;
    int m0 = blockIdx.y * 128, n0 = blockIdx.x * 128;
    int lane = tid & 63, w = tid >> 6, wm = w >> 1, wn = w & 1;
    int lm = lane & 15, lk = lane >> 4;

    int4 rA[4], rB[4];
    auto loadAll = [&](int kb) {
#pragma unroll
        for (int it = 0; it < 4; ++it) {
            int g = tid + it * 256, row = g >> 3, kg = g & 7;
            const float* s = A + (size_t)(m0 + row) * K + kb + kg * 8;
            float4 f0 = *(const float4*)s, f1 = *(const float4*)(s + 4);
            rA[it] = make_int4(pkbf(f0.x, f0.y), pkbf(f0.z, f0.w),
                               pkbf(f1.x, f1.y), pkbf(f1.z, f1.w));
            rB[it] = loadW16<WB>(Bw, (size_t)(n0 + row) * K + kb + kg * 8);
        }
    };
    auto writeAll = [&]() {
#pragma unroll
        for (int it = 0; it < 4; ++it) {
            int g = tid + it * 256, row = g >> 3, kg = g & 7;
            int byte = row * 128 + ((kg * 16) ^ ((row & 7) << 4));
            *(int4*)(As + byte) = rA[it];
            *(int4*)(Bs + byte) = rB[it];
        }
    };

    f32x4 z = {0.f, 0.f, 0.f, 0.f};
    f32x4 acc[4][4];
#pragma unroll
    for (int mf = 0; mf < 4; ++mf)
#pragma unroll
        for (int nf = 0; nf < 4; ++nf) acc[mf][nf] = z;

    loadAll(0);
    for (int kt = 0; kt < K / 64; ++kt) {
        __syncthreads();
        writeAll();
        __syncthreads();
        if (kt + 1 < K / 64) loadAll((kt + 1) * 64);
#pragma unroll
        for (int ks = 0; ks < 2; ++ks) {
            bf16x8 af[4];
#pragma unroll
            for (int mf = 0; mf < 4; ++mf) {
                int row = wm * 64 + mf * 16 + lm;
                af[mf] = *(const bf16x8*)(As + row * 128 + ((ks * 64 + lk * 16) ^ ((row & 7) << 4)));
            }
#pragma unroll
            for (int nf = 0; nf < 4; ++nf) {
                int brow = wn * 64 + nf * 16 + lm;
                bf16x8 bf = *(const bf16x8*)(Bs + brow * 128 + ((ks * 64 + lk * 16) ^ ((brow & 7) << 4)));
#pragma unroll
                for (int mf = 0; mf < 4; ++mf)
                    acc[mf][nf] = __builtin_amdgcn_mfma_f32_16x16x32_bf16(af[mf], bf, acc[mf][nf], 0, 0, 0);
            }
        }
    }

#pragma unroll
    for (int mf = 0; mf < 4; ++mf)
#pragma unroll
        for (int nf = 0; nf < 4; ++nf) {
            int col = n0 + wn * 64 + nf * 16 + lm;
#pragma unroll
            for (int j = 0; j < 4; ++j) {
                int row = m0 + wm * 64 + mf * 16 + lk * 4 + j;
                float r = Res ? Res[(size_t)row * N + col] : 0.0f;
                C[(size_t)row * N + col] = acc[mf][nf][j] + r;
            }
        }
}

// ---------------- RoPE + bf16 (WB path): reads fused bf16 qkvb [S][2048]
__global__ __launch_bounds__(256) void rope_conv_b(const unsigned short* __restrict__ qkvb,
                                                   unsigned short* __restrict__ qbf,
                                                   unsigned short* __restrict__ kbf)
{
    int idx = blockIdx.x * 256 + threadIdx.x;
    const int totq = S_ * NH_ * 32;
    const int tot = totq + S_ * KVH_ * 32;
    if (idx >= tot) return;
    const unsigned short* src; unsigned short* dst; int s, di; float sc;
    if (idx < totq) {
        s = idx / (NH_ * 32); int r = idx % (NH_ * 32); int h = r >> 5;
        src = qkvb + (size_t)s * 2048 + h * 64;
        dst = qbf + ((size_t)s * NH_ + h) * HD_;
        di = r & 31; sc = 0.125f;
    } else {
        int j2 = idx - totq;
        s = j2 / (KVH_ * 32); int r = j2 % (KVH_ * 32); int kvh = r >> 5;
        src = qkvb + (size_t)s * 2048 + 1024 + kvh * 64;
        dst = kbf + ((size_t)s * KVH_ + kvh) * HD_;
        di = r & 31; sc = 1.0f;
    }
    float invf = powf(THETA_, -(2.0f * di) / (float)HD_);
    float ang = (float)s * invf;
    float c = cosf(ang), sn = sinf(ang);
    float x0 = bf2f(src[di]), x1 = bf2f(src[di + 32]);
    dst[di]      = f2bf((x0 * c - x1 * sn) * sc);
    dst[di + 32] = f2bf((x1 * c + x0 * sn) * sc);
}

// ---------------- V transpose (WB path): V from qkvb cols [1536..2048)
__global__ __launch_bounds__(256) void v_trans_b(const unsigned short* __restrict__ qkvb,
                                                 unsigned short* __restrict__ vtb)
{
    int t0 = blockIdx.x * 64, kvh = blockIdx.y;
    __shared__ unsigned short T[64][64];
    int tid = threadIdx.x;
    int k = tid >> 2, d0 = (tid & 3) * 16;
    const unsigned short* src = qkvb + (size_t)(t0 + k) * 2048 + 1536 + kvh * 64 + d0;
    *(int4*)&T[k][d0]     = *(const int4*)(src);
    *(int4*)&T[k][d0 + 8] = *(const int4*)(src + 8);
    __syncthreads();
    int d = tid >> 2, s0 = (tid & 3) * 16;
    unsigned short tmp[16] __attribute__((aligned(16)));
#pragma unroll
    for (int x = 0; x < 16; ++x) {
        int s = s0 + x;
        int key = 16 * (s & 3) + (s >> 2);
        tmp[x] = T[key][d];
    }
    unsigned short* dst = vtb + ((size_t)kvh * HD_ + d) * S_ + t0 + s0;
    *(int4*)(dst)     = *(int4*)(tmp);
    *(int4*)(dst + 8) = *(int4*)(tmp + 8);
}

// ---------------- RoPE + bf16 convert (fallback: fp32 q/k inputs)
__global__ __launch_bounds__(256) void rope_conv(const float* __restrict__ q,
                                                 const float* __restrict__ k,
                                                 unsigned short* __restrict__ qbf,
                                                 unsigned short* __restrict__ kbf)
{
    int idx = blockIdx.x * 256 + threadIdx.x;
    const int totq = S_ * NH_ * 32;
    const int tot = totq + S_ * KVH_ * 32;
    if (idx >= tot) return;
    const float* base; unsigned short* obase; int s, di; float sc;
    if (idx < totq) {
        s = idx / (NH_ * 32); int r = idx % (NH_ * 32);
        size_t o = ((size_t)s * NH_ + (r >> 5)) * HD_;
        base = q + o; obase = qbf + o; di = r & 31; sc = 0.125f;
    } else {
        int j2 = idx - totq;
        s = j2 / (KVH_ * 32); int r = j2 % (KVH_ * 32);
        size_t o = ((size_t)s * KVH_ + (r >> 5)) * HD_;
        base = k + o; obase = kbf + o; di = r & 31; sc = 1.0f;
    }
    float invf = powf(THETA_, -(2.0f * di) / (float)HD_);
    float ang = (float)s * invf;
    float c = cosf(ang), sn = sinf(ang);
    float x0 = base[di], x1 = base[di + 32];
    obase[di]      = f2bf((x0 * c - x1 * sn) * sc);
    obase[di + 32] = f2bf((x1 * c + x0 * sn) * sc);
}

// ---------------- V transpose (fallback: fp32 V input)
__global__ __launch_bounds__(256) void v_trans(const float* __restrict__ v,
                                               unsigned short* __restrict__ vtb)
{
    int t0 = blockIdx.x * 64, kvh = blockIdx.y;
    __shared__ unsigned short T[64][64];
    int tid = threadIdx.x;
    int k = tid >> 2, d0 = (tid & 3) * 16;
    const float* src = v + ((size_t)(t0 + k) * KVH_ + kvh) * HD_ + d0;
#pragma unroll
    for (int x = 0; x < 4; ++x) {
        float4 f = *(const float4*)(src + x * 4);
        T[k][d0 + x*4 + 0] = f2bf(f.x);
        T[k][d0 + x*4 + 1] = f2bf(f.y);
        T[k][d0 + x*4 + 2] = f2bf(f.z);
        T[k][d0 + x*4 + 3] = f2bf(f.w);
    }
    __syncthreads();
    int d = tid >> 2, s0 = (tid & 3) * 16;
    unsigned short tmp[16] __attribute__((aligned(16)));
#pragma unroll
    for (int x = 0; x < 16; ++x) {
        int s = s0 + x;
        int key = 16 * (s & 3) + (s >> 2);
        tmp[x] = T[key][d];
    }
    unsigned short* dst = vtb + ((size_t)kvh * HD_ + d) * S_ + t0 + s0;
    *(int4*)(dst)     = *(int4*)(tmp);
    *(int4*)(dst + 8) = *(int4*)(tmp + 8);
}

// ---------------- MFMA flash attention (writes fp32 ctx + bf16 ctxb)
__global__ __launch_bounds__(256) void attn_mfma(const unsigned short* __restrict__ qbf,
                                                 const unsigned short* __restrict__ kbf,
                                                 const unsigned short* __restrict__ vtb,
                                                 float* __restrict__ ctx,
                                                 unsigned short* __restrict__ ctxb)
{
    __shared__ char Ps[4 * 2048];
    int pair = blockIdx.x, h = blockIdx.y, z = blockIdx.z;
    int qb = z ? (31 - pair) : pair;
    int q0 = qb * 64;
    int kvh = h >> 1;
    int tid = threadIdx.x;
    int w = tid >> 6, lane = tid & 63;
    int lm = lane & 15, lk = lane >> 4;
    char* myP = Ps + w * 2048;

    bf16x8 qf[2];
    const unsigned short* qrow = qbf + ((size_t)(q0 + w * 16 + lm) * NH_ + h) * HD_;
#pragma unroll
    for (int ks = 0; ks < 2; ++ks)
        qf[ks] = *(const bf16x8*)(qrow + ks * 32 + lk * 8);

    float m_[4], l_[4];
    f32x4 o_[4];
#pragma unroll
    for (int j = 0; j < 4; ++j) { m_[j] = -1e30f; l_[j] = 0.f; }
    f32x4 zf = {0.f, 0.f, 0.f, 0.f};
#pragma unroll
    for (int nd = 0; nd < 4; ++nd) o_[nd] = zf;

    for (int t0 = 0; t0 <= q0; t0 += 64) {
        f32x4 s[4];
#pragma unroll
        for (int nf = 0; nf < 4; ++nf) {
            const unsigned short* krow = kbf + ((size_t)(t0 + nf * 16 + lm) * KVH_ + kvh) * HD_;
            bf16x8 k0 = *(const bf16x8*)(krow + lk * 8);
            bf16x8 k1 = *(const bf16x8*)(krow + 32 + lk * 8);
            f32x4 acc = zf;
            acc = __builtin_amdgcn_mfma_f32_16x16x32_bf16(qf[0], k0, acc, 0, 0, 0);
            acc = __builtin_amdgcn_mfma_f32_16x16x32_bf16(qf[1], k1, acc, 0, 0, 0);
            s[nf] = acc;
        }
        if (t0 == q0) {
#pragma unroll
            for (int nf = 0; nf < 4; ++nf)
#pragma unroll
                for (int j = 0; j < 4; ++j) {
                    int key = nf * 16 + lm, qq = w * 16 + lk * 4 + j;
                    if (key > qq) s[nf][j] = -1e30f;
                }
        }
        float p_[4][4];
#pragma unroll
        for (int j = 0; j < 4; ++j) {
            float mx = fmaxf(fmaxf(s[0][j], s[1][j]), fmaxf(s[2][j], s[3][j]));
#pragma unroll
            for (int off = 8; off > 0; off >>= 1) mx = fmaxf(mx, __shfl_xor(mx, off));
            float nm = fmaxf(m_[j], mx);
            float rs = __expf(m_[j] - nm);
            float sum = 0.f;
#pragma unroll
            for (int nf = 0; nf < 4; ++nf) {
                float pv = __expf(s[nf][j] - nm);
                p_[nf][j] = pv; sum += pv;
            }
#pragma unroll
            for (int off = 8; off > 0; off >>= 1) sum += __shfl_xor(sum, off);
            l_[j] = l_[j] * rs + sum;
            m_[j] = nm;
#pragma unroll
            for (int nd = 0; nd < 4; ++nd) o_[nd][j] *= rs;
        }
#pragma unroll
        for (int j = 0; j < 4; ++j) {
            int r = lk * 4 + j;
            unsigned lo = pkbf(p_[0][j], p_[1][j]);
            unsigned hi = pkbf(p_[2][j], p_[3][j]);
            int byte = (lm * 8) ^ ((r & 7) << 4);
            *(uint2*)(myP + r * 128 + byte) = make_uint2(lo, hi);
        }
#pragma unroll
        for (int ks = 0; ks < 2; ++ks) {
            int byte = (ks * 64 + lk * 16) ^ ((lm & 7) << 4);
            bf16x8 pA = *(const bf16x8*)(myP + lm * 128 + byte);
#pragma unroll
            for (int nd = 0; nd < 4; ++nd) {
                const unsigned short* vrow = vtb + ((size_t)kvh * HD_ + nd * 16 + lm) * S_ + t0 + ks * 32 + lk * 8;
                bf16x8 vB = *(const bf16x8*)vrow;
                o_[nd] = __builtin_amdgcn_mfma_f32_16x16x32_bf16(pA, vB, o_[nd], 0, 0, 0);
            }
        }
    }
#pragma unroll
    for (int nd = 0; nd < 4; ++nd)
#pragma unroll
        for (int j = 0; j < 4; ++j) {
            int r = lk * 4 + j;
            float val = o_[nd][j] / l_[j];
            size_t oidx = ((size_t)(q0 + w * 16 + r) * NH_ + h) * HD_ + nd * 16 + lm;
            ctx[oidx] = val;
            ctxb[oidx] = f2bf(val);
        }
}

// ---------------- Router
__global__ __launch_bounds__(64) void router_k(const float* __restrict__ x2,
                                               const float* __restrict__ gw,
                                               int* __restrict__ cnt,
                                               int* __restrict__ elist,
                                               int* __restrict__ eslot,
                                               float* __restrict__ wslot)
{
    int n = blockIdx.x, lane = threadIdx.x;
    float part[E_];
#pragma unroll
    for (int e = 0; e < E_; ++e) part[e] = 0.f;
    const float* xr = x2 + (size_t)n * H_;
    for (int j = lane; j < H_; j += 64) {
        float xv = xr[j];
#pragma unroll
        for (int e = 0; e < E_; ++e) part[e] = fmaf(xv, gw[e * H_ + j], part[e]);
    }
#pragma unroll
    for (int e = 0; e < E_; ++e)
#pragma unroll
        for (int off = 32; off > 0; off >>= 1) part[e] += __shfl_xor(part[e], off);
    if (lane == 0) {
        float mx = part[0];
#pragma unroll
        for (int e = 1; e < E_; ++e) mx = fmaxf(mx, part[e]);
        float rw[E_]; float ssum = 0.f;
#pragma unroll
        for (int e = 0; e < E_; ++e) { rw[e] = expf(part[e] - mx); ssum += rw[e]; }
#pragma unroll
        for (int e = 0; e < E_; ++e) rw[e] /= ssum;
        float best = -1.f; int ba = 0, bb = 1;
        for (int a = 0; a < E_; ++a)
            for (int b = a + 1; b < E_; ++b) {
                float scv = rw[a] + rw[b];
                if (scv > best) { best = scv; ba = a; bb = b; }
            }
        float wa = rw[ba], wb = rw[bb], wsum = wa + wb;
        wa /= wsum; wb /= wsum;
        int p = atomicAdd(&cnt[ba], 1);
        elist[ba * S_ + p] = n; eslot[ba * S_ + p] = 2 * n;
        p = atomicAdd(&cnt[bb], 1);
        elist[bb * S_ + p] = n; eslot[bb * S_ + p] = 2 * n + 1;
        wslot[2 * n] = wa; wslot[2 * n + 1] = wb;
    }
}

// ---------------- MoE up via global_load_lds (WB path): 128(M) x 64(N), BK=64.
__global__ __launch_bounds__(256) void moe_up_g(const unsigned short* __restrict__ x2b,
                                                const unsigned short* __restrict__ w1b,
                                                const unsigned short* __restrict__ w3b,
                                                const int* __restrict__ cnt,
                                                const int* __restrict__ elist,
                                                const int* __restrict__ eslot,
                                                unsigned short* __restrict__ hbuf)
{
    int e = blockIdx.z;
    int c = cnt[e];
    int p0 = blockIdx.y * 128;
    if (p0 >= c) return;
    int i0 = blockIdx.x * 64;
    int tid = threadIdx.x;

    __shared__ char As[16384], B1s[8192], B3s[8192];
    __shared__ int rowtokS[128], rowslotS[128];
    if (tid < 128) {
        int p = min(p0 + tid, c - 1);
        rowtokS[tid]  = elist[e * S_ + p];
        rowslotS[tid] = eslot[e * S_ + p];
    }
    __syncthreads();

    int lane = tid & 63, w = tid >> 6, wm = w >> 1, wn = w & 1;
    int lm = lane & 15, lk = lane >> 4;
    int wb16 = (tid & ~63) * 16;
    size_t wbase = (size_t)e * I_ * H_;

    f32x4 z = {0.f, 0.f, 0.f, 0.f};
    f32x4 acc1[4][2], acc3[4][2];
#pragma unroll
    for (int mf = 0; mf < 4; ++mf)
#pragma unroll
        for (int nf = 0; nf < 2; ++nf) { acc1[mf][nf] = z; acc3[mf][nf] = z; }

    for (int kt = 0; kt < H_ / 64; ++kt) {
        int kb = kt * 64;
#pragma unroll
        for (int it = 0; it < 4; ++it) {
            int g = tid + it * 256, row = g >> 3, kg = g & 7;
            int kgs = kg ^ (row & 7);
            gload16u(x2b + (size_t)rowtokS[row] * H_ + kb + kgs * 8, As, wb16 + it * 4096);
        }
#pragma unroll
        for (int it = 0; it < 2; ++it) {
            int g = tid + it * 256, row = g >> 3, kg = g & 7;
            int kgs = kg ^ (row & 7);
            size_t off = wbase + (size_t)(i0 + row) * H_ + kb + kgs * 8;
            gload16u(w1b + off, B1s, wb16 + it * 4096);
            gload16u(w3b + off, B3s, wb16 + it * 4096);
        }
        vmdrain();
        __syncthreads();
#pragma unroll
        for (int ks = 0; ks < 2; ++ks) {
            bf16x8 af[4];
#pragma unroll
            for (int mf = 0; mf < 4; ++mf) {
                int row = wm * 64 + mf * 16 + lm;
                af[mf] = *(const bf16x8*)(As + row * 128 + ((ks * 64 + lk * 16) ^ ((row & 7) << 4)));
            }
#pragma unroll
            for (int nf = 0; nf < 2; ++nf) {
                int brow = wn * 32 + nf * 16 + lm;
                int bby = brow * 128 + ((ks * 64 + lk * 16) ^ ((brow & 7) << 4));
                bf16x8 b1 = *(const bf16x8*)(B1s + bby);
                bf16x8 b3 = *(const bf16x8*)(B3s + bby);
#pragma unroll
                for (int mf = 0; mf < 4; ++mf) {
                    acc1[mf][nf] = __builtin_amdgcn_mfma_f32_16x16x32_bf16(af[mf], b1, acc1[mf][nf], 0, 0, 0);
                    acc3[mf][nf] = __builtin_amdgcn_mfma_f32_16x16x32_bf16(af[mf], b3, acc3[mf][nf], 0, 0, 0);
                }
            }
        }
        __syncthreads();
    }

#pragma unroll
    for (int mf = 0; mf < 4; ++mf)
#pragma unroll
        for (int nf = 0; nf < 2; ++nf) {
            int coli = i0 + wn * 32 + nf * 16 + lm;
#pragma unroll
            for (int j = 0; j < 4; ++j) {
                int rloc = wm * 64 + mf * 16 + lk * 4 + j;
                if (p0 + rloc < c) {
                    float h1 = acc1[mf][nf][j];
                    float val = h1 / (1.f + __expf(-h1)) * acc3[mf][nf][j];
                    hbuf[(size_t)rowslotS[rloc] * I_ + coli] = f2bf(val);
                }
            }
        }
}

// ---------------- MoE down via global_load_lds (WB path): 128x128, BK=64, split-K.
__global__ __launch_bounds__(256) void moe_dn_g(const unsigned short* __restrict__ hbuf,
                                                const unsigned short* __restrict__ w2b,
                                                const int* __restrict__ cnt,
                                                const int* __restrict__ eslot,
                                                unsigned short* __restrict__ dbuf)
{
    int e = blockIdx.z >> 2;
    int slice = blockIdx.z & 3;
    int c = cnt[e];
    int p0 = blockIdx.y * 128;
    if (p0 >= c) return;
    int h0 = blockIdx.x * 128;
    int tid = threadIdx.x;
    const int kb0 = slice * (I_ / KSLC);

    __shared__ char As[16384], Bs[16384];
    __shared__ int rowslotS[128];
    if (tid < 128) rowslotS[tid] = eslot[e * S_ + min(p0 + tid, c - 1)];
    __syncthreads();

    int lane = tid & 63, w = tid >> 6, wm = w >> 1, wn = w & 1;
    int lm = lane & 15, lk = lane >> 4;
    int wb16 = (tid & ~63) * 16;
    size_t wbase = (size_t)e * H_ * I_;

    f32x4 z = {0.f, 0.f, 0.f, 0.f};
    f32x4 acc[4][4];
#pragma unroll
    for (int mf = 0; mf < 4; ++mf)
#pragma unroll
        for (int nf = 0; nf < 4; ++nf) acc[mf][nf] = z;

    const int NKT = (I_ / KSLC) / 64;
    for (int kt = 0; kt < NKT; ++kt) {
        int kb = kb0 + kt * 64;
#pragma unroll
        for (int it = 0; it < 4; ++it) {
            int g = tid + it * 256, row = g >> 3, kg = g & 7;
            int kgs = kg ^ (row & 7);
            gload16u(hbuf + (size_t)rowslotS[row] * I_ + kb + kgs * 8, As, wb16 + it * 4096);
            gload16u(w2b + wbase + (size_t)(h0 + row) * I_ + kb + kgs * 8, Bs, wb16 + it * 4096);
        }
        vmdrain();
        __syncthreads();
#pragma unroll
        for (int ks = 0; ks < 2; ++ks) {
            bf16x8 af[4];
#pragma unroll
            for (int mf = 0; mf < 4; ++mf) {
                int row = wm * 64 + mf * 16 + lm;
                af[mf] = *(const bf16x8*)(As + row * 128 + ((ks * 64 + lk * 16) ^ ((row & 7) << 4)));
            }
#pragma unroll
            for (int nf = 0; nf < 4; ++nf) {
                int brow = wn * 64 + nf * 16 + lm;
                bf16x8 bf = *(const bf16x8*)(Bs + brow * 128 + ((ks * 64 + lk * 16) ^ ((brow & 7) << 4)));
#pragma unroll
                for (int mf = 0; mf < 4; ++mf)
                    acc[mf][nf] = __builtin_amdgcn_mfma_f32_16x16x32_bf16(af[mf], bf, acc[mf][nf], 0, 0, 0);
            }
        }
        __syncthreads();
    }

    unsigned short* dslice = dbuf + (size_t)slice * S_ * 2 * H_;
#pragma unroll
    for (int mf = 0; mf < 4; ++mf)
#pragma unroll
        for (int nf = 0; nf < 4; ++nf) {
            int colh = h0 + wn * 64 + nf * 16 + lm;
#pragma unroll
            for (int j = 0; j < 4; ++j) {
                int rloc = wm * 64 + mf * 16 + lk * 4 + j;
                if (p0 + rloc < c)
                    dslice[(size_t)rowslotS[rloc] * H_ + colh] = f2bf(acc[mf][nf][j]);
            }
        }
}

// ---------------- MoE up (reg-staged, WB=false fallback)
template<bool WB>
__global__ __launch_bounds__(256) void moe_up_mfma(const float* __restrict__ x2,
                                                   const void* __restrict__ w1,
                                                   const void* __restrict__ w3,
                                                   const int* __restrict__ cnt,
                                                   const int* __restrict__ elist,
                                                   const int* __restrict__ eslot,
                                                   unsigned short* __restrict__ hbuf)
{
    int e = blockIdx.z;
    int c = cnt[e];
    int p0 = blockIdx.y * 128;
    if (p0 >= c) return;
    int i0 = blockIdx.x * 64;
    int tid = threadIdx.x;

    __shared__ char As[16384], B1s[8192], B3s[8192];
    __shared__ int rowtokS[128], rowslotS[128];
    if (tid < 128) {
        int p = min(p0 + tid, c - 1);
        rowtokS[tid]  = elist[e * S_ + p];
        rowslotS[tid] = eslot[e * S_ + p];
    }
    __syncthreads();

    int lane = tid & 63, w = tid >> 6, wm = w >> 1, wn = w & 1;
    int lm = lane & 15, lk = lane >> 4;
    size_t wbase = (size_t)e * I_ * H_;

    int4 rA[4], rB1[2], rB3[2];
    auto loadAll = [&](int kb) {
#pragma unroll
        for (int it = 0; it < 4; ++it) {
            int g = tid + it * 256, row = g >> 3, kg = g & 7;
            const float* s = x2 + (size_t)rowtokS[row] * H_ + kb + kg * 8;
            float4 f0 = *(const float4*)s, f1 = *(const float4*)(s + 4);
            rA[it] = make_int4(pkbf(f0.x, f0.y), pkbf(f0.z, f0.w),
                               pkbf(f1.x, f1.y), pkbf(f1.z, f1.w));
        }
#pragma unroll
        for (int it = 0; it < 2; ++it) {
            int g = tid + it * 256, row = g >> 3, kg = g & 7;
            size_t off = wbase + (size_t)(i0 + row) * H_ + kb + kg * 8;
            rB1[it] = loadW16<WB>(w1, off);
            rB3[it] = loadW16<WB>(w3, off);
        }
    };
    auto writeAll = [&]() {
#pragma unroll
        for (int it = 0; it < 4; ++it) {
            int g = tid + it * 256, row = g >> 3, kg = g & 7;
            int byte = row * 128 + ((kg * 16) ^ ((row & 7) << 4));
            *(int4*)(As + byte) = rA[it];
        }
#pragma unroll
        for (int it = 0; it < 2; ++it) {
            int g = tid + it * 256, row = g >> 3, kg = g & 7;
            int byte = row * 128 + ((kg * 16) ^ ((row & 7) << 4));
            *(int4*)(B1s + byte) = rB1[it];
            *(int4*)(B3s + byte) = rB3[it];
        }
    };

    f32x4 z = {0.f, 0.f, 0.f, 0.f};
    f32x4 acc1[4][2], acc3[4][2];
#pragma unroll
    for (int mf = 0; mf < 4; ++mf)
#pragma unroll
        for (int nf = 0; nf < 2; ++nf) { acc1[mf][nf] = z; acc3[mf][nf] = z; }

    loadAll(0);
    for (int kt = 0; kt < H_ / 64; ++kt) {
        __syncthreads();
        writeAll();
        __syncthreads();
        if (kt + 1 < H_ / 64) loadAll((kt + 1) * 64);
#pragma unroll
        for (int ks = 0; ks < 2; ++ks) {
            bf16x8 af[4];
#pragma unroll
            for (int mf = 0; mf < 4; ++mf) {
                int row = wm * 64 + mf * 16 + lm;
                af[mf] = *(const bf16x8*)(As + row * 128 + ((ks * 64 + lk * 16) ^ ((row & 7) << 4)));
            }
#pragma unroll
            for (int nf = 0; nf < 2; ++nf) {
                int brow = wn * 32 + nf * 16 + lm;
                int bby = brow * 128 + ((ks * 64 + lk * 16) ^ ((brow & 7) << 4));
                bf16x8 b1 = *(const bf16x8*)(B1s + bby);
                bf16x8 b3 = *(const bf16x8*)(B3s + bby);
#pragma unroll
                for (int mf = 0; mf < 4; ++mf) {
                    acc1[mf][nf] = __builtin_amdgcn_mfma_f32_16x16x32_bf16(af[mf], b1, acc1[mf][nf], 0, 0, 0);
                    acc3[mf][nf] = __builtin_amdgcn_mfma_f32_16x16x32_bf16(af[mf], b3, acc3[mf][nf], 0, 0, 0);
                }
            }
        }
    }

#pragma unroll
    for (int mf = 0; mf < 4; ++mf)
#pragma unroll
        for (int nf = 0; nf < 2; ++nf) {
            int coli = i0 + wn * 32 + nf * 16 + lm;
#pragma unroll
            for (int j = 0; j < 4; ++j) {
                int rloc = wm * 64 + mf * 16 + lk * 4 + j;
                if (p0 + rloc < c) {
                    float h1 = acc1[mf][nf][j];
                    float val = h1 / (1.f + __expf(-h1)) * acc3[mf][nf][j];
                    hbuf[(size_t)rowslotS[rloc] * I_ + coli] = f2bf(val);
                }
            }
        }
}

// ---------------- MoE down (reg-staged, WB=false fallback)
template<bool WB>
__global__ __launch_bounds__(256) void moe_dn_mfma(const unsigned short* __restrict__ hbuf,
                                                   const void* __restrict__ w2,
                                                   const int* __restrict__ cnt,
                                                   const int* __restrict__ eslot,
                                                   unsigned short* __restrict__ dbuf)
{
    int e = blockIdx.z >> 2;
    int slice = blockIdx.z & 3;
    int c = cnt[e];
    int p0 = blockIdx.y * 128;
    if (p0 >= c) return;
    int h0 = blockIdx.x * 128;
    int tid = threadIdx.x;
    const int kb0 = slice * (I_ / KSLC);

    __shared__ char As[16384], Bs[16384];
    __shared__ int rowslotS[128];
    if (tid < 128) rowslotS[tid] = eslot[e * S_ + min(p0 + tid, c - 1)];
    __syncthreads();

    int lane = tid & 63, w = tid >> 6, wm = w >> 1, wn = w & 1;
    int lm = lane & 15, lk = lane >> 4;
    size_t wbase = (size_t)e * H_ * I_;

    int4 rA[4], rB[4];
    auto loadAll = [&](int kb) {
#pragma unroll
        for (int it = 0; it < 4; ++it) {
            int g = tid + it * 256, row = g >> 3, kg = g & 7;
            rA[it] = *(const int4*)(hbuf + (size_t)rowslotS[row] * I_ + kb + kg * 8);
            rB[it] = loadW16<WB>(w2, wbase + (size_t)(h0 + row) * I_ + kb + kg * 8);
        }
    };
    auto writeAll = [&]() {
#pragma unroll
        for (int it = 0; it < 4; ++it) {
            int g = tid + it * 256, row = g >> 3, kg = g & 7;
            int byte = row * 128 + ((kg * 16) ^ ((row & 7) << 4));
            *(int4*)(As + byte) = rA[it];
            *(int4*)(Bs + byte) = rB[it];
        }
    };

    f32x4 z = {0.f, 0.f, 0.f, 0.f};
    f32x4 acc[4][4];
#pragma unroll
    for (int mf = 0; mf < 4; ++mf)
#pragma unroll
        for (int nf = 0; nf < 4; ++nf) acc[mf][nf] = z;

    loadAll(kb0);
    const int NKT = (I_ / KSLC) / 64;
    for (int kt = 0; kt < NKT; ++kt) {
        __syncthreads();
        writeAll();
        __syncthreads();
        if (kt + 1 < NKT) loadAll(kb0 + (kt + 1) * 64);
#pragma unroll
        for (int ks = 0; ks < 2; ++ks) {
            bf16x8 af[4];
#pragma unroll
            for (int mf = 0; mf < 4; ++mf) {
                int row = wm * 64 + mf * 16 + lm;
                af[mf] = *(const bf16x8*)(As + row * 128 + ((ks * 64 + lk * 16) ^ ((row & 7) << 4)));
            }
#pragma unroll
            for (int nf = 0; nf < 4; ++nf) {
                int brow = wn * 64 + nf * 16 + lm;
                bf16x8 bf = *(const bf16x8*)(Bs + brow * 128 + ((ks * 64 + lk * 16) ^ ((brow & 7) << 4)));
#pragma unroll
                for (int mf = 0; mf < 4; ++mf)
                    acc[mf][nf] = __builtin_amdgcn_mfma_f32_16x16x32_bf16(af[mf], bf, acc[mf][nf], 0, 0, 0);
            }
        }
    }

    unsigned short* dslice = dbuf + (size_t)slice * S_ * 2 * H_;
#pragma unroll
    for (int mf = 0; mf < 4; ++mf)
#pragma unroll
        for (int nf = 0; nf < 4; ++nf) {
            int colh = h0 + wn * 64 + nf * 16 + lm;
#pragma unroll
            for (int j = 0; j < 4; ++j) {
                int rloc = wm * 64 + mf * 16 + lk * 4 + j;
                if (p0 + rloc < c)
                    dslice[(size_t)rowslotS[rloc] * H_ + colh] = f2bf(acc[mf][nf][j]);
            }
        }
}

// ---------------- Final combine
__global__ __launch_bounds__(256) void combine_k(const float* __restrict__ hid2,
                                                 const unsigned short* __restrict__ dbuf,
                                                 const float* __restrict__ wslot,
                                                 float* __restrict__ out)
{
    int idx = blockIdx.x * 256 + threadIdx.x;
    if (idx >= S_ * H_) return;
    int n = idx >> 10;
    int hcol = idx & (H_ - 1);
    float s0 = 0.f, s1 = 0.f;
#pragma unroll
    for (int sl = 0; sl < KSLC; ++sl) {
        const unsigned short* base = dbuf + (size_t)sl * S_ * 2 * H_;
        s0 += bf2f(base[(size_t)(2 * n)     * H_ + hcol]);
        s1 += bf2f(base[(size_t)(2 * n + 1) * H_ + hcol]);
    }
    out[idx] = hid2[idx] + wslot[2 * n] * s0 + wslot[2 * n + 1] * s1;
}

extern "C" void kernel_launch(void* const* d_in, const int* in_sizes, int n_in,
                              void* d_out, int out_size, void* d_ws, size_t ws_size,
                              hipStream_t stream)
{
    const float* hidden = (const float*)d_in[0];
    const float* ln1    = (const float*)d_in[1];
    const float* ln2    = (const float*)d_in[2];
    const float* wq     = (const float*)d_in[3];
    const float* wk     = (const float*)d_in[4];
    const float* wv     = (const float*)d_in[5];
    const float* wo     = (const float*)d_in[6];
    const float* gw     = (const float*)d_in[7];
    const float* w1     = (const float*)d_in[8];
    const float* w2     = (const float*)d_in[9];
    const float* w3     = (const float*)d_in[10];
    float* out = (float*)d_out;

    char* p = (char*)d_ws;
    auto alignp = [&]() { p = (char*)(((uintptr_t)p + 255) & ~(uintptr_t)255); };
    auto alloc_f = [&](size_t n) { alignp(); float* r = (float*)p; p += n * 4; return r; };
    auto alloc_h = [&](size_t n) { alignp(); unsigned short* r = (unsigned short*)p; p += n * 2; return r; };
    auto alloc_i = [&](size_t n) { alignp(); int* r = (int*)p; p += n * 4; return r; };

    float* xb   = alloc_f((size_t)S_ * H_);
    unsigned short* xbb = alloc_h((size_t)S_ * H_);
    float* q    = alloc_f((size_t)S_ * NH_ * HD_);
    float* kb   = alloc_f((size_t)S_ * KVH_ * HD_);
    float* vb   = alloc_f((size_t)S_ * KVH_ * HD_);
    unsigned short* qkvb = alloc_h((size_t)S_ * 2048);
    float* hid2 = alloc_f((size_t)S_ * H_);
    float* x2   = alloc_f((size_t)S_ * H_);
    unsigned short* x2b  = alloc_h((size_t)S_ * H_);
    unsigned short* ctxb = alloc_h((size_t)S_ * H_);
    unsigned short* hbuf = alloc_h((size_t)S_ * 2 * I_);
    unsigned short* dbuf = alloc_h((size_t)KSLC * S_ * 2 * H_);
    float* wslot= alloc_f((size_t)S_ * 2);
    unsigned short* qbf = alloc_h((size_t)S_ * NH_ * HD_);
    unsigned short* kbf = alloc_h((size_t)S_ * KVH_ * HD_);
    unsigned short* vtb = alloc_h((size_t)KVH_ * HD_ * S_);
    int* cnt   = alloc_i(E_);
    int* elist = alloc_i((size_t)E_ * S_);
    int* eslot = alloc_i((size_t)E_ * S_);
    float* ctx = xb;  // alias: xb dead after QKV

    size_t used = (size_t)(p - (char*)d_ws);
    const size_t nW = (size_t)E_ * I_ * H_;
    size_t wbf_bytes = (3 * nW + (size_t)2048 * H_ + (size_t)H_ * NH_ * HD_) * 2 + 8192;
    bool WB = ws_size > used && (ws_size - used) >= wbf_bytes;

    unsigned short *w1b = nullptr, *w3b = nullptr, *w2b = nullptr;
    unsigned short *wqkvb = nullptr, *wob = nullptr;
    if (WB) {
        w1b = alloc_h(nW); w3b = alloc_h(nW); w2b = alloc_h(nW);
        wqkvb = alloc_h((size_t)2048 * H_);           // [q 1024 | k 512 | v 512] rows
        wob = alloc_h((size_t)H_ * NH_ * HD_);
    }

    hipMemsetAsync(cnt, 0, E_ * sizeof(int), stream);

    if (WB) {
        conv_bf16<<<2048, 256, 0, stream>>>(w1, w1b, (long)(nW / 8));
        conv_bf16<<<2048, 256, 0, stream>>>(w3, w3b, (long)(nW / 8));
        conv_bf16<<<2048, 256, 0, stream>>>(w2, w2b, (long)(nW / 8));
        conv_bf16<<<512, 256, 0, stream>>>(wq, wqkvb, (long)((size_t)NH_*HD_*H_ / 8));
        conv_bf16<<<256, 256, 0, stream>>>(wk, wqkvb + (size_t)NH_*HD_*H_, (long)((size_t)KVH_*HD_*H_ / 8));
        conv_bf16<<<256, 256, 0, stream>>>(wv, wqkvb + (size_t)(NH_+KVH_)*HD_*H_, (long)((size_t)KVH_*HD_*H_ / 8));
        conv_bf16<<<512, 256, 0, stream>>>(wo, wob, (long)((size_t)H_*NH_*HD_ / 8));
    }

    rmsnorm_k<<<S_, 256, 0, stream>>>(hidden, ln1, xb, WB ? xbb : nullptr);

    if (WB) {
        // fused QKV: A=xbb [2048x1024], B=wqkvb [2048x1024], OUT bf16 qkvb [2048x2048]
        dense_g<false><<<dim3(32, 16), 256, 0, stream>>>(xbb, wqkvb, nullptr, qkvb, H_, 2048);
        {
            int tot = S_ * (NH_ + KVH_) * 32;
            rope_conv_b<<<SDIV(tot, 256), 256, 0, stream>>>(qkvb, qbf, kbf);
        }
        v_trans_b<<<dim3(S_ / 64, KVH_), 256, 0, stream>>>(qkvb, vtb);
        attn_mfma<<<dim3(16, NH_, 2), 256, 0, stream>>>(qbf, kbf, vtb, ctx, ctxb);
        dense_g<true><<<dim3(16, 16), 256, 0, stream>>>(ctxb, wob, hidden, hid2, H_, H_);
    } else {
        dense_mfma<false><<<dim3(8, 16), 256, 0, stream>>>(xb, wq, nullptr, q,  S_, NH_ * HD_, H_);
        dense_mfma<false><<<dim3(4, 16), 256, 0, stream>>>(xb, wk, nullptr, kb, S_, KVH_ * HD_, H_);
        dense_mfma<false><<<dim3(4, 16), 256, 0, stream>>>(xb, wv, nullptr, vb, S_, KVH_ * HD_, H_);
        {
            int tot = S_ * (NH_ + KVH_) * 32;
            rope_conv<<<SDIV(tot, 256), 256, 0, stream>>>(q, kb, qbf, kbf);
        }
        v_trans<<<dim3(S_ / 64, KVH_), 256, 0, stream>>>(vb, vtb);
        attn_mfma<<<dim3(16, NH_, 2), 256, 0, stream>>>(qbf, kbf, vtb, ctx, ctxb);
        dense_mfma<false><<<dim3(8, 16), 256, 0, stream>>>(ctx, wo, hidden, hid2, S_, H_, NH_ * HD_);
    }

    rmsnorm_k<<<S_, 256, 0, stream>>>(hid2, ln2, x2, x2b);
    router_k<<<S_, 64, 0, stream>>>(x2, gw, cnt, elist, eslot, wslot);

    if (WB) {
        moe_up_g<<<dim3(I_ / 64, S_ / 128, E_), 256, 0, stream>>>(x2b, w1b, w3b, cnt, elist, eslot, hbuf);
        moe_dn_g<<<dim3(H_ / 128, S_ / 128, E_ * KSLC), 256, 0, stream>>>(hbuf, w2b, cnt, eslot, dbuf);
    } else {
        moe_up_mfma<false><<<dim3(I_ / 64, S_ / 128, E_), 256, 0, stream>>>(x2, w1, w3, cnt, elist, eslot, hbuf);
        moe_dn_mfma<false><<<dim3(H_ / 128, S_ / 128, E_ * KSLC), 256, 0, stream>>>(hbuf, w2, cnt, eslot, dbuf);
    }
    combine_k<<<SDIV(S_ * H_, 256), 256, 0, stream>>>(hid2, dbuf, wslot, out);
}